// Round 7
// baseline (1973.365 us; speedup 1.0000x reference)
//
#include <hip/hip_runtime.h>
#include <math.h>

#define D_MODEL 1024
#define N_HEADS 16
#define HEAD_DIM 64
#define HIDDEN 4096
#define TMAX 2048

typedef __attribute__((ext_vector_type(8))) short s16x8;
typedef __attribute__((ext_vector_type(4))) float f32x4;

// ---------------- wave helpers (wave64) ----------------
__device__ __forceinline__ float wave_max_f(float v) {
#pragma unroll
  for (int o = 32; o > 0; o >>= 1) v = fmaxf(v, __shfl_xor(v, o));
  return v;
}
__device__ __forceinline__ float wave_sum_f(float v) {
#pragma unroll
  for (int o = 32; o > 0; o >>= 1) v += __shfl_xor(v, o);
  return v;
}
__device__ __forceinline__ unsigned long long wave_max_u64(unsigned long long k) {
#pragma unroll
  for (int o = 32; o > 0; o >>= 1) {
    unsigned long long u = __shfl_xor(k, o);
    if (u > k) k = u;
  }
  return k;
}
__device__ __forceinline__ unsigned ford(float v) {
  unsigned u = __float_as_uint(v);
  return (u & 0x80000000u) ? ~u : (u | 0x80000000u);
}
// fp32 -> bf16 RNE
__device__ __forceinline__ unsigned short f2bf(float f) {
  unsigned u = __float_as_uint(f);
  u += 0x7FFFu + ((u >> 16) & 1u);
  return (unsigned short)(u >> 16);
}
__device__ __forceinline__ float bf2f(unsigned short h) {
  return __uint_as_float((unsigned)h << 16);
}

__device__ __forceinline__ void gload_lds16(const void* g, void* l) {
  __builtin_amdgcn_global_load_lds(
      (const __attribute__((address_space(1))) void*)g,
      (__attribute__((address_space(3))) void*)l, 16, 0, 0);
}

// ---------------- embedding ----------------
__global__ __launch_bounds__(256) void embed_kernel(const int* __restrict__ ids,
    const float* __restrict__ Wemb, const float* __restrict__ Wpos, float* __restrict__ X) {
  int t = blockIdx.x, tid = threadIdx.x;
  int id = ids[t];
  float4 e = ((const float4*)(Wemb + (size_t)id * D_MODEL))[tid];
  float4 p = ((const float4*)(Wpos + (size_t)t * D_MODEL))[tid];
  e.x += p.x; e.y += p.y; e.z += p.z; e.w += p.w;
  ((float4*)(X + (size_t)t * D_MODEL))[tid] = e;
}

// ---------------- layernorm; optional fp32 out + bf16 hi/lo out ----------------
__global__ __launch_bounds__(256) void ln_kernel(const float* __restrict__ X,
    float* __restrict__ Y, unsigned short* __restrict__ Ybh, unsigned short* __restrict__ Ybl,
    const float* __restrict__ g, const float* __restrict__ b) {
  int row = blockIdx.x, tid = threadIdx.x;
  int lane = tid & 63, wid = tid >> 6;
  __shared__ float red[8];
  float4 v = ((const float4*)(X + (size_t)row * D_MODEL))[tid];
  float s = v.x + v.y + v.z + v.w;
  s = wave_sum_f(s);
  if (lane == 0) red[wid] = s;
  __syncthreads();
  float mean = (red[0] + red[1] + red[2] + red[3]) * (1.0f / D_MODEL);
  float dx = v.x - mean, dy = v.y - mean, dz = v.z - mean, dw = v.w - mean;
  float q = dx * dx + dy * dy + dz * dz + dw * dw;
  q = wave_sum_f(q);
  if (lane == 0) red[4 + wid] = q;
  __syncthreads();
  float var = (red[4] + red[5] + red[6] + red[7]) * (1.0f / D_MODEL);
  float rs = rsqrtf(var + 1e-5f);
  float4 gg = ((const float4*)g)[tid], bb = ((const float4*)b)[tid];
  float4 y;
  y.x = dx * rs * gg.x + bb.x;
  y.y = dy * rs * gg.y + bb.y;
  y.z = dz * rs * gg.z + bb.z;
  y.w = dw * rs * gg.w + bb.w;
  if (Y) ((float4*)(Y + (size_t)row * D_MODEL))[tid] = y;
  if (Ybh) {
    ushort4 oh;
    oh.x = f2bf(y.x); oh.y = f2bf(y.y); oh.z = f2bf(y.z); oh.w = f2bf(y.w);
    ((ushort4*)(Ybh + (size_t)row * D_MODEL))[tid] = oh;
    if (Ybl) {
      ushort4 ol;
      ol.x = f2bf(y.x - bf2f(oh.x)); ol.y = f2bf(y.y - bf2f(oh.y));
      ol.z = f2bf(y.z - bf2f(oh.z)); ol.w = f2bf(y.w - bf2f(oh.w));
      ((ushort4*)(Ybl + (size_t)row * D_MODEL))[tid] = ol;
    }
  }
}

// ---------------- sparsify (exact top-fk by |value| per 64 segment) ----------------
__global__ __launch_bounds__(256) void sparsify_kernel(float* __restrict__ X, int nseg, int fk) {
  int seg = blockIdx.x * 4 + (threadIdx.x >> 6);
  if (seg >= nseg) return;
  int lane = threadIdx.x & 63;
  size_t idx = (size_t)seg * 64 + lane;
  float x = X[idx];
  float a = fabsf(x);
  float cur = INFINITY;
  int remaining = fk;
  float thr = 0.0f;
  for (;;) {
    float cand = (a < cur) ? a : -INFINITY;
    float mv = wave_max_f(cand);
    if (mv == -INFINITY) { thr = mv; break; }
    int c = __popcll(__ballot(a == mv));
    if (c >= remaining) { thr = mv; break; }
    remaining -= c; cur = mv;
  }
  if (!(a >= thr)) X[idx] = 0.0f;
}

// ---------------- transpose fp32 [R][C] -> [C][R] ----------------
__global__ __launch_bounds__(256) void transpose_kernel(const float* __restrict__ in,
    float* __restrict__ out, int R, int Cc) {
  __shared__ float tile[32][33];
  int c0 = blockIdx.x * 32, r0 = blockIdx.y * 32;
  int tx = threadIdx.x & 31, ty = threadIdx.x >> 5;
  for (int i = ty; i < 32; i += 8)
    tile[i][tx] = in[(size_t)(r0 + i) * Cc + c0 + tx];
  __syncthreads();
  for (int i = ty; i < 32; i += 8)
    out[(size_t)(c0 + i) * R + r0 + tx] = tile[tx][i];
}

// ---------------- transpose-convert fp32 [R][C] -> bf16 hi/lo [C][R] ----------------
__global__ __launch_bounds__(256) void transpose_conv_pair_kernel(const float* __restrict__ in,
    unsigned short* __restrict__ oh, unsigned short* __restrict__ ol, int R, int Cc) {
  __shared__ float tile[32][33];
  int c0 = blockIdx.x * 32, r0 = blockIdx.y * 32;
  int tx = threadIdx.x & 31, ty = threadIdx.x >> 5;
  for (int i = ty; i < 32; i += 8)
    tile[i][tx] = in[(size_t)(r0 + i) * Cc + c0 + tx];
  __syncthreads();
  for (int i = ty; i < 32; i += 8) {
    float v = tile[tx][i];
    unsigned short h = f2bf(v);
    size_t idx = (size_t)(c0 + i) * R + r0 + tx;
    oh[idx] = h;
    ol[idx] = f2bf(v - bf2f(h));
  }
}

// ---------------- fp32 -> bf16 elementwise ----------------
__global__ __launch_bounds__(256) void conv_bf16_kernel(const float* __restrict__ in,
    unsigned short* __restrict__ out, size_t n) {
  size_t i = ((size_t)blockIdx.x * 256 + threadIdx.x) * 4;
  size_t stride = (size_t)gridDim.x * 1024;
  for (; i < n; i += stride) {
    float4 v = *(const float4*)(in + i);
    ushort4 o;
    o.x = f2bf(v.x); o.y = f2bf(v.y); o.z = f2bf(v.z); o.w = f2bf(v.w);
    *(ushort4*)(out + i) = o;
  }
}

// ---------------- attention: one wave per (head, query-row) ----------------
// exact: scores=q@k^T/8 causal; stable top-64 (val desc, idx asc); softmax; @v
// staged sc[] score pass (reg q-features); rank-select top-64 (64<=P<=128);
// argmax fallback (128<P<=320); full exact path otherwise.
__global__ __launch_bounds__(64) void attn_kernel(const float* __restrict__ Q,
    const float* __restrict__ Kt, const float* __restrict__ V,
    float* __restrict__ Of, unsigned short* __restrict__ Oh, unsigned short* __restrict__ Ol,
    int T) {
  int t = blockIdx.x % T;
  int h = blockIdx.x / T;
  int lane = threadIdx.x;
  unsigned long long lmlt = (1ull << lane) - 1ull;

  __shared__ float sc[TMAX];
  __shared__ float qval[HEAD_DIM];
  __shared__ int qdim[HEAD_DIM];
  constexpr int PCAP = 320;
  __shared__ float posv[PCAP];
  __shared__ int posi[PCAP];
  __shared__ unsigned long long kbuf[128];
  __shared__ int seli[64];
  __shared__ float selv[64];
  __shared__ float wsel[64];

  int hoff = h * HEAD_DIM;
  float qv = Q[(size_t)t * D_MODEL + hoff + lane];
  unsigned long long nzm = __ballot(qv != 0.0f);
  int nq = __popcll(nzm);
  if (qv != 0.0f) {
    int p = __popcll(nzm & lmlt);
    qval[p] = qv; qdim[p] = lane;
  }
  __syncthreads();

  // hoist q-features into registers (nq <= 4 covers all practical cases)
  unsigned long long mm = nzm;
  int d0 = 0, d1, d2, d3;
  if (mm) { d0 = __builtin_ctzll(mm); mm &= mm - 1; }
  if (mm) { d1 = __builtin_ctzll(mm); mm &= mm - 1; } else d1 = d0;
  if (mm) { d2 = __builtin_ctzll(mm); mm &= mm - 1; } else d2 = d0;
  if (mm) { d3 = __builtin_ctzll(mm); mm &= mm - 1; } else d3 = d0;
  float q0 = __shfl(qv, d0), q1 = __shfl(qv, d1), q2 = __shfl(qv, d2), q3 = __shfl(qv, d3);
  if (nq == 0) q0 = 0.0f;
  if (nq < 2) q1 = 0.0f;
  if (nq < 3) q2 = 0.0f;
  if (nq < 4) q3 = 0.0f;
  const float* kt0 = Kt + (size_t)(hoff + d0) * T;
  const float* kt1 = Kt + (size_t)(hoff + d1) * T;
  const float* kt2 = Kt + (size_t)(hoff + d2) * T;
  const float* kt3 = Kt + (size_t)(hoff + d3) * T;

  int Vn = t + 1;
  // ---- staged score pass (independent iterations -> deep load pipelining) ----
  if (nq == 2) {
    for (int s = lane; s < Vn; s += 64)
      sc[s] = fmaf(q1, kt1[s], q0 * kt0[s]) * 0.125f;
  } else if (nq <= 4) {
    for (int s = lane; s < Vn; s += 64)
      sc[s] = fmaf(q3, kt3[s], fmaf(q2, kt2[s], fmaf(q1, kt1[s], q0 * kt0[s]))) * 0.125f;
  } else {
    for (int s = lane; s < Vn; s += 64) {
      float acc = 0.0f;
      for (int j = 0; j < nq; ++j)
        acc += qval[j] * Kt[(size_t)(hoff + qdim[j]) * T + s];
      sc[s] = acc * 0.125f;
    }
  }
  __syncthreads();

  int nsel = 0;
  if (Vn <= 64) {
    nsel = Vn;
    if (lane < Vn) { seli[lane] = lane; selv[lane] = sc[lane]; }
    __syncthreads();
  } else {
    // compact positive scores (list index order == s order)
    int base = 0;
    for (int s0 = 0; s0 < Vn; s0 += 64) {
      int s = s0 + lane;
      float v = (s < Vn) ? sc[s] : -1.0f;
      unsigned long long pm = __ballot(v > 0.0f);
      if (v > 0.0f) {
        int p = base + __popcll(pm & lmlt);
        if (p < PCAP) { posv[p] = v; posi[p] = s; }
      }
      base += __popcll(pm);
    }
    int P = base;
    __syncthreads();

    bool fullpath = false;
    if (P >= 64) {
      if (P <= 128) {
        // ---- rank-select top-64: rank = #(keys greater); keys unique ----
        unsigned long long k0 =
            (((unsigned long long)ford(posv[lane]) << 32) |
             (unsigned long long)(0xFFFFFFFFu - (unsigned)lane));  // lane < 64 <= P
        int e1 = lane + 64;
        unsigned long long k1 = (e1 < P)
            ? (((unsigned long long)ford(posv[e1]) << 32) |
               (unsigned long long)(0xFFFFFFFFu - (unsigned)e1))
            : 0ull;
        kbuf[lane] = k0;
        kbuf[e1] = k1;
        __syncthreads();
        int r0 = 0, r1 = 0;
#pragma unroll
        for (int j = 0; j < 128; j += 2) {
          unsigned long long a = kbuf[j], b = kbuf[j + 1];
          r0 += (a > k0) ? 1 : 0;
          r0 += (b > k0) ? 1 : 0;
          r1 += (a > k1) ? 1 : 0;
          r1 += (b > k1) ? 1 : 0;
        }
        if (r0 < 64) { seli[r0] = posi[lane]; selv[r0] = posv[lane]; }
        if (k1 != 0ull && r1 < 64) { seli[r1] = posi[e1]; selv[r1] = posv[e1]; }
        nsel = 64;
        __syncthreads();
      } else if (P <= PCAP) {
        for (int r = 0; r < 64; ++r) {
          unsigned long long best = 0ull;
          for (int j = lane; j < P; j += 64) {
            float v = posv[j];
            if (v > 0.0f) {
              unsigned long long key =
                  ((unsigned long long)ford(v) << 32) | (unsigned)(0xFFFFFFFFu - (unsigned)j);
              if (key > best) best = key;
            }
          }
          best = wave_max_u64(best);
          int j = (int)(0xFFFFFFFFu - (unsigned)(best & 0xFFFFFFFFull));
          if (lane == (j & 63)) {
            seli[r] = posi[j]; selv[r] = posv[j]; posv[j] = -INFINITY;
          }
          __syncthreads();
        }
        nsel = 64;
      } else {
        fullpath = true;
      }
    } else {
      if (lane < P) { seli[lane] = posi[lane]; selv[lane] = posv[lane]; }
      int need = 64 - P;
      int zbase = 0;
      bool done = false;
      for (int s0 = 0; s0 < Vn && !done; s0 += 64) {
        int s = s0 + lane;
        bool isz = (s < Vn) && (sc[s] == 0.0f);
        unsigned long long zm = __ballot(isz);
        int pre = __popcll(zm & lmlt);
        if (isz && (zbase + pre) < need) {
          seli[P + zbase + pre] = s;
          selv[P + zbase + pre] = 0.0f;
        }
        zbase += __popcll(zm);
        if (zbase >= need) done = true;
      }
      if (zbase >= need) {
        nsel = 64;
        __syncthreads();
      } else {
        fullpath = true;
      }
    }

    if (fullpath) {
      __syncthreads();
      nsel = 64;
      for (int r = 0; r < 64; ++r) {
        unsigned long long best = 0ull;
        for (int s = lane; s < Vn; s += 64) {
          float v = sc[s];
          if (v != -INFINITY) {
            unsigned long long key =
                ((unsigned long long)ford(v) << 32) | (unsigned)(0x7FFFFFFFu - (unsigned)s);
            if (key > best) best = key;
          }
        }
        best = wave_max_u64(best);
        if (best == 0ull) { nsel = r; break; }
        int s = (int)(0x7FFFFFFFu - (unsigned)(best & 0xFFFFFFFFull));
        if (lane == (s & 63)) {
          seli[r] = s; selv[r] = sc[s]; sc[s] = -INFINITY;
        }
        __syncthreads();
      }
    }
  }

  // ---- softmax over selected (LDS-broadcast tree reductions) ----
  float vsel = (lane < nsel) ? selv[lane] : -INFINITY;
  wsel[lane] = vsel;
  __syncthreads();
  float m = -INFINITY;
#pragma unroll
  for (int j = 0; j < 64; j += 4) {
    float4 f = *(const float4*)&wsel[j];
    m = fmaxf(m, fmaxf(fmaxf(f.x, f.y), fmaxf(f.z, f.w)));
  }
  float wexp = (lane < nsel) ? expf(vsel - m) : 0.0f;
  __syncthreads();
  wsel[lane] = wexp;
  __syncthreads();
  float ds = 0.0f;
#pragma unroll
  for (int j = 0; j < 64; j += 4) {
    float4 f = *(const float4*)&wsel[j];
    ds += (f.x + f.y) + (f.z + f.w);
  }
  __syncthreads();
  wsel[lane] = wexp / ds;
  __syncthreads();

  // ---- weighted V accumulation ----
  float o = 0.0f;
  for (int r = 0; r < nsel; ++r)
    o += wsel[r] * V[(size_t)seli[r] * D_MODEL + hoff + lane];

  size_t oidx = (size_t)t * D_MODEL + hoff + lane;
  if (Of) Of[oidx] = o;
  if (Oh) {
    unsigned short hh = f2bf(o);
    Oh[oidx] = hh;
    Ol[oidx] = f2bf(o - bf2f(hh));
  }
}

// ============ single bf16 MFMA GEMM (NT): C[M,N] = A @ B^T ============
template <int FLAGS, typename CT>
__global__ __launch_bounds__(256) void gemm_bt_bf16(const unsigned short* __restrict__ A,
    const unsigned short* __restrict__ B, CT* __restrict__ C,
    const float* __restrict__ bias, const float* __restrict__ res, int M, int N, int K) {
  constexpr bool HAS_BIAS = (FLAGS & 1) != 0;
  constexpr bool HAS_GELU = (FLAGS & 2) != 0;
  constexpr bool HAS_RES = (FLAGS & 4) != 0;
  __shared__ unsigned short As[128 * 32];
  __shared__ unsigned short Bs[128 * 32];
  int tid = threadIdx.x;
  int lane = tid & 63, wid = tid >> 6;
  int wr = wid >> 1, wc = wid & 1;
  int m0 = blockIdx.y * 128, n0 = blockIdx.x * 128;

  int r_in = lane >> 2;
  int slot = lane & 3;

  f32x4 acc[4][4] = {};

  int fr = lane & 15;
  int ksl = lane >> 4;

  for (int k0 = 0; k0 < K; k0 += 32) {
#pragma unroll
    for (int s = 0; s < 2; ++s) {
      int row = wid * 32 + s * 16 + r_in;
      int ksw = (slot ^ ((row >> 1) & 3)) * 8;
      const unsigned short* ga = A + (size_t)(m0 + row) * K + k0 + ksw;
      const unsigned short* gb = B + (size_t)(n0 + row) * K + k0 + ksw;
      gload_lds16(ga, &As[(wid * 32 + s * 16) * 32]);
      gload_lds16(gb, &Bs[(wid * 32 + s * 16) * 32]);
    }
    asm volatile("s_waitcnt vmcnt(0)" ::: "memory");
    __syncthreads();

    s16x8 av[4], bv[4];
#pragma unroll
    for (int mi = 0; mi < 4; ++mi) {
      int ar = wr * 64 + mi * 16 + fr;
      av[mi] = *(const s16x8*)&As[ar * 32 + ((ksl ^ ((ar >> 1) & 3)) * 8)];
    }
#pragma unroll
    for (int ni = 0; ni < 4; ++ni) {
      int br = wc * 64 + ni * 16 + fr;
      bv[ni] = *(const s16x8*)&Bs[br * 32 + ((ksl ^ ((br >> 1) & 3)) * 8)];
    }
#pragma unroll
    for (int mi = 0; mi < 4; ++mi)
#pragma unroll
      for (int ni = 0; ni < 4; ++ni)
        acc[mi][ni] = __builtin_amdgcn_mfma_f32_16x16x32_bf16(av[mi], bv[ni], acc[mi][ni], 0, 0, 0);
    __syncthreads();
  }

  int cr = lane >> 4, cc = lane & 15;
#pragma unroll
  for (int mi = 0; mi < 4; ++mi) {
#pragma unroll
    for (int j = 0; j < 4; ++j) {
      int row = m0 + wr * 64 + mi * 16 + cr * 4 + j;
#pragma unroll
      for (int ni = 0; ni < 4; ++ni) {
        int col = n0 + wc * 64 + ni * 16 + cc;
        float vv = acc[mi][ni][j];
        if (HAS_BIAS) vv += bias[col];
        if (HAS_GELU) vv = 0.5f * vv * (1.0f + erff(vv * 0.70710678118654752f));
        if (HAS_RES) vv += res[(size_t)row * N + col];
        if constexpr (sizeof(CT) == 2)
          C[(size_t)row * N + col] = (CT)f2bf(vv);
        else
          C[(size_t)row * N + col] = (CT)vv;
      }
    }
  }
}

// ============ bf16x3 split-precision MFMA GEMM (NT) ============
template <int FLAGS, int OUTMODE>
__global__ __launch_bounds__(256) void gemm3_bt(
    const unsigned short* __restrict__ Ah, const unsigned short* __restrict__ Al,
    const unsigned short* __restrict__ Bh, const unsigned short* __restrict__ Bl,
    float* __restrict__ Cf, unsigned short* __restrict__ Ch, unsigned short* __restrict__ Cl,
    const float* __restrict__ bias, const float* __restrict__ res, int M, int N, int K) {
  constexpr bool HAS_BIAS = (FLAGS & 1) != 0;
  constexpr bool HAS_GELU = (FLAGS & 2) != 0;
  constexpr bool HAS_RES = (FLAGS & 4) != 0;
  __shared__ unsigned short As[2][128 * 32];
  __shared__ unsigned short Bs[2][128 * 32];
  int tid = threadIdx.x;
  int lane = tid & 63, wid = tid >> 6;
  int wr = wid >> 1, wc = wid & 1;
  int m0 = blockIdx.y * 128, n0 = blockIdx.x * 128;

  int r_in = lane >> 2;
  int slot = lane & 3;

  f32x4 acc[4][4] = {};

  int fr = lane & 15;
  int ksl = lane >> 4;

  for (int k0 = 0; k0 < K; k0 += 32) {
#pragma unroll
    for (int s = 0; s < 2; ++s) {
      int row = wid * 32 + s * 16 + r_in;
      int ksw = (slot ^ ((row >> 1) & 3)) * 8;
      size_t ao = (size_t)(m0 + row) * K + k0 + ksw;
      size_t bo = (size_t)(n0 + row) * K + k0 + ksw;
      int ldst = (wid * 32 + s * 16) * 32;
      gload_lds16(Ah + ao, &As[0][ldst]);
      gload_lds16(Al + ao, &As[1][ldst]);
      gload_lds16(Bh + bo, &Bs[0][ldst]);
      gload_lds16(Bl + bo, &Bs[1][ldst]);
    }
    asm volatile("s_waitcnt vmcnt(0)" ::: "memory");
    __syncthreads();

    s16x8 avh[4], avl[4], bvh[4], bvl[4];
#pragma unroll
    for (int mi = 0; mi < 4; ++mi) {
      int ar = wr * 64 + mi * 16 + fr;
      int off = ar * 32 + ((ksl ^ ((ar >> 1) & 3)) * 8);
      avh[mi] = *(const s16x8*)&As[0][off];
      avl[mi] = *(const s16x8*)&As[1][off];
    }
#pragma unroll
    for (int ni = 0; ni < 4; ++ni) {
      int br = wc * 64 + ni * 16 + fr;
      int off = br * 32 + ((ksl ^ ((br >> 1) & 3)) * 8);
      bvh[ni] = *(const s16x8*)&Bs[0][off];
      bvl[ni] = *(const s16x8*)&Bs[1][off];
    }
#pragma unroll
    for (int mi = 0; mi < 4; ++mi)
#pragma unroll
      for (int ni = 0; ni < 4; ++ni) {
        acc[mi][ni] = __builtin_amdgcn_mfma_f32_16x16x32_bf16(avh[mi], bvh[ni], acc[mi][ni], 0, 0, 0);
        acc[mi][ni] = __builtin_amdgcn_mfma_f32_16x16x32_bf16(avl[mi], bvh[ni], acc[mi][ni], 0, 0, 0);
        acc[mi][ni] = __builtin_amdgcn_mfma_f32_16x16x32_bf16(avh[mi], bvl[ni], acc[mi][ni], 0, 0, 0);
      }
    __syncthreads();
  }

  int cr = lane >> 4, cc = lane & 15;
#pragma unroll
  for (int mi = 0; mi < 4; ++mi) {
#pragma unroll
    for (int j = 0; j < 4; ++j) {
      int row = m0 + wr * 64 + mi * 16 + cr * 4 + j;
#pragma unroll
      for (int ni = 0; ni < 4; ++ni) {
        int col = n0 + wc * 64 + ni * 16 + cc;
        float vv = acc[mi][ni][j];
        if (HAS_BIAS) vv += bias[col];
        if (HAS_GELU) vv = 0.5f * vv * (1.0f + erff(vv * 0.70710678118654752f));
        if (HAS_RES) vv += res[(size_t)row * N + col];
        if constexpr (OUTMODE == 0) {
          Cf[(size_t)row * N + col] = vv;
        } else {
          unsigned short h = f2bf(vv);
          Ch[(size_t)row * N + col] = h;
          Cl[(size_t)row * N + col] = f2bf(vv - bf2f(h));
        }
      }
    }
  }
}

// ---------------- fp32 fused QKV GEMM (NN): [q|k|v] = xn @ [Wq|Wk|Wv] ----------------
__global__ __launch_bounds__(256) void gemm_nn_qkv(const float* __restrict__ A,
    const float* __restrict__ Bq, const float* __restrict__ Bk, const float* __restrict__ Bv,
    float* __restrict__ C, int M, int K) {
  __shared__ float As[16][68];
  __shared__ float Bs[16][68];
  int tid = threadIdx.x;
  int m0 = blockIdx.y * 64;
  int n0g = blockIdx.x * 64;
  const float* B = (n0g < 1024) ? Bq : (n0g < 2048 ? Bk : Bv);
  float* Cb = C + (size_t)(n0g >> 10) * ((size_t)M * 1024);
  int n0 = n0g & 1023;
  int tx = tid & 15, ty = tid >> 4;
  int am = tid >> 2, ak = (tid & 3) * 4;
  int bk = tid >> 4, bn = (tid & 15) * 4;
  const float* Ap = A + (size_t)(m0 + am) * K + ak;
  const float* Bp = B + (size_t)bk * 1024 + n0 + bn;
  float acc[4][4] = {};
  for (int k0 = 0; k0 < K; k0 += 16) {
    float4 a4 = *(const float4*)(Ap + k0);
    float4 b4 = *(const float4*)(Bp + (size_t)k0 * 1024);
    As[ak + 0][am] = a4.x; As[ak + 1][am] = a4.y;
    As[ak + 2][am] = a4.z; As[ak + 3][am] = a4.w;
    *(float4*)&Bs[bk][bn] = b4;
    __syncthreads();
#pragma unroll
    for (int k = 0; k < 16; ++k) {
      float4 bq = *(const float4*)&Bs[k][tx * 4];
#pragma unroll
      for (int i = 0; i < 4; ++i) {
        float av = As[k][ty * 4 + i];
        acc[i][0] += av * bq.x; acc[i][1] += av * bq.y;
        acc[i][2] += av * bq.z; acc[i][3] += av * bq.w;
      }
    }
    __syncthreads();
  }
#pragma unroll
  for (int i = 0; i < 4; ++i) {
    int row = m0 + ty * 4 + i;
#pragma unroll
    for (int j = 0; j < 4; ++j) {
      int col = n0 + tx * 4 + j;
      Cb[(size_t)row * 1024 + col] = acc[i][j];
    }
  }
}

// ---------------- fp32 tiled GEMM (NN) ----------------
template <int FLAGS>
__global__ __launch_bounds__(256) void gemm_nn(const float* __restrict__ A,
    const float* __restrict__ B, float* __restrict__ C, const float* __restrict__ bias,
    const float* __restrict__ res, int M, int N, int K) {
  constexpr bool HAS_BIAS = (FLAGS & 1) != 0;
  constexpr bool HAS_GELU = (FLAGS & 2) != 0;
  constexpr bool HAS_RES = (FLAGS & 4) != 0;
  __shared__ float As[16][68];
  __shared__ float Bs[16][68];
  int tid = threadIdx.x;
  int m0 = blockIdx.y * 64, n0 = blockIdx.x * 64;
  int tx = tid & 15, ty = tid >> 4;
  int am = tid >> 2, ak = (tid & 3) * 4;
  int bk = tid >> 4, bn = (tid & 15) * 4;
  const float* Ap = A + (size_t)(m0 + am) * K + ak;
  const float* Bp = B + (size_t)bk * N + n0 + bn;
  float acc[4][4] = {};
  for (int k0 = 0; k0 < K; k0 += 16) {
    float4 a4 = *(const float4*)(Ap + k0);
    float4 b4 = *(const float4*)(Bp + (size_t)k0 * N);
    As[ak + 0][am] = a4.x; As[ak + 1][am] = a4.y;
    As[ak + 2][am] = a4.z; As[ak + 3][am] = a4.w;
    *(float4*)&Bs[bk][bn] = b4;
    __syncthreads();
#pragma unroll
    for (int k = 0; k < 16; ++k) {
      float4 bq = *(const float4*)&Bs[k][tx * 4];
#pragma unroll
      for (int i = 0; i < 4; ++i) {
        float av = As[k][ty * 4 + i];
        acc[i][0] += av * bq.x; acc[i][1] += av * bq.y;
        acc[i][2] += av * bq.z; acc[i][3] += av * bq.w;
      }
    }
    __syncthreads();
  }
#pragma unroll
  for (int i = 0; i < 4; ++i) {
    int row = m0 + ty * 4 + i;
#pragma unroll
    for (int j = 0; j < 4; ++j) {
      int col = n0 + tx * 4 + j;
      float vv = acc[i][j];
      if (HAS_BIAS) vv += bias[col];
      if (HAS_GELU) vv = 0.5f * vv * (1.0f + erff(vv * 0.70710678118654752f));
      if (HAS_RES) vv += res[(size_t)row * N + col];
      C[(size_t)row * N + col] = vv;
    }
  }
}

// ---------------- fp32 tiled GEMM (NT, fallback logits) ----------------
template <int FLAGS>
__global__ __launch_bounds__(256) void gemm_nt(const float* __restrict__ A,
    const float* __restrict__ B, float* __restrict__ C, const float* __restrict__ bias,
    const float* __restrict__ res, int M, int N, int K) {
  constexpr bool HAS_BIAS = (FLAGS & 1) != 0;
  constexpr bool HAS_GELU = (FLAGS & 2) != 0;
  constexpr bool HAS_RES = (FLAGS & 4) != 0;
  __shared__ float As[16][68];
  __shared__ float Bs[16][68];
  int tid = threadIdx.x;
  int m0 = blockIdx.y * 64, n0 = blockIdx.x * 64;
  int tx = tid & 15, ty = tid >> 4;
  int am = tid >> 2, ak = (tid & 3) * 4;
  int bn2 = tid >> 2, bk2 = (tid & 3) * 4;
  const float* Ap = A + (size_t)(m0 + am) * K + ak;
  const float* Bp = B + (size_t)(n0 + bn2) * K + bk2;
  float acc[4][4] = {};
  for (int k0 = 0; k0 < K; k0 += 16) {
    float4 a4 = *(const float4*)(Ap + k0);
    float4 b4 = *(const float4*)(Bp + k0);
    As[ak + 0][am] = a4.x; As[ak + 1][am] = a4.y;
    As[ak + 2][am] = a4.z; As[ak + 3][am] = a4.w;
    Bs[bk2 + 0][bn2] = b4.x; Bs[bk2 + 1][bn2] = b4.y;
    Bs[bk2 + 2][bn2] = b4.z; Bs[bk2 + 3][bn2] = b4.w;
    __syncthreads();
#pragma unroll
    for (int k = 0; k < 16; ++k) {
      float4 bq = *(const float4*)&Bs[k][tx * 4];
#pragma unroll
      for (int i = 0; i < 4; ++i) {
        float av = As[k][ty * 4 + i];
        acc[i][0] += av * bq.x; acc[i][1] += av * bq.y;
        acc[i][2] += av * bq.z; acc[i][3] += av * bq.w;
      }
    }
    __syncthreads();
  }
#pragma unroll
  for (int i = 0; i < 4; ++i) {
    int row = m0 + ty * 4 + i;
#pragma unroll
    for (int j = 0; j < 4; ++j) {
      int col = n0 + tx * 4 + j;
      float vv = acc[i][j];
      if (HAS_BIAS) vv += bias[col];
      if (HAS_GELU) vv = 0.5f * vv * (1.0f + erff(vv * 0.70710678118654752f));
      if (HAS_RES) vv += res[(size_t)row * N + col];
      C[(size_t)row * N + col] = vv;
    }
  }
}

// ---------------- host orchestration ----------------
extern "C" void kernel_launch(void* const* d_in, const int* in_sizes, int n_in,
                              void* d_out, int out_size, void* d_ws, size_t ws_size,
                              hipStream_t stream) {
  const int* ids = (const int*)d_in[0];
  const float* Wemb = (const float*)d_in[1];
  const float* Wpos = (const float*)d_in[2];
  const float* ln1_g = (const float*)d_in[3];
  const float* ln1_b = (const float*)d_in[4];
  const float* Wq = (const float*)d_in[5];
  const float* Wk = (const float*)d_in[6];
  const float* Wv = (const float*)d_in[7];
  const float* Wo = (const float*)d_in[8];
  const float* ln2_g = (const float*)d_in[9];
  const float* ln2_b = (const float*)d_in[10];
  const float* W1 = (const float*)d_in[11];
  const float* b1 = (const float*)d_in[12];
  const float* W2 = (const float*)d_in[13];
  const float* b2 = (const float*)d_in[14];
  const float* lnf_g = (const float*)d_in[15];
  const float* lnf_b = (const float*)d_in[16];

  const int T = in_sizes[0];          // 2048
  const int D = D_MODEL;
  const int VOC = in_sizes[1] / D;    // 32000

  char* ws = (char*)d_ws;
  float* x = (float*)(ws);
  float* xn = (float*)(ws + 8388608ull);
  unsigned short* xnbh = (unsigned short*)(ws + 8388608ull);
  unsigned short* xnbl = (unsigned short*)(ws + 12582912ull);
  float* q = (float*)(ws + 16777216ull);
  float* k = (float*)(ws + 25165824ull);
  float* v = (float*)(ws + 33554432ull);
  float* kt = (float*)(ws + 41943040ull);
  unsigned short* w1th = (unsigned short*)(ws + 16777216ull);
  unsigned short* w1tl = (unsigned short*)(ws + 25165824ull);
  unsigned short* w2th = (unsigned short*)(ws + 33554432ull);
  unsigned short* w2tl = (unsigned short*)(ws + 41943040ull);
  unsigned short* hbh = (unsigned short*)(ws + 50331648ull);
  unsigned short* hbl = (unsigned short*)(ws + 67108864ull);
  unsigned short* woth = (unsigned short*)(ws + 83886080ull);
  unsigned short* wotl = (unsigned short*)(ws + 85983232ull);
  unsigned short* wembb = (unsigned short*)(ws + 16777216ull);
  const size_t NEED = 88080384ull;  // 84 MB

  int kkeep = (T < 64) ? T : 64;
  int fk = (HEAD_DIM * kkeep + T - 1) / T;
  if (fk < 1) fk = 1;
  int nseg = T * N_HEADS;

  embed_kernel<<<T, 256, 0, stream>>>(ids, Wemb, Wpos, x);

  if (ws_size >= NEED && (T % 128) == 0 && (VOC % 128) == 0 &&
      (size_t)VOC * D * 2 <= 67108864ull) {
    // ---- bf16 MFMA path ----
    for (int l = 0; l < 2; ++l) {
      const float* wq = Wq + (size_t)l * D * D;
      const float* wk = Wk + (size_t)l * D * D;
      const float* wv = Wv + (size_t)l * D * D;
      const float* wo = Wo + (size_t)l * D * D;

      ln_kernel<<<T, 256, 0, stream>>>(x, xn, nullptr, nullptr,
                                       ln1_g + (size_t)l * D, ln1_b + (size_t)l * D);

      gemm_nn_qkv<<<dim3(3 * D / 64, T / 64), 256, 0, stream>>>(xn, wq, wk, wv, q, T, D);

      sparsify_kernel<<<(3 * nseg + 3) / 4, 256, 0, stream>>>(q, 3 * nseg, fk);

      transpose_kernel<<<dim3(D / 32, T / 32), 256, 0, stream>>>(k, kt, T, D);

      attn_kernel<<<T * N_HEADS, 64, 0, stream>>>(q, kt, v, nullptr, xnbh, xnbl, T);

      transpose_conv_pair_kernel<<<dim3(D / 32, D / 32), 256, 0, stream>>>(wo, woth, wotl, D, D);
      gemm3_bt<4, 0><<<dim3(D / 128, T / 128), 256, 0, stream>>>(
          xnbh, xnbl, woth, wotl, x, nullptr, nullptr, nullptr, x, T, D, D);

      ln_kernel<<<T, 256, 0, stream>>>(x, nullptr, xnbh, xnbl,
                                       ln2_g + (size_t)l * D, ln2_b + (size_t)l * D);

      transpose_conv_pair_kernel<<<dim3(HIDDEN / 32, D / 32), 256, 0, stream>>>(
          W1 + (size_t)l * D * HIDDEN, w1th, w1tl, D, HIDDEN);
      gemm3_bt<3, 1><<<dim3(HIDDEN / 128, T / 128), 256, 0, stream>>>(
          xnbh, xnbl, w1th, w1tl, nullptr, hbh, hbl,
          b1 + (size_t)l * HIDDEN, nullptr, T, HIDDEN, D);
      transpose_conv_pair_kernel<<<dim3(D / 32, HIDDEN / 32), 256, 0, stream>>>(
          W2 + (size_t)l * HIDDEN * D, w2th, w2tl, HIDDEN, D);
      gemm3_bt<5, 0><<<dim3(D / 128, T / 128), 256, 0, stream>>>(
          hbh, hbl, w2th, w2tl, x, nullptr, nullptr,
          b2 + (size_t)l * D, x, T, D, HIDDEN);
    }

    ln_kernel<<<T, 256, 0, stream>>>(x, nullptr, xnbh, nullptr, lnf_g, lnf_b);

    conv_bf16_kernel<<<4096, 256, 0, stream>>>(Wemb, wembb, (size_t)VOC * D);

    gemm_bt_bf16<0, float><<<dim3(VOC / 128, T / 128), 256, 0, stream>>>(
        xnbh, wembb, (float*)d_out, nullptr, nullptr, T, VOC, D);
  } else {
    // ---- fp32 fallback ----
    float* hbuf = q;
    for (int l = 0; l < 2; ++l) {
      const float* wq = Wq + (size_t)l * D * D;
      const float* wk = Wk + (size_t)l * D * D;
      const float* wv = Wv + (size_t)l * D * D;
      const float* wo = Wo + (size_t)l * D * D;

      ln_kernel<<<T, 256, 0, stream>>>(x, xn, nullptr, nullptr,
                                       ln1_g + (size_t)l * D, ln1_b + (size_t)l * D);

      dim3 g1(D / 64, T / 64);
      gemm_nn<0><<<g1, 256, 0, stream>>>(xn, wq, q, nullptr, nullptr, T, D, D);
      gemm_nn<0><<<g1, 256, 0, stream>>>(xn, wk, k, nullptr, nullptr, T, D, D);
      gemm_nn<0><<<g1, 256, 0, stream>>>(xn, wv, v, nullptr, nullptr, T, D, D);

      sparsify_kernel<<<(nseg + 3) / 4, 256, 0, stream>>>(q, nseg, fk);
      sparsify_kernel<<<(nseg + 3) / 4, 256, 0, stream>>>(k, nseg, fk);
      sparsify_kernel<<<(nseg + 3) / 4, 256, 0, stream>>>(v, nseg, fk);

      transpose_kernel<<<dim3(D / 32, T / 32), 256, 0, stream>>>(k, kt, T, D);

      attn_kernel<<<T * N_HEADS, 64, 0, stream>>>(q, kt, v, xn, nullptr, nullptr, T);

      gemm_nn<4><<<g1, 256, 0, stream>>>(xn, wo, x, nullptr, x, T, D, D);

      ln_kernel<<<T, 256, 0, stream>>>(x, xn, nullptr, nullptr,
                                       ln2_g + (size_t)l * D, ln2_b + (size_t)l * D);

      gemm_nn<3><<<dim3(HIDDEN / 64, T / 64), 256, 0, stream>>>(
          xn, W1 + (size_t)l * D * HIDDEN, hbuf, b1 + (size_t)l * HIDDEN, nullptr, T, HIDDEN, D);
      gemm_nn<5><<<g1, 256, 0, stream>>>(
          hbuf, W2 + (size_t)l * HIDDEN * D, x, b2 + (size_t)l * D, x, T, D, HIDDEN);
    }

    ln_kernel<<<T, 256, 0, stream>>>(x, xn, nullptr, nullptr, lnf_g, lnf_b);

    gemm_nt<0><<<dim3(VOC / 64, T / 64), 256, 0, stream>>>(
        xn, Wemb, (float*)d_out, nullptr, nullptr, T, VOC, D);
  }
}

// Round 8
// 1835.288 us; speedup vs baseline: 1.0752x; 1.0752x over previous
//
#include <hip/hip_runtime.h>
#include <math.h>

#define D_MODEL 1024
#define N_HEADS 16
#define HEAD_DIM 64
#define HIDDEN 4096
#define TMAX 2048

typedef __attribute__((ext_vector_type(8))) short s16x8;
typedef __attribute__((ext_vector_type(4))) float f32x4;

// ---------------- wave helpers (wave64) ----------------
__device__ __forceinline__ float wave_max_f(float v) {
#pragma unroll
  for (int o = 32; o > 0; o >>= 1) v = fmaxf(v, __shfl_xor(v, o));
  return v;
}
__device__ __forceinline__ float wave_sum_f(float v) {
#pragma unroll
  for (int o = 32; o > 0; o >>= 1) v += __shfl_xor(v, o);
  return v;
}
__device__ __forceinline__ unsigned long long wave_max_u64(unsigned long long k) {
#pragma unroll
  for (int o = 32; o > 0; o >>= 1) {
    unsigned long long u = __shfl_xor(k, o);
    if (u > k) k = u;
  }
  return k;
}
__device__ __forceinline__ unsigned ford(float v) {
  unsigned u = __float_as_uint(v);
  return (u & 0x80000000u) ? ~u : (u | 0x80000000u);
}
// fp32 -> bf16 RNE
__device__ __forceinline__ unsigned short f2bf(float f) {
  unsigned u = __float_as_uint(f);
  u += 0x7FFFu + ((u >> 16) & 1u);
  return (unsigned short)(u >> 16);
}
__device__ __forceinline__ float bf2f(unsigned short h) {
  return __uint_as_float((unsigned)h << 16);
}

__device__ __forceinline__ void gload_lds16(const void* g, void* l) {
  __builtin_amdgcn_global_load_lds(
      (const __attribute__((address_space(1))) void*)g,
      (__attribute__((address_space(3))) void*)l, 16, 0, 0);
}

// ---------------- embedding ----------------
__global__ __launch_bounds__(256) void embed_kernel(const int* __restrict__ ids,
    const float* __restrict__ Wemb, const float* __restrict__ Wpos, float* __restrict__ X) {
  int t = blockIdx.x, tid = threadIdx.x;
  int id = ids[t];
  float4 e = ((const float4*)(Wemb + (size_t)id * D_MODEL))[tid];
  float4 p = ((const float4*)(Wpos + (size_t)t * D_MODEL))[tid];
  e.x += p.x; e.y += p.y; e.z += p.z; e.w += p.w;
  ((float4*)(X + (size_t)t * D_MODEL))[tid] = e;
}

// ---------------- layernorm; optional fp32 out + bf16 hi/lo out ----------------
__global__ __launch_bounds__(256) void ln_kernel(const float* __restrict__ X,
    float* __restrict__ Y, unsigned short* __restrict__ Ybh, unsigned short* __restrict__ Ybl,
    const float* __restrict__ g, const float* __restrict__ b) {
  int row = blockIdx.x, tid = threadIdx.x;
  int lane = tid & 63, wid = tid >> 6;
  __shared__ float red[8];
  float4 v = ((const float4*)(X + (size_t)row * D_MODEL))[tid];
  float s = v.x + v.y + v.z + v.w;
  s = wave_sum_f(s);
  if (lane == 0) red[wid] = s;
  __syncthreads();
  float mean = (red[0] + red[1] + red[2] + red[3]) * (1.0f / D_MODEL);
  float dx = v.x - mean, dy = v.y - mean, dz = v.z - mean, dw = v.w - mean;
  float q = dx * dx + dy * dy + dz * dz + dw * dw;
  q = wave_sum_f(q);
  if (lane == 0) red[4 + wid] = q;
  __syncthreads();
  float var = (red[4] + red[5] + red[6] + red[7]) * (1.0f / D_MODEL);
  float rs = rsqrtf(var + 1e-5f);
  float4 gg = ((const float4*)g)[tid], bb = ((const float4*)b)[tid];
  float4 y;
  y.x = dx * rs * gg.x + bb.x;
  y.y = dy * rs * gg.y + bb.y;
  y.z = dz * rs * gg.z + bb.z;
  y.w = dw * rs * gg.w + bb.w;
  if (Y) ((float4*)(Y + (size_t)row * D_MODEL))[tid] = y;
  if (Ybh) {
    ushort4 oh;
    oh.x = f2bf(y.x); oh.y = f2bf(y.y); oh.z = f2bf(y.z); oh.w = f2bf(y.w);
    ((ushort4*)(Ybh + (size_t)row * D_MODEL))[tid] = oh;
    if (Ybl) {
      ushort4 ol;
      ol.x = f2bf(y.x - bf2f(oh.x)); ol.y = f2bf(y.y - bf2f(oh.y));
      ol.z = f2bf(y.z - bf2f(oh.z)); ol.w = f2bf(y.w - bf2f(oh.w));
      ((ushort4*)(Ybl + (size_t)row * D_MODEL))[tid] = ol;
    }
  }
}

// ---------------- sparsify (exact top-fk by |value| per 64 segment) ----------------
__global__ __launch_bounds__(256) void sparsify_kernel(float* __restrict__ X, int nseg, int fk) {
  int seg = blockIdx.x * 4 + (threadIdx.x >> 6);
  if (seg >= nseg) return;
  int lane = threadIdx.x & 63;
  size_t idx = (size_t)seg * 64 + lane;
  float x = X[idx];
  float a = fabsf(x);
  float cur = INFINITY;
  int remaining = fk;
  float thr = 0.0f;
  for (;;) {
    float cand = (a < cur) ? a : -INFINITY;
    float mv = wave_max_f(cand);
    if (mv == -INFINITY) { thr = mv; break; }
    int c = __popcll(__ballot(a == mv));
    if (c >= remaining) { thr = mv; break; }
    remaining -= c; cur = mv;
  }
  if (!(a >= thr)) X[idx] = 0.0f;
}

// ---------------- transpose fp32 [R][C] -> [C][R] ----------------
__global__ __launch_bounds__(256) void transpose_kernel(const float* __restrict__ in,
    float* __restrict__ out, int R, int Cc) {
  __shared__ float tile[32][33];
  int c0 = blockIdx.x * 32, r0 = blockIdx.y * 32;
  int tx = threadIdx.x & 31, ty = threadIdx.x >> 5;
  for (int i = ty; i < 32; i += 8)
    tile[i][tx] = in[(size_t)(r0 + i) * Cc + c0 + tx];
  __syncthreads();
  for (int i = ty; i < 32; i += 8)
    out[(size_t)(c0 + i) * R + r0 + tx] = tile[tx][i];
}

// ---------------- transpose-convert fp32 [R][C] -> bf16 hi/lo [C][R] ----------------
__global__ __launch_bounds__(256) void transpose_conv_pair_kernel(const float* __restrict__ in,
    unsigned short* __restrict__ oh, unsigned short* __restrict__ ol, int R, int Cc) {
  __shared__ float tile[32][33];
  int c0 = blockIdx.x * 32, r0 = blockIdx.y * 32;
  int tx = threadIdx.x & 31, ty = threadIdx.x >> 5;
  for (int i = ty; i < 32; i += 8)
    tile[i][tx] = in[(size_t)(r0 + i) * Cc + c0 + tx];
  __syncthreads();
  for (int i = ty; i < 32; i += 8) {
    float v = tile[tx][i];
    unsigned short h = f2bf(v);
    size_t idx = (size_t)(c0 + i) * R + r0 + tx;
    oh[idx] = h;
    ol[idx] = f2bf(v - bf2f(h));
  }
}

// ---------------- fp32 -> bf16 elementwise ----------------
__global__ __launch_bounds__(256) void conv_bf16_kernel(const float* __restrict__ in,
    unsigned short* __restrict__ out, size_t n) {
  size_t i = ((size_t)blockIdx.x * 256 + threadIdx.x) * 4;
  size_t stride = (size_t)gridDim.x * 1024;
  for (; i < n; i += stride) {
    float4 v = *(const float4*)(in + i);
    ushort4 o;
    o.x = f2bf(v.x); o.y = f2bf(v.y); o.z = f2bf(v.z); o.w = f2bf(v.w);
    *(ushort4*)(out + i) = o;
  }
}

// ---------------- attention: one wave per (head, query-row)  [r4: 380 us] ----------------
// exact: scores=q@k^T/8 causal; stable top-64 (val desc, idx asc); softmax; @v
__global__ __launch_bounds__(64) void attn_kernel(const float* __restrict__ Q,
    const float* __restrict__ Kt, const float* __restrict__ V,
    float* __restrict__ Of, unsigned short* __restrict__ Oh, unsigned short* __restrict__ Ol,
    int T) {
  int t = blockIdx.x % T;
  int h = blockIdx.x / T;
  int lane = threadIdx.x;
  unsigned long long lmlt = (1ull << lane) - 1ull;

  __shared__ float sc[TMAX];
  __shared__ float qval[HEAD_DIM];
  __shared__ int qdim[HEAD_DIM];
  constexpr int PCAP = 320;
  __shared__ float posv[PCAP];
  __shared__ int posi[PCAP];
  __shared__ int seli[64];
  __shared__ float selv[64];
  __shared__ float wsel[64];

  float qv = Q[(size_t)t * D_MODEL + h * HEAD_DIM + lane];
  unsigned long long nzm = __ballot(qv != 0.0f);
  int nq = __popcll(nzm);
  if (qv != 0.0f) {
    int p = __popcll(nzm & lmlt);
    qval[p] = qv; qdim[p] = lane;
  }
  __syncthreads();

  int Vn = t + 1;
  for (int s = lane; s < Vn; s += 64) {
    float acc = 0.0f;
    for (int j = 0; j < nq; ++j)
      acc += qval[j] * Kt[(size_t)(h * HEAD_DIM + qdim[j]) * T + s];
    sc[s] = acc * 0.125f;
  }
  __syncthreads();

  int nsel = 0;
  if (Vn <= 64) {
    nsel = Vn;
    if (lane < Vn) { seli[lane] = lane; selv[lane] = sc[lane]; }
    __syncthreads();
  } else {
    // compact positive scores (list index order == s order)
    int base = 0;
    for (int s0 = 0; s0 < Vn; s0 += 64) {
      int s = s0 + lane;
      float v = (s < Vn) ? sc[s] : -1.0f;
      unsigned long long pm = __ballot(v > 0.0f);
      if (v > 0.0f) {
        int p = base + __popcll(pm & lmlt);
        if (p < PCAP) { posv[p] = v; posi[p] = s; }
      }
      base += __popcll(pm);
    }
    int P = base;
    __syncthreads();

    bool fullpath = false;
    if (P >= 64) {
      if (P <= 128) {
        // ---- bitonic-128 top-64: key = (ford(v)<<32) | (0xFFFFFFFF - idx) ----
        unsigned long long key0, key1;
        {
          int e0 = lane, e1 = lane + 64;
          key0 = (e0 < P) ? (((unsigned long long)ford(posv[e0]) << 32) |
                             (unsigned long long)(0xFFFFFFFFu - (unsigned)e0)) : 0ull;
          key1 = (e1 < P) ? (((unsigned long long)ford(posv[e1]) << 32) |
                             (unsigned long long)(0xFFFFFFFFu - (unsigned)e1)) : 0ull;
        }
        for (int k = 2; k <= 128; k <<= 1) {
          for (int j = k >> 1; j > 0; j >>= 1) {
            if (j == 64) {
              if (key0 < key1) { unsigned long long tm = key0; key0 = key1; key1 = tm; }
            } else {
              bool iLower = (lane & j) == 0;
              {
                unsigned long long prt = __shfl_xor(key0, j);
                bool desc = ((lane & k) == 0);
                bool keepMax = (iLower == desc);
                key0 = keepMax ? (key0 > prt ? key0 : prt) : (key0 < prt ? key0 : prt);
              }
              {
                unsigned long long prt = __shfl_xor(key1, j);
                int e1 = lane + 64;
                bool desc = ((e1 & k) == 0);
                bool keepMax = (iLower == desc);
                key1 = keepMax ? (key1 > prt ? key1 : prt) : (key1 < prt ? key1 : prt);
              }
            }
          }
        }
        int e = (int)(0xFFFFFFFFu - (unsigned)(key0 & 0xFFFFFFFFull));
        seli[lane] = posi[e];
        selv[lane] = posv[e];
        nsel = 64;
        __syncthreads();
      } else if (P <= PCAP) {
        for (int r = 0; r < 64; ++r) {
          unsigned long long best = 0ull;
          for (int j = lane; j < P; j += 64) {
            float v = posv[j];
            if (v > 0.0f) {
              unsigned long long key =
                  ((unsigned long long)ford(v) << 32) | (unsigned)(0xFFFFFFFFu - (unsigned)j);
              if (key > best) best = key;
            }
          }
          best = wave_max_u64(best);
          int j = (int)(0xFFFFFFFFu - (unsigned)(best & 0xFFFFFFFFull));
          if (lane == (j & 63)) {
            seli[r] = posi[j]; selv[r] = posv[j]; posv[j] = -INFINITY;
          }
          __syncthreads();
        }
        nsel = 64;
      } else {
        fullpath = true;
      }
    } else {
      if (lane < P) { seli[lane] = posi[lane]; selv[lane] = posv[lane]; }
      int need = 64 - P;
      int zbase = 0;
      bool done = false;
      for (int s0 = 0; s0 < Vn && !done; s0 += 64) {
        int s = s0 + lane;
        bool isz = (s < Vn) && (sc[s] == 0.0f);
        unsigned long long zm = __ballot(isz);
        int pre = __popcll(zm & lmlt);
        if (isz && (zbase + pre) < need) {
          seli[P + zbase + pre] = s;
          selv[P + zbase + pre] = 0.0f;
        }
        zbase += __popcll(zm);
        if (zbase >= need) done = true;
      }
      if (zbase >= need) {
        nsel = 64;
        __syncthreads();
      } else {
        fullpath = true;
      }
    }

    if (fullpath) {
      __syncthreads();
      nsel = 64;
      for (int r = 0; r < 64; ++r) {
        unsigned long long best = 0ull;
        for (int s = lane; s < Vn; s += 64) {
          float v = sc[s];
          if (v != -INFINITY) {
            unsigned long long key =
                ((unsigned long long)ford(v) << 32) | (unsigned)(0x7FFFFFFFu - (unsigned)s);
            if (key > best) best = key;
          }
        }
        best = wave_max_u64(best);
        if (best == 0ull) { nsel = r; break; }
        int s = (int)(0x7FFFFFFFu - (unsigned)(best & 0xFFFFFFFFull));
        if (lane == (s & 63)) {
          seli[r] = s; selv[r] = sc[s]; sc[s] = -INFINITY;
        }
        __syncthreads();
      }
    }
  }

  float v = (lane < nsel) ? selv[lane] : -INFINITY;
  float m = wave_max_f(v);
  float w = (lane < nsel) ? expf(v - m) : 0.0f;
  float ds = wave_sum_f(w);
  wsel[lane] = w / ds;
  __syncthreads();
  float o = 0.0f;
  for (int r = 0; r < nsel; ++r)
    o += wsel[r] * V[(size_t)seli[r] * D_MODEL + h * HEAD_DIM + lane];
  size_t oidx = (size_t)t * D_MODEL + h * HEAD_DIM + lane;
  if (Of) Of[oidx] = o;
  if (Oh) {
    unsigned short hh = f2bf(o);
    Oh[oidx] = hh;
    Ol[oidx] = f2bf(o - bf2f(hh));
  }
}

// ============ single bf16 MFMA GEMM (NT): C[M,N] = A @ B^T ============
template <int FLAGS, typename CT>
__global__ __launch_bounds__(256) void gemm_bt_bf16(const unsigned short* __restrict__ A,
    const unsigned short* __restrict__ B, CT* __restrict__ C,
    const float* __restrict__ bias, const float* __restrict__ res, int M, int N, int K) {
  constexpr bool HAS_BIAS = (FLAGS & 1) != 0;
  constexpr bool HAS_GELU = (FLAGS & 2) != 0;
  constexpr bool HAS_RES = (FLAGS & 4) != 0;
  __shared__ unsigned short As[128 * 32];
  __shared__ unsigned short Bs[128 * 32];
  int tid = threadIdx.x;
  int lane = tid & 63, wid = tid >> 6;
  int wr = wid >> 1, wc = wid & 1;
  int m0 = blockIdx.y * 128, n0 = blockIdx.x * 128;

  int r_in = lane >> 2;
  int slot = lane & 3;

  f32x4 acc[4][4] = {};

  int fr = lane & 15;
  int ksl = lane >> 4;

  for (int k0 = 0; k0 < K; k0 += 32) {
#pragma unroll
    for (int s = 0; s < 2; ++s) {
      int row = wid * 32 + s * 16 + r_in;
      int ksw = (slot ^ ((row >> 1) & 3)) * 8;
      const unsigned short* ga = A + (size_t)(m0 + row) * K + k0 + ksw;
      const unsigned short* gb = B + (size_t)(n0 + row) * K + k0 + ksw;
      gload_lds16(ga, &As[(wid * 32 + s * 16) * 32]);
      gload_lds16(gb, &Bs[(wid * 32 + s * 16) * 32]);
    }
    asm volatile("s_waitcnt vmcnt(0)" ::: "memory");
    __syncthreads();

    s16x8 av[4], bv[4];
#pragma unroll
    for (int mi = 0; mi < 4; ++mi) {
      int ar = wr * 64 + mi * 16 + fr;
      av[mi] = *(const s16x8*)&As[ar * 32 + ((ksl ^ ((ar >> 1) & 3)) * 8)];
    }
#pragma unroll
    for (int ni = 0; ni < 4; ++ni) {
      int br = wc * 64 + ni * 16 + fr;
      bv[ni] = *(const s16x8*)&Bs[br * 32 + ((ksl ^ ((br >> 1) & 3)) * 8)];
    }
#pragma unroll
    for (int mi = 0; mi < 4; ++mi)
#pragma unroll
      for (int ni = 0; ni < 4; ++ni)
        acc[mi][ni] = __builtin_amdgcn_mfma_f32_16x16x32_bf16(av[mi], bv[ni], acc[mi][ni], 0, 0, 0);
    __syncthreads();
  }

  int cr = lane >> 4, cc = lane & 15;
#pragma unroll
  for (int mi = 0; mi < 4; ++mi) {
#pragma unroll
    for (int j = 0; j < 4; ++j) {
      int row = m0 + wr * 64 + mi * 16 + cr * 4 + j;
#pragma unroll
      for (int ni = 0; ni < 4; ++ni) {
        int col = n0 + wc * 64 + ni * 16 + cc;
        float vv = acc[mi][ni][j];
        if (HAS_BIAS) vv += bias[col];
        if (HAS_GELU) vv = 0.5f * vv * (1.0f + erff(vv * 0.70710678118654752f));
        if (HAS_RES) vv += res[(size_t)row * N + col];
        if constexpr (sizeof(CT) == 2)
          C[(size_t)row * N + col] = (CT)f2bf(vv);
        else
          C[(size_t)row * N + col] = (CT)vv;
      }
    }
  }
}

// ============ bf16x3 split-precision MFMA GEMM (NT) ============
template <int FLAGS, int OUTMODE>
__global__ __launch_bounds__(256) void gemm3_bt(
    const unsigned short* __restrict__ Ah, const unsigned short* __restrict__ Al,
    const unsigned short* __restrict__ Bh, const unsigned short* __restrict__ Bl,
    float* __restrict__ Cf, unsigned short* __restrict__ Ch, unsigned short* __restrict__ Cl,
    const float* __restrict__ bias, const float* __restrict__ res, int M, int N, int K) {
  constexpr bool HAS_BIAS = (FLAGS & 1) != 0;
  constexpr bool HAS_GELU = (FLAGS & 2) != 0;
  constexpr bool HAS_RES = (FLAGS & 4) != 0;
  __shared__ unsigned short As[2][128 * 32];
  __shared__ unsigned short Bs[2][128 * 32];
  int tid = threadIdx.x;
  int lane = tid & 63, wid = tid >> 6;
  int wr = wid >> 1, wc = wid & 1;
  int m0 = blockIdx.y * 128, n0 = blockIdx.x * 128;

  int r_in = lane >> 2;
  int slot = lane & 3;

  f32x4 acc[4][4] = {};

  int fr = lane & 15;
  int ksl = lane >> 4;

  for (int k0 = 0; k0 < K; k0 += 32) {
#pragma unroll
    for (int s = 0; s < 2; ++s) {
      int row = wid * 32 + s * 16 + r_in;
      int ksw = (slot ^ ((row >> 1) & 3)) * 8;
      size_t ao = (size_t)(m0 + row) * K + k0 + ksw;
      size_t bo = (size_t)(n0 + row) * K + k0 + ksw;
      int ldst = (wid * 32 + s * 16) * 32;
      gload_lds16(Ah + ao, &As[0][ldst]);
      gload_lds16(Al + ao, &As[1][ldst]);
      gload_lds16(Bh + bo, &Bs[0][ldst]);
      gload_lds16(Bl + bo, &Bs[1][ldst]);
    }
    asm volatile("s_waitcnt vmcnt(0)" ::: "memory");
    __syncthreads();

    s16x8 avh[4], avl[4], bvh[4], bvl[4];
#pragma unroll
    for (int mi = 0; mi < 4; ++mi) {
      int ar = wr * 64 + mi * 16 + fr;
      int off = ar * 32 + ((ksl ^ ((ar >> 1) & 3)) * 8);
      avh[mi] = *(const s16x8*)&As[0][off];
      avl[mi] = *(const s16x8*)&As[1][off];
    }
#pragma unroll
    for (int ni = 0; ni < 4; ++ni) {
      int br = wc * 64 + ni * 16 + fr;
      int off = br * 32 + ((ksl ^ ((br >> 1) & 3)) * 8);
      bvh[ni] = *(const s16x8*)&Bs[0][off];
      bvl[ni] = *(const s16x8*)&Bs[1][off];
    }
#pragma unroll
    for (int mi = 0; mi < 4; ++mi)
#pragma unroll
      for (int ni = 0; ni < 4; ++ni) {
        acc[mi][ni] = __builtin_amdgcn_mfma_f32_16x16x32_bf16(avh[mi], bvh[ni], acc[mi][ni], 0, 0, 0);
        acc[mi][ni] = __builtin_amdgcn_mfma_f32_16x16x32_bf16(avl[mi], bvh[ni], acc[mi][ni], 0, 0, 0);
        acc[mi][ni] = __builtin_amdgcn_mfma_f32_16x16x32_bf16(avh[mi], bvl[ni], acc[mi][ni], 0, 0, 0);
      }
    __syncthreads();
  }

  int cr = lane >> 4, cc = lane & 15;
#pragma unroll
  for (int mi = 0; mi < 4; ++mi) {
#pragma unroll
    for (int j = 0; j < 4; ++j) {
      int row = m0 + wr * 64 + mi * 16 + cr * 4 + j;
#pragma unroll
      for (int ni = 0; ni < 4; ++ni) {
        int col = n0 + wc * 64 + ni * 16 + cc;
        float vv = acc[mi][ni][j];
        if (HAS_BIAS) vv += bias[col];
        if (HAS_GELU) vv = 0.5f * vv * (1.0f + erff(vv * 0.70710678118654752f));
        if (HAS_RES) vv += res[(size_t)row * N + col];
        if constexpr (OUTMODE == 0) {
          Cf[(size_t)row * N + col] = vv;
        } else {
          unsigned short h = f2bf(vv);
          Ch[(size_t)row * N + col] = h;
          Cl[(size_t)row * N + col] = f2bf(vv - bf2f(h));
        }
      }
    }
  }
}

// ---------------- fp32 fused QKV GEMM (NN), 128x128 tile, 8x8 utile ----------------
// [q|k|v] = xn @ [Wq|Wk|Wv]; per-output k-accumulation order identical to the
// 64-tile version (sequential k) -> bit-identical results.
__global__ __launch_bounds__(256) void gemm_nn_qkv128(const float* __restrict__ A,
    const float* __restrict__ Bq, const float* __restrict__ Bk, const float* __restrict__ Bv,
    float* __restrict__ C, int M, int K) {
  __shared__ float As[16][132];
  __shared__ float Bs[16][132];
  int tid = threadIdx.x;
  int m0 = blockIdx.y * 128;
  int n0g = blockIdx.x * 128;
  const float* B = (n0g < 1024) ? Bq : (n0g < 2048 ? Bk : Bv);
  float* Cb = C + (size_t)(n0g >> 10) * ((size_t)M * 1024);
  int n0 = n0g & 1023;
  int tx = tid & 15, ty = tid >> 4;
  int am = tid >> 1;          // 0..127 (2 threads per A row)
  int ak = (tid & 1) * 8;     // 0 or 8
  int bk = tid >> 4;          // 0..15
  int bn = (tid & 15) * 8;    // 0..120
  const float* Ap = A + (size_t)(m0 + am) * K + ak;
  const float* Bp = B + (size_t)bk * 1024 + n0 + bn;
  float acc[8][8] = {};
  for (int k0 = 0; k0 < K; k0 += 16) {
    float4 a0 = *(const float4*)(Ap + k0);
    float4 a1 = *(const float4*)(Ap + k0 + 4);
    float4 b0 = *(const float4*)(Bp + (size_t)k0 * 1024);
    float4 b1 = *(const float4*)(Bp + (size_t)k0 * 1024 + 4);
    As[ak + 0][am] = a0.x; As[ak + 1][am] = a0.y;
    As[ak + 2][am] = a0.z; As[ak + 3][am] = a0.w;
    As[ak + 4][am] = a1.x; As[ak + 5][am] = a1.y;
    As[ak + 6][am] = a1.z; As[ak + 7][am] = a1.w;
    *(float4*)&Bs[bk][bn] = b0;
    *(float4*)&Bs[bk][bn + 4] = b1;
    __syncthreads();
#pragma unroll
    for (int k = 0; k < 16; ++k) {
      float a8[8], b8[8];
      *(float4*)&a8[0] = *(const float4*)&As[k][ty * 8];
      *(float4*)&a8[4] = *(const float4*)&As[k][ty * 8 + 4];
      *(float4*)&b8[0] = *(const float4*)&Bs[k][tx * 8];
      *(float4*)&b8[4] = *(const float4*)&Bs[k][tx * 8 + 4];
#pragma unroll
      for (int i = 0; i < 8; ++i)
#pragma unroll
        for (int j = 0; j < 8; ++j)
          acc[i][j] = fmaf(a8[i], b8[j], acc[i][j]);
    }
    __syncthreads();
  }
#pragma unroll
  for (int i = 0; i < 8; ++i) {
    int row = m0 + ty * 8 + i;
#pragma unroll
    for (int j = 0; j < 8; ++j)
      Cb[(size_t)row * 1024 + n0 + tx * 8 + j] = acc[i][j];
  }
}

// ---------------- fp32 tiled GEMM (NN) ----------------
template <int FLAGS>
__global__ __launch_bounds__(256) void gemm_nn(const float* __restrict__ A,
    const float* __restrict__ B, float* __restrict__ C, const float* __restrict__ bias,
    const float* __restrict__ res, int M, int N, int K) {
  constexpr bool HAS_BIAS = (FLAGS & 1) != 0;
  constexpr bool HAS_GELU = (FLAGS & 2) != 0;
  constexpr bool HAS_RES = (FLAGS & 4) != 0;
  __shared__ float As[16][68];
  __shared__ float Bs[16][68];
  int tid = threadIdx.x;
  int m0 = blockIdx.y * 64, n0 = blockIdx.x * 64;
  int tx = tid & 15, ty = tid >> 4;
  int am = tid >> 2, ak = (tid & 3) * 4;
  int bk = tid >> 4, bn = (tid & 15) * 4;
  const float* Ap = A + (size_t)(m0 + am) * K + ak;
  const float* Bp = B + (size_t)bk * N + n0 + bn;
  float acc[4][4] = {};
  for (int k0 = 0; k0 < K; k0 += 16) {
    float4 a4 = *(const float4*)(Ap + k0);
    float4 b4 = *(const float4*)(Bp + (size_t)k0 * N);
    As[ak + 0][am] = a4.x; As[ak + 1][am] = a4.y;
    As[ak + 2][am] = a4.z; As[ak + 3][am] = a4.w;
    *(float4*)&Bs[bk][bn] = b4;
    __syncthreads();
#pragma unroll
    for (int k = 0; k < 16; ++k) {
      float4 bq = *(const float4*)&Bs[k][tx * 4];
#pragma unroll
      for (int i = 0; i < 4; ++i) {
        float av = As[k][ty * 4 + i];
        acc[i][0] += av * bq.x; acc[i][1] += av * bq.y;
        acc[i][2] += av * bq.z; acc[i][3] += av * bq.w;
      }
    }
    __syncthreads();
  }
#pragma unroll
  for (int i = 0; i < 4; ++i) {
    int row = m0 + ty * 4 + i;
#pragma unroll
    for (int j = 0; j < 4; ++j) {
      int col = n0 + tx * 4 + j;
      float vv = acc[i][j];
      if (HAS_BIAS) vv += bias[col];
      if (HAS_GELU) vv = 0.5f * vv * (1.0f + erff(vv * 0.70710678118654752f));
      if (HAS_RES) vv += res[(size_t)row * N + col];
      C[(size_t)row * N + col] = vv;
    }
  }
}

// ---------------- fp32 tiled GEMM (NT, fallback logits) ----------------
template <int FLAGS>
__global__ __launch_bounds__(256) void gemm_nt(const float* __restrict__ A,
    const float* __restrict__ B, float* __restrict__ C, const float* __restrict__ bias,
    const float* __restrict__ res, int M, int N, int K) {
  constexpr bool HAS_BIAS = (FLAGS & 1) != 0;
  constexpr bool HAS_GELU = (FLAGS & 2) != 0;
  constexpr bool HAS_RES = (FLAGS & 4) != 0;
  __shared__ float As[16][68];
  __shared__ float Bs[16][68];
  int tid = threadIdx.x;
  int m0 = blockIdx.y * 64, n0 = blockIdx.x * 64;
  int tx = tid & 15, ty = tid >> 4;
  int am = tid >> 2, ak = (tid & 3) * 4;
  int bn2 = tid >> 2, bk2 = (tid & 3) * 4;
  const float* Ap = A + (size_t)(m0 + am) * K + ak;
  const float* Bp = B + (size_t)(n0 + bn2) * K + bk2;
  float acc[4][4] = {};
  for (int k0 = 0; k0 < K; k0 += 16) {
    float4 a4 = *(const float4*)(Ap + k0);
    float4 b4 = *(const float4*)(Bp + k0);
    As[ak + 0][am] = a4.x; As[ak + 1][am] = a4.y;
    As[ak + 2][am] = a4.z; As[ak + 3][am] = a4.w;
    Bs[bk2 + 0][bn2] = b4.x; Bs[bk2 + 1][bn2] = b4.y;
    Bs[bk2 + 2][bn2] = b4.z; Bs[bk2 + 3][bn2] = b4.w;
    __syncthreads();
#pragma unroll
    for (int k = 0; k < 16; ++k) {
      float4 bq = *(const float4*)&Bs[k][tx * 4];
#pragma unroll
      for (int i = 0; i < 4; ++i) {
        float av = As[k][ty * 4 + i];
        acc[i][0] += av * bq.x; acc[i][1] += av * bq.y;
        acc[i][2] += av * bq.z; acc[i][3] += av * bq.w;
      }
    }
    __syncthreads();
  }
#pragma unroll
  for (int i = 0; i < 4; ++i) {
    int row = m0 + ty * 4 + i;
#pragma unroll
    for (int j = 0; j < 4; ++j) {
      int col = n0 + tx * 4 + j;
      float vv = acc[i][j];
      if (HAS_BIAS) vv += bias[col];
      if (HAS_GELU) vv = 0.5f * vv * (1.0f + erff(vv * 0.70710678118654752f));
      if (HAS_RES) vv += res[(size_t)row * N + col];
      C[(size_t)row * N + col] = vv;
    }
  }
}

// ---------------- host orchestration ----------------
extern "C" void kernel_launch(void* const* d_in, const int* in_sizes, int n_in,
                              void* d_out, int out_size, void* d_ws, size_t ws_size,
                              hipStream_t stream) {
  const int* ids = (const int*)d_in[0];
  const float* Wemb = (const float*)d_in[1];
  const float* Wpos = (const float*)d_in[2];
  const float* ln1_g = (const float*)d_in[3];
  const float* ln1_b = (const float*)d_in[4];
  const float* Wq = (const float*)d_in[5];
  const float* Wk = (const float*)d_in[6];
  const float* Wv = (const float*)d_in[7];
  const float* Wo = (const float*)d_in[8];
  const float* ln2_g = (const float*)d_in[9];
  const float* ln2_b = (const float*)d_in[10];
  const float* W1 = (const float*)d_in[11];
  const float* b1 = (const float*)d_in[12];
  const float* W2 = (const float*)d_in[13];
  const float* b2 = (const float*)d_in[14];
  const float* lnf_g = (const float*)d_in[15];
  const float* lnf_b = (const float*)d_in[16];

  const int T = in_sizes[0];          // 2048
  const int D = D_MODEL;
  const int VOC = in_sizes[1] / D;    // 32000

  char* ws = (char*)d_ws;
  float* x = (float*)(ws);
  float* xn = (float*)(ws + 8388608ull);
  unsigned short* xnbh = (unsigned short*)(ws + 8388608ull);
  unsigned short* xnbl = (unsigned short*)(ws + 12582912ull);
  float* q = (float*)(ws + 16777216ull);
  float* k = (float*)(ws + 25165824ull);
  float* v = (float*)(ws + 33554432ull);
  float* kt = (float*)(ws + 41943040ull);
  unsigned short* w1th = (unsigned short*)(ws + 16777216ull);
  unsigned short* w1tl = (unsigned short*)(ws + 25165824ull);
  unsigned short* w2th = (unsigned short*)(ws + 33554432ull);
  unsigned short* w2tl = (unsigned short*)(ws + 41943040ull);
  unsigned short* hbh = (unsigned short*)(ws + 50331648ull);
  unsigned short* hbl = (unsigned short*)(ws + 67108864ull);
  unsigned short* woth = (unsigned short*)(ws + 83886080ull);
  unsigned short* wotl = (unsigned short*)(ws + 85983232ull);
  unsigned short* wembb = (unsigned short*)(ws + 16777216ull);
  const size_t NEED = 88080384ull;  // 84 MB

  int kkeep = (T < 64) ? T : 64;
  int fk = (HEAD_DIM * kkeep + T - 1) / T;
  if (fk < 1) fk = 1;
  int nseg = T * N_HEADS;

  embed_kernel<<<T, 256, 0, stream>>>(ids, Wemb, Wpos, x);

  if (ws_size >= NEED && (T % 128) == 0 && (VOC % 128) == 0 &&
      (size_t)VOC * D * 2 <= 67108864ull) {
    // ---- bf16 MFMA path ----
    for (int l = 0; l < 2; ++l) {
      const float* wq = Wq + (size_t)l * D * D;
      const float* wk = Wk + (size_t)l * D * D;
      const float* wv = Wv + (size_t)l * D * D;
      const float* wo = Wo + (size_t)l * D * D;

      ln_kernel<<<T, 256, 0, stream>>>(x, xn, nullptr, nullptr,
                                       ln1_g + (size_t)l * D, ln1_b + (size_t)l * D);

      gemm_nn_qkv128<<<dim3(3 * D / 128, T / 128), 256, 0, stream>>>(xn, wq, wk, wv, q, T, D);

      sparsify_kernel<<<(3 * nseg + 3) / 4, 256, 0, stream>>>(q, 3 * nseg, fk);

      transpose_kernel<<<dim3(D / 32, T / 32), 256, 0, stream>>>(k, kt, T, D);

      attn_kernel<<<T * N_HEADS, 64, 0, stream>>>(q, kt, v, nullptr, xnbh, xnbl, T);

      transpose_conv_pair_kernel<<<dim3(D / 32, D / 32), 256, 0, stream>>>(wo, woth, wotl, D, D);
      gemm3_bt<4, 0><<<dim3(D / 128, T / 128), 256, 0, stream>>>(
          xnbh, xnbl, woth, wotl, x, nullptr, nullptr, nullptr, x, T, D, D);

      ln_kernel<<<T, 256, 0, stream>>>(x, nullptr, xnbh, xnbl,
                                       ln2_g + (size_t)l * D, ln2_b + (size_t)l * D);

      transpose_conv_pair_kernel<<<dim3(HIDDEN / 32, D / 32), 256, 0, stream>>>(
          W1 + (size_t)l * D * HIDDEN, w1th, w1tl, D, HIDDEN);
      gemm3_bt<3, 1><<<dim3(HIDDEN / 128, T / 128), 256, 0, stream>>>(
          xnbh, xnbl, w1th, w1tl, nullptr, hbh, hbl,
          b1 + (size_t)l * HIDDEN, nullptr, T, HIDDEN, D);
      transpose_conv_pair_kernel<<<dim3(D / 32, HIDDEN / 32), 256, 0, stream>>>(
          W2 + (size_t)l * HIDDEN * D, w2th, w2tl, HIDDEN, D);
      gemm3_bt<5, 0><<<dim3(D / 128, T / 128), 256, 0, stream>>>(
          hbh, hbl, w2th, w2tl, x, nullptr, nullptr,
          b2 + (size_t)l * D, x, T, D, HIDDEN);
    }

    ln_kernel<<<T, 256, 0, stream>>>(x, nullptr, xnbh, nullptr, lnf_g, lnf_b);

    conv_bf16_kernel<<<4096, 256, 0, stream>>>(Wemb, wembb, (size_t)VOC * D);

    gemm_bt_bf16<0, float><<<dim3(VOC / 128, T / 128), 256, 0, stream>>>(
        xnbh, wembb, (float*)d_out, nullptr, nullptr, T, VOC, D);
  } else {
    // ---- fp32 fallback ----
    float* hbuf = q;
    for (int l = 0; l < 2; ++l) {
      const float* wq = Wq + (size_t)l * D * D;
      const float* wk = Wk + (size_t)l * D * D;
      const float* wv = Wv + (size_t)l * D * D;
      const float* wo = Wo + (size_t)l * D * D;

      ln_kernel<<<T, 256, 0, stream>>>(x, xn, nullptr, nullptr,
                                       ln1_g + (size_t)l * D, ln1_b + (size_t)l * D);

      dim3 g1(D / 64, T / 64);
      gemm_nn<0><<<g1, 256, 0, stream>>>(xn, wq, q, nullptr, nullptr, T, D, D);
      gemm_nn<0><<<g1, 256, 0, stream>>>(xn, wk, k, nullptr, nullptr, T, D, D);
      gemm_nn<0><<<g1, 256, 0, stream>>>(xn, wv, v, nullptr, nullptr, T, D, D);

      sparsify_kernel<<<(nseg + 3) / 4, 256, 0, stream>>>(q, nseg, fk);
      sparsify_kernel<<<(nseg + 3) / 4, 256, 0, stream>>>(k, nseg, fk);
      sparsify_kernel<<<(nseg + 3) / 4, 256, 0, stream>>>(v, nseg, fk);

      transpose_kernel<<<dim3(D / 32, T / 32), 256, 0, stream>>>(k, kt, T, D);

      attn_kernel<<<T * N_HEADS, 64, 0, stream>>>(q, kt, v, xn, nullptr, nullptr, T);

      gemm_nn<4><<<g1, 256, 0, stream>>>(xn, wo, x, nullptr, x, T, D, D);

      ln_kernel<<<T, 256, 0, stream>>>(x, xn, nullptr, nullptr,
                                       ln2_g + (size_t)l * D, ln2_b + (size_t)l * D);

      gemm_nn<3><<<dim3(HIDDEN / 64, T / 64), 256, 0, stream>>>(
          xn, W1 + (size_t)l * D * HIDDEN, hbuf, b1 + (size_t)l * HIDDEN, nullptr, T, HIDDEN, D);
      gemm_nn<5><<<g1, 256, 0, stream>>>(
          hbuf, W2 + (size_t)l * HIDDEN * D, x, b2 + (size_t)l * D, x, T, D, HIDDEN);
    }

    ln_kernel<<<T, 256, 0, stream>>>(x, xn, nullptr, nullptr, lnf_g, lnf_b);

    gemm_nt<0><<<dim3(VOC / 64, T / 64), 256, 0, stream>>>(
        xn, Wemb, (float*)d_out, nullptr, nullptr, T, VOC, D);
  }
}

// Round 9
// 1649.406 us; speedup vs baseline: 1.1964x; 1.1127x over previous
//
#include <hip/hip_runtime.h>
#include <math.h>

#define D_MODEL 1024
#define N_HEADS 16
#define HEAD_DIM 64
#define HIDDEN 4096
#define TMAX 2048

typedef __attribute__((ext_vector_type(8))) short s16x8;
typedef __attribute__((ext_vector_type(4))) float f32x4;

// ---------------- wave helpers (wave64) ----------------
__device__ __forceinline__ float wave_max_f(float v) {
#pragma unroll
  for (int o = 32; o > 0; o >>= 1) v = fmaxf(v, __shfl_xor(v, o));
  return v;
}
__device__ __forceinline__ float wave_sum_f(float v) {
#pragma unroll
  for (int o = 32; o > 0; o >>= 1) v += __shfl_xor(v, o);
  return v;
}
__device__ __forceinline__ unsigned long long wave_max_u64(unsigned long long k) {
#pragma unroll
  for (int o = 32; o > 0; o >>= 1) {
    unsigned long long u = __shfl_xor(k, o);
    if (u > k) k = u;
  }
  return k;
}
__device__ __forceinline__ unsigned ford(float v) {
  unsigned u = __float_as_uint(v);
  return (u & 0x80000000u) ? ~u : (u | 0x80000000u);
}
// fp32 -> bf16 RNE
__device__ __forceinline__ unsigned short f2bf(float f) {
  unsigned u = __float_as_uint(f);
  u += 0x7FFFu + ((u >> 16) & 1u);
  return (unsigned short)(u >> 16);
}
__device__ __forceinline__ float bf2f(unsigned short h) {
  return __uint_as_float((unsigned)h << 16);
}

__device__ __forceinline__ void gload_lds16(const void* g, void* l) {
  __builtin_amdgcn_global_load_lds(
      (const __attribute__((address_space(1))) void*)g,
      (__attribute__((address_space(3))) void*)l, 16, 0, 0);
}

// ---------------- embedding ----------------
__global__ __launch_bounds__(256) void embed_kernel(const int* __restrict__ ids,
    const float* __restrict__ Wemb, const float* __restrict__ Wpos, float* __restrict__ X) {
  int t = blockIdx.x, tid = threadIdx.x;
  int id = ids[t];
  float4 e = ((const float4*)(Wemb + (size_t)id * D_MODEL))[tid];
  float4 p = ((const float4*)(Wpos + (size_t)t * D_MODEL))[tid];
  e.x += p.x; e.y += p.y; e.z += p.z; e.w += p.w;
  ((float4*)(X + (size_t)t * D_MODEL))[tid] = e;
}

// ---------------- layernorm; optional fp32 out + bf16 hi/lo out ----------------
__global__ __launch_bounds__(256) void ln_kernel(const float* __restrict__ X,
    float* __restrict__ Y, unsigned short* __restrict__ Ybh, unsigned short* __restrict__ Ybl,
    const float* __restrict__ g, const float* __restrict__ b) {
  int row = blockIdx.x, tid = threadIdx.x;
  int lane = tid & 63, wid = tid >> 6;
  __shared__ float red[8];
  float4 v = ((const float4*)(X + (size_t)row * D_MODEL))[tid];
  float s = v.x + v.y + v.z + v.w;
  s = wave_sum_f(s);
  if (lane == 0) red[wid] = s;
  __syncthreads();
  float mean = (red[0] + red[1] + red[2] + red[3]) * (1.0f / D_MODEL);
  float dx = v.x - mean, dy = v.y - mean, dz = v.z - mean, dw = v.w - mean;
  float q = dx * dx + dy * dy + dz * dz + dw * dw;
  q = wave_sum_f(q);
  if (lane == 0) red[4 + wid] = q;
  __syncthreads();
  float var = (red[4] + red[5] + red[6] + red[7]) * (1.0f / D_MODEL);
  float rs = rsqrtf(var + 1e-5f);
  float4 gg = ((const float4*)g)[tid], bb = ((const float4*)b)[tid];
  float4 y;
  y.x = dx * rs * gg.x + bb.x;
  y.y = dy * rs * gg.y + bb.y;
  y.z = dz * rs * gg.z + bb.z;
  y.w = dw * rs * gg.w + bb.w;
  if (Y) ((float4*)(Y + (size_t)row * D_MODEL))[tid] = y;
  if (Ybh) {
    ushort4 oh;
    oh.x = f2bf(y.x); oh.y = f2bf(y.y); oh.z = f2bf(y.z); oh.w = f2bf(y.w);
    ((ushort4*)(Ybh + (size_t)row * D_MODEL))[tid] = oh;
    if (Ybl) {
      ushort4 ol;
      ol.x = f2bf(y.x - bf2f(oh.x)); ol.y = f2bf(y.y - bf2f(oh.y));
      ol.z = f2bf(y.z - bf2f(oh.z)); ol.w = f2bf(y.w - bf2f(oh.w));
      ((ushort4*)(Ybl + (size_t)row * D_MODEL))[tid] = ol;
    }
  }
}

// ---------------- sparsify (exact top-fk by |value| per 64 segment) ----------------
__global__ __launch_bounds__(256) void sparsify_kernel(float* __restrict__ X, int nseg, int fk) {
  int seg = blockIdx.x * 4 + (threadIdx.x >> 6);
  if (seg >= nseg) return;
  int lane = threadIdx.x & 63;
  size_t idx = (size_t)seg * 64 + lane;
  float x = X[idx];
  float a = fabsf(x);
  float cur = INFINITY;
  int remaining = fk;
  float thr = 0.0f;
  for (;;) {
    float cand = (a < cur) ? a : -INFINITY;
    float mv = wave_max_f(cand);
    if (mv == -INFINITY) { thr = mv; break; }
    int c = __popcll(__ballot(a == mv));
    if (c >= remaining) { thr = mv; break; }
    remaining -= c; cur = mv;
  }
  if (!(a >= thr)) X[idx] = 0.0f;
}

// ---------------- transpose fp32 [R][C] -> [C][R] ----------------
__global__ __launch_bounds__(256) void transpose_kernel(const float* __restrict__ in,
    float* __restrict__ out, int R, int Cc) {
  __shared__ float tile[32][33];
  int c0 = blockIdx.x * 32, r0 = blockIdx.y * 32;
  int tx = threadIdx.x & 31, ty = threadIdx.x >> 5;
  for (int i = ty; i < 32; i += 8)
    tile[i][tx] = in[(size_t)(r0 + i) * Cc + c0 + tx];
  __syncthreads();
  for (int i = ty; i < 32; i += 8)
    out[(size_t)(c0 + i) * R + r0 + tx] = tile[tx][i];
}

// ---------------- transpose-convert fp32 [R][C] -> bf16 hi/lo [C][R] ----------------
__global__ __launch_bounds__(256) void transpose_conv_pair_kernel(const float* __restrict__ in,
    unsigned short* __restrict__ oh, unsigned short* __restrict__ ol, int R, int Cc) {
  __shared__ float tile[32][33];
  int c0 = blockIdx.x * 32, r0 = blockIdx.y * 32;
  int tx = threadIdx.x & 31, ty = threadIdx.x >> 5;
  for (int i = ty; i < 32; i += 8)
    tile[i][tx] = in[(size_t)(r0 + i) * Cc + c0 + tx];
  __syncthreads();
  for (int i = ty; i < 32; i += 8) {
    float v = tile[tx][i];
    unsigned short h = f2bf(v);
    size_t idx = (size_t)(c0 + i) * R + r0 + tx;
    oh[idx] = h;
    ol[idx] = f2bf(v - bf2f(h));
  }
}

// ---------------- fp32 -> bf16 elementwise ----------------
__global__ __launch_bounds__(256) void conv_bf16_kernel(const float* __restrict__ in,
    unsigned short* __restrict__ out, size_t n) {
  size_t i = ((size_t)blockIdx.x * 256 + threadIdx.x) * 4;
  size_t stride = (size_t)gridDim.x * 1024;
  for (; i < n; i += stride) {
    float4 v = *(const float4*)(in + i);
    ushort4 o;
    o.x = f2bf(v.x); o.y = f2bf(v.y); o.z = f2bf(v.z); o.w = f2bf(v.w);
    *(ushort4*)(out + i) = o;
  }
}

// ---------------- attention: one wave per (head, query-row) ----------------
// r4 structure (proven 380us) + nq==2 score specialization + fixed-trip gather.
// exact: scores=q@k^T/8 causal; stable top-64 (val desc, idx asc); softmax; @v
__global__ __launch_bounds__(64) void attn_kernel(const float* __restrict__ Q,
    const float* __restrict__ Kt, const float* __restrict__ V,
    float* __restrict__ Of, unsigned short* __restrict__ Oh, unsigned short* __restrict__ Ol,
    int T) {
  int t = blockIdx.x % T;
  int h = blockIdx.x / T;
  int lane = threadIdx.x;
  unsigned long long lmlt = (1ull << lane) - 1ull;

  __shared__ float sc[TMAX];
  __shared__ float qval[HEAD_DIM];
  __shared__ int qdim[HEAD_DIM];
  constexpr int PCAP = 320;
  __shared__ float posv[PCAP];
  __shared__ int posi[PCAP];
  __shared__ int seli[64];
  __shared__ float selv[64];
  __shared__ float wsel[64];

  int hoff = h * HEAD_DIM;
  float qv = Q[(size_t)t * D_MODEL + hoff + lane];
  unsigned long long nzm = __ballot(qv != 0.0f);
  int nq = __popcll(nzm);
  if (qv != 0.0f) {
    int p = __popcll(nzm & lmlt);
    qval[p] = qv; qdim[p] = lane;
  }
  seli[lane] = 0;  // pad target for fixed-trip gather
  __syncthreads();

  int Vn = t + 1;
  // ---- score pass; nq==2 fast path (registers hoisted once, independent iters) ----
  if (nq == 2) {
    float qA = qval[0], qB = qval[1];
    const float* ktA = Kt + (size_t)(hoff + qdim[0]) * T;
    const float* ktB = Kt + (size_t)(hoff + qdim[1]) * T;
    for (int s = lane; s < Vn; s += 64)
      sc[s] = fmaf(qB, ktB[s], qA * ktA[s]) * 0.125f;
  } else {
    for (int s = lane; s < Vn; s += 64) {
      float acc = 0.0f;
      for (int j = 0; j < nq; ++j)
        acc += qval[j] * Kt[(size_t)(hoff + qdim[j]) * T + s];
      sc[s] = acc * 0.125f;
    }
  }
  __syncthreads();

  int nsel = 0;
  if (Vn <= 64) {
    nsel = Vn;
    if (lane < Vn) { seli[lane] = lane; selv[lane] = sc[lane]; }
    __syncthreads();
  } else {
    // compact positive scores (list index order == s order)
    int base = 0;
    for (int s0 = 0; s0 < Vn; s0 += 64) {
      int s = s0 + lane;
      float v = (s < Vn) ? sc[s] : -1.0f;
      unsigned long long pm = __ballot(v > 0.0f);
      if (v > 0.0f) {
        int p = base + __popcll(pm & lmlt);
        if (p < PCAP) { posv[p] = v; posi[p] = s; }
      }
      base += __popcll(pm);
    }
    int P = base;
    __syncthreads();

    bool fullpath = false;
    if (P >= 64) {
      if (P <= 128) {
        // ---- bitonic-128 top-64: key = (ford(v)<<32) | (0xFFFFFFFF - idx) ----
        unsigned long long key0, key1;
        {
          int e0 = lane, e1 = lane + 64;
          key0 = (e0 < P) ? (((unsigned long long)ford(posv[e0]) << 32) |
                             (unsigned long long)(0xFFFFFFFFu - (unsigned)e0)) : 0ull;
          key1 = (e1 < P) ? (((unsigned long long)ford(posv[e1]) << 32) |
                             (unsigned long long)(0xFFFFFFFFu - (unsigned)e1)) : 0ull;
        }
        for (int k = 2; k <= 128; k <<= 1) {
          for (int j = k >> 1; j > 0; j >>= 1) {
            if (j == 64) {
              if (key0 < key1) { unsigned long long tm = key0; key0 = key1; key1 = tm; }
            } else {
              bool iLower = (lane & j) == 0;
              {
                unsigned long long prt = __shfl_xor(key0, j);
                bool desc = ((lane & k) == 0);
                bool keepMax = (iLower == desc);
                key0 = keepMax ? (key0 > prt ? key0 : prt) : (key0 < prt ? key0 : prt);
              }
              {
                unsigned long long prt = __shfl_xor(key1, j);
                int e1 = lane + 64;
                bool desc = ((e1 & k) == 0);
                bool keepMax = (iLower == desc);
                key1 = keepMax ? (key1 > prt ? key1 : prt) : (key1 < prt ? key1 : prt);
              }
            }
          }
        }
        int e = (int)(0xFFFFFFFFu - (unsigned)(key0 & 0xFFFFFFFFull));
        seli[lane] = posi[e];
        selv[lane] = posv[e];
        nsel = 64;
        __syncthreads();
      } else if (P <= PCAP) {
        for (int r = 0; r < 64; ++r) {
          unsigned long long best = 0ull;
          for (int j = lane; j < P; j += 64) {
            float v = posv[j];
            if (v > 0.0f) {
              unsigned long long key =
                  ((unsigned long long)ford(v) << 32) | (unsigned)(0xFFFFFFFFu - (unsigned)j);
              if (key > best) best = key;
            }
          }
          best = wave_max_u64(best);
          int j = (int)(0xFFFFFFFFu - (unsigned)(best & 0xFFFFFFFFull));
          if (lane == (j & 63)) {
            seli[r] = posi[j]; selv[r] = posv[j]; posv[j] = -INFINITY;
          }
          __syncthreads();
        }
        nsel = 64;
      } else {
        fullpath = true;
      }
    } else {
      if (lane < P) { seli[lane] = posi[lane]; selv[lane] = posv[lane]; }
      int need = 64 - P;
      int zbase = 0;
      bool done = false;
      for (int s0 = 0; s0 < Vn && !done; s0 += 64) {
        int s = s0 + lane;
        bool isz = (s < Vn) && (sc[s] == 0.0f);
        unsigned long long zm = __ballot(isz);
        int pre = __popcll(zm & lmlt);
        if (isz && (zbase + pre) < need) {
          seli[P + zbase + pre] = s;
          selv[P + zbase + pre] = 0.0f;
        }
        zbase += __popcll(zm);
        if (zbase >= need) done = true;
      }
      if (zbase >= need) {
        nsel = 64;
        __syncthreads();
      } else {
        fullpath = true;
      }
    }

    if (fullpath) {
      __syncthreads();
      nsel = 64;
      for (int r = 0; r < 64; ++r) {
        unsigned long long best = 0ull;
        for (int s = lane; s < Vn; s += 64) {
          float v = sc[s];
          if (v != -INFINITY) {
            unsigned long long key =
                ((unsigned long long)ford(v) << 32) | (unsigned)(0x7FFFFFFFu - (unsigned)s);
            if (key > best) best = key;
          }
        }
        best = wave_max_u64(best);
        if (best == 0ull) { nsel = r; break; }
        int s = (int)(0x7FFFFFFFu - (unsigned)(best & 0xFFFFFFFFull));
        if (lane == (s & 63)) {
          seli[r] = s; selv[r] = sc[s]; sc[s] = -INFINITY;
        }
        __syncthreads();
      }
    }
  }

  float v = (lane < nsel) ? selv[lane] : -INFINITY;
  float m = wave_max_f(v);
  float w = (lane < nsel) ? expf(v - m) : 0.0f;
  float ds = wave_sum_f(w);
  wsel[lane] = w / ds;   // == 0 for lane >= nsel
  __syncthreads();

  // fixed-trip gather: iterations r >= nsel are exact fma(0,.,o) no-ops
  float o = 0.0f;
#pragma unroll 4
  for (int r = 0; r < 64; ++r)
    o = fmaf(wsel[r], V[(size_t)seli[r] * D_MODEL + hoff + lane], o);

  size_t oidx = (size_t)t * D_MODEL + hoff + lane;
  if (Of) Of[oidx] = o;
  if (Oh) {
    unsigned short hh = f2bf(o);
    Oh[oidx] = hh;
    Ol[oidx] = f2bf(o - bf2f(hh));
  }
}

// ============ single bf16 MFMA GEMM (NT): C[M,N] = A @ B^T ============
// SWAPXY: take M-tile from blockIdx.x (fastest) so consecutive blocks share
// the same B panel (L2 reuse); A panel set stays L2-resident.
template <int FLAGS, typename CT, bool SWAPXY = false>
__global__ __launch_bounds__(256) void gemm_bt_bf16(const unsigned short* __restrict__ A,
    const unsigned short* __restrict__ B, CT* __restrict__ C,
    const float* __restrict__ bias, const float* __restrict__ res, int M, int N, int K) {
  constexpr bool HAS_BIAS = (FLAGS & 1) != 0;
  constexpr bool HAS_GELU = (FLAGS & 2) != 0;
  constexpr bool HAS_RES = (FLAGS & 4) != 0;
  __shared__ unsigned short As[128 * 32];
  __shared__ unsigned short Bs[128 * 32];
  int tid = threadIdx.x;
  int lane = tid & 63, wid = tid >> 6;
  int wr = wid >> 1, wc = wid & 1;
  int m0 = (SWAPXY ? blockIdx.x : blockIdx.y) * 128;
  int n0 = (SWAPXY ? blockIdx.y : blockIdx.x) * 128;

  int r_in = lane >> 2;
  int slot = lane & 3;

  f32x4 acc[4][4] = {};

  int fr = lane & 15;
  int ksl = lane >> 4;

  for (int k0 = 0; k0 < K; k0 += 32) {
#pragma unroll
    for (int s = 0; s < 2; ++s) {
      int row = wid * 32 + s * 16 + r_in;
      int ksw = (slot ^ ((row >> 1) & 3)) * 8;
      const unsigned short* ga = A + (size_t)(m0 + row) * K + k0 + ksw;
      const unsigned short* gb = B + (size_t)(n0 + row) * K + k0 + ksw;
      gload_lds16(ga, &As[(wid * 32 + s * 16) * 32]);
      gload_lds16(gb, &Bs[(wid * 32 + s * 16) * 32]);
    }
    asm volatile("s_waitcnt vmcnt(0)" ::: "memory");
    __syncthreads();

    s16x8 av[4], bv[4];
#pragma unroll
    for (int mi = 0; mi < 4; ++mi) {
      int ar = wr * 64 + mi * 16 + fr;
      av[mi] = *(const s16x8*)&As[ar * 32 + ((ksl ^ ((ar >> 1) & 3)) * 8)];
    }
#pragma unroll
    for (int ni = 0; ni < 4; ++ni) {
      int br = wc * 64 + ni * 16 + fr;
      bv[ni] = *(const s16x8*)&Bs[br * 32 + ((ksl ^ ((br >> 1) & 3)) * 8)];
    }
#pragma unroll
    for (int mi = 0; mi < 4; ++mi)
#pragma unroll
      for (int ni = 0; ni < 4; ++ni)
        acc[mi][ni] = __builtin_amdgcn_mfma_f32_16x16x32_bf16(av[mi], bv[ni], acc[mi][ni], 0, 0, 0);
    __syncthreads();
  }

  int cr = lane >> 4, cc = lane & 15;
#pragma unroll
  for (int mi = 0; mi < 4; ++mi) {
#pragma unroll
    for (int j = 0; j < 4; ++j) {
      int row = m0 + wr * 64 + mi * 16 + cr * 4 + j;
#pragma unroll
      for (int ni = 0; ni < 4; ++ni) {
        int col = n0 + wc * 64 + ni * 16 + cc;
        float vv = acc[mi][ni][j];
        if (HAS_BIAS) vv += bias[col];
        if (HAS_GELU) vv = 0.5f * vv * (1.0f + erff(vv * 0.70710678118654752f));
        if (HAS_RES) vv += res[(size_t)row * N + col];
        if constexpr (sizeof(CT) == 2)
          C[(size_t)row * N + col] = (CT)f2bf(vv);
        else
          C[(size_t)row * N + col] = (CT)vv;
      }
    }
  }
}

// ============ bf16x3 split-precision MFMA GEMM (NT) ============
template <int FLAGS, int OUTMODE>
__global__ __launch_bounds__(256) void gemm3_bt(
    const unsigned short* __restrict__ Ah, const unsigned short* __restrict__ Al,
    const unsigned short* __restrict__ Bh, const unsigned short* __restrict__ Bl,
    float* __restrict__ Cf, unsigned short* __restrict__ Ch, unsigned short* __restrict__ Cl,
    const float* __restrict__ bias, const float* __restrict__ res, int M, int N, int K) {
  constexpr bool HAS_BIAS = (FLAGS & 1) != 0;
  constexpr bool HAS_GELU = (FLAGS & 2) != 0;
  constexpr bool HAS_RES = (FLAGS & 4) != 0;
  __shared__ unsigned short As[2][128 * 32];
  __shared__ unsigned short Bs[2][128 * 32];
  int tid = threadIdx.x;
  int lane = tid & 63, wid = tid >> 6;
  int wr = wid >> 1, wc = wid & 1;
  int m0 = blockIdx.y * 128, n0 = blockIdx.x * 128;

  int r_in = lane >> 2;
  int slot = lane & 3;

  f32x4 acc[4][4] = {};

  int fr = lane & 15;
  int ksl = lane >> 4;

  for (int k0 = 0; k0 < K; k0 += 32) {
#pragma unroll
    for (int s = 0; s < 2; ++s) {
      int row = wid * 32 + s * 16 + r_in;
      int ksw = (slot ^ ((row >> 1) & 3)) * 8;
      size_t ao = (size_t)(m0 + row) * K + k0 + ksw;
      size_t bo = (size_t)(n0 + row) * K + k0 + ksw;
      int ldst = (wid * 32 + s * 16) * 32;
      gload_lds16(Ah + ao, &As[0][ldst]);
      gload_lds16(Al + ao, &As[1][ldst]);
      gload_lds16(Bh + bo, &Bs[0][ldst]);
      gload_lds16(Bl + bo, &Bs[1][ldst]);
    }
    asm volatile("s_waitcnt vmcnt(0)" ::: "memory");
    __syncthreads();

    s16x8 avh[4], avl[4], bvh[4], bvl[4];
#pragma unroll
    for (int mi = 0; mi < 4; ++mi) {
      int ar = wr * 64 + mi * 16 + fr;
      int off = ar * 32 + ((ksl ^ ((ar >> 1) & 3)) * 8);
      avh[mi] = *(const s16x8*)&As[0][off];
      avl[mi] = *(const s16x8*)&As[1][off];
    }
#pragma unroll
    for (int ni = 0; ni < 4; ++ni) {
      int br = wc * 64 + ni * 16 + fr;
      int off = br * 32 + ((ksl ^ ((br >> 1) & 3)) * 8);
      bvh[ni] = *(const s16x8*)&Bs[0][off];
      bvl[ni] = *(const s16x8*)&Bs[1][off];
    }
#pragma unroll
    for (int mi = 0; mi < 4; ++mi)
#pragma unroll
      for (int ni = 0; ni < 4; ++ni) {
        acc[mi][ni] = __builtin_amdgcn_mfma_f32_16x16x32_bf16(avh[mi], bvh[ni], acc[mi][ni], 0, 0, 0);
        acc[mi][ni] = __builtin_amdgcn_mfma_f32_16x16x32_bf16(avl[mi], bvh[ni], acc[mi][ni], 0, 0, 0);
        acc[mi][ni] = __builtin_amdgcn_mfma_f32_16x16x32_bf16(avh[mi], bvl[ni], acc[mi][ni], 0, 0, 0);
      }
    __syncthreads();
  }

  int cr = lane >> 4, cc = lane & 15;
#pragma unroll
  for (int mi = 0; mi < 4; ++mi) {
#pragma unroll
    for (int j = 0; j < 4; ++j) {
      int row = m0 + wr * 64 + mi * 16 + cr * 4 + j;
#pragma unroll
      for (int ni = 0; ni < 4; ++ni) {
        int col = n0 + wc * 64 + ni * 16 + cc;
        float vv = acc[mi][ni][j];
        if (HAS_BIAS) vv += bias[col];
        if (HAS_GELU) vv = 0.5f * vv * (1.0f + erff(vv * 0.70710678118654752f));
        if (HAS_RES) vv += res[(size_t)row * N + col];
        if constexpr (OUTMODE == 0) {
          Cf[(size_t)row * N + col] = vv;
        } else {
          unsigned short h = f2bf(vv);
          Ch[(size_t)row * N + col] = h;
          Cl[(size_t)row * N + col] = f2bf(vv - bf2f(h));
        }
      }
    }
  }
}

// ---------------- fp32 fused QKV GEMM (NN): [q|k|v] = xn @ [Wq|Wk|Wv] ----------------
__global__ __launch_bounds__(256) void gemm_nn_qkv(const float* __restrict__ A,
    const float* __restrict__ Bq, const float* __restrict__ Bk, const float* __restrict__ Bv,
    float* __restrict__ C, int M, int K) {
  __shared__ float As[16][68];
  __shared__ float Bs[16][68];
  int tid = threadIdx.x;
  int m0 = blockIdx.y * 64;
  int n0g = blockIdx.x * 64;
  const float* B = (n0g < 1024) ? Bq : (n0g < 2048 ? Bk : Bv);
  float* Cb = C + (size_t)(n0g >> 10) * ((size_t)M * 1024);
  int n0 = n0g & 1023;
  int tx = tid & 15, ty = tid >> 4;
  int am = tid >> 2, ak = (tid & 3) * 4;
  int bk = tid >> 4, bn = (tid & 15) * 4;
  const float* Ap = A + (size_t)(m0 + am) * K + ak;
  const float* Bp = B + (size_t)bk * 1024 + n0 + bn;
  float acc[4][4] = {};
  for (int k0 = 0; k0 < K; k0 += 16) {
    float4 a4 = *(const float4*)(Ap + k0);
    float4 b4 = *(const float4*)(Bp + (size_t)k0 * 1024);
    As[ak + 0][am] = a4.x; As[ak + 1][am] = a4.y;
    As[ak + 2][am] = a4.z; As[ak + 3][am] = a4.w;
    *(float4*)&Bs[bk][bn] = b4;
    __syncthreads();
#pragma unroll
    for (int k = 0; k < 16; ++k) {
      float4 bq = *(const float4*)&Bs[k][tx * 4];
#pragma unroll
      for (int i = 0; i < 4; ++i) {
        float av = As[k][ty * 4 + i];
        acc[i][0] += av * bq.x; acc[i][1] += av * bq.y;
        acc[i][2] += av * bq.z; acc[i][3] += av * bq.w;
      }
    }
    __syncthreads();
  }
#pragma unroll
  for (int i = 0; i < 4; ++i) {
    int row = m0 + ty * 4 + i;
#pragma unroll
    for (int j = 0; j < 4; ++j) {
      int col = n0 + tx * 4 + j;
      Cb[(size_t)row * 1024 + col] = acc[i][j];
    }
  }
}

// ---------------- fp32 tiled GEMM (NN) ----------------
template <int FLAGS>
__global__ __launch_bounds__(256) void gemm_nn(const float* __restrict__ A,
    const float* __restrict__ B, float* __restrict__ C, const float* __restrict__ bias,
    const float* __restrict__ res, int M, int N, int K) {
  constexpr bool HAS_BIAS = (FLAGS & 1) != 0;
  constexpr bool HAS_GELU = (FLAGS & 2) != 0;
  constexpr bool HAS_RES = (FLAGS & 4) != 0;
  __shared__ float As[16][68];
  __shared__ float Bs[16][68];
  int tid = threadIdx.x;
  int m0 = blockIdx.y * 64, n0 = blockIdx.x * 64;
  int tx = tid & 15, ty = tid >> 4;
  int am = tid >> 2, ak = (tid & 3) * 4;
  int bk = tid >> 4, bn = (tid & 15) * 4;
  const float* Ap = A + (size_t)(m0 + am) * K + ak;
  const float* Bp = B + (size_t)bk * N + n0 + bn;
  float acc[4][4] = {};
  for (int k0 = 0; k0 < K; k0 += 16) {
    float4 a4 = *(const float4*)(Ap + k0);
    float4 b4 = *(const float4*)(Bp + (size_t)k0 * N);
    As[ak + 0][am] = a4.x; As[ak + 1][am] = a4.y;
    As[ak + 2][am] = a4.z; As[ak + 3][am] = a4.w;
    *(float4*)&Bs[bk][bn] = b4;
    __syncthreads();
#pragma unroll
    for (int k = 0; k < 16; ++k) {
      float4 bq = *(const float4*)&Bs[k][tx * 4];
#pragma unroll
      for (int i = 0; i < 4; ++i) {
        float av = As[k][ty * 4 + i];
        acc[i][0] += av * bq.x; acc[i][1] += av * bq.y;
        acc[i][2] += av * bq.z; acc[i][3] += av * bq.w;
      }
    }
    __syncthreads();
  }
#pragma unroll
  for (int i = 0; i < 4; ++i) {
    int row = m0 + ty * 4 + i;
#pragma unroll
    for (int j = 0; j < 4; ++j) {
      int col = n0 + tx * 4 + j;
      float vv = acc[i][j];
      if (HAS_BIAS) vv += bias[col];
      if (HAS_GELU) vv = 0.5f * vv * (1.0f + erff(vv * 0.70710678118654752f));
      if (HAS_RES) vv += res[(size_t)row * N + col];
      C[(size_t)row * N + col] = vv;
    }
  }
}

// ---------------- fp32 tiled GEMM (NT, fallback logits) ----------------
template <int FLAGS>
__global__ __launch_bounds__(256) void gemm_nt(const float* __restrict__ A,
    const float* __restrict__ B, float* __restrict__ C, const float* __restrict__ bias,
    const float* __restrict__ res, int M, int N, int K) {
  constexpr bool HAS_BIAS = (FLAGS & 1) != 0;
  constexpr bool HAS_GELU = (FLAGS & 2) != 0;
  constexpr bool HAS_RES = (FLAGS & 4) != 0;
  __shared__ float As[16][68];
  __shared__ float Bs[16][68];
  int tid = threadIdx.x;
  int m0 = blockIdx.y * 64, n0 = blockIdx.x * 64;
  int tx = tid & 15, ty = tid >> 4;
  int am = tid >> 2, ak = (tid & 3) * 4;
  int bn2 = tid >> 2, bk2 = (tid & 3) * 4;
  const float* Ap = A + (size_t)(m0 + am) * K + ak;
  const float* Bp = B + (size_t)(n0 + bn2) * K + bk2;
  float acc[4][4] = {};
  for (int k0 = 0; k0 < K; k0 += 16) {
    float4 a4 = *(const float4*)(Ap + k0);
    float4 b4 = *(const float4*)(Bp + k0);
    As[ak + 0][am] = a4.x; As[ak + 1][am] = a4.y;
    As[ak + 2][am] = a4.z; As[ak + 3][am] = a4.w;
    Bs[bk2 + 0][bn2] = b4.x; Bs[bk2 + 1][bn2] = b4.y;
    Bs[bk2 + 2][bn2] = b4.z; Bs[bk2 + 3][bn2] = b4.w;
    __syncthreads();
#pragma unroll
    for (int k = 0; k < 16; ++k) {
      float4 bq = *(const float4*)&Bs[k][tx * 4];
#pragma unroll
      for (int i = 0; i < 4; ++i) {
        float av = As[k][ty * 4 + i];
        acc[i][0] += av * bq.x; acc[i][1] += av * bq.y;
        acc[i][2] += av * bq.z; acc[i][3] += av * bq.w;
      }
    }
    __syncthreads();
  }
#pragma unroll
  for (int i = 0; i < 4; ++i) {
    int row = m0 + ty * 4 + i;
#pragma unroll
    for (int j = 0; j < 4; ++j) {
      int col = n0 + tx * 4 + j;
      float vv = acc[i][j];
      if (HAS_BIAS) vv += bias[col];
      if (HAS_GELU) vv = 0.5f * vv * (1.0f + erff(vv * 0.70710678118654752f));
      if (HAS_RES) vv += res[(size_t)row * N + col];
      C[(size_t)row * N + col] = vv;
    }
  }
}

// ---------------- host orchestration ----------------
extern "C" void kernel_launch(void* const* d_in, const int* in_sizes, int n_in,
                              void* d_out, int out_size, void* d_ws, size_t ws_size,
                              hipStream_t stream) {
  const int* ids = (const int*)d_in[0];
  const float* Wemb = (const float*)d_in[1];
  const float* Wpos = (const float*)d_in[2];
  const float* ln1_g = (const float*)d_in[3];
  const float* ln1_b = (const float*)d_in[4];
  const float* Wq = (const float*)d_in[5];
  const float* Wk = (const float*)d_in[6];
  const float* Wv = (const float*)d_in[7];
  const float* Wo = (const float*)d_in[8];
  const float* ln2_g = (const float*)d_in[9];
  const float* ln2_b = (const float*)d_in[10];
  const float* W1 = (const float*)d_in[11];
  const float* b1 = (const float*)d_in[12];
  const float* W2 = (const float*)d_in[13];
  const float* b2 = (const float*)d_in[14];
  const float* lnf_g = (const float*)d_in[15];
  const float* lnf_b = (const float*)d_in[16];

  const int T = in_sizes[0];          // 2048
  const int D = D_MODEL;
  const int VOC = in_sizes[1] / D;    // 32000

  char* ws = (char*)d_ws;
  float* x = (float*)(ws);
  float* xn = (float*)(ws + 8388608ull);
  unsigned short* xnbh = (unsigned short*)(ws + 8388608ull);
  unsigned short* xnbl = (unsigned short*)(ws + 12582912ull);
  float* q = (float*)(ws + 16777216ull);
  float* k = (float*)(ws + 25165824ull);
  float* v = (float*)(ws + 33554432ull);
  float* kt = (float*)(ws + 41943040ull);
  unsigned short* w1th = (unsigned short*)(ws + 16777216ull);
  unsigned short* w1tl = (unsigned short*)(ws + 25165824ull);
  unsigned short* w2th = (unsigned short*)(ws + 33554432ull);
  unsigned short* w2tl = (unsigned short*)(ws + 41943040ull);
  unsigned short* hbh = (unsigned short*)(ws + 50331648ull);
  unsigned short* hbl = (unsigned short*)(ws + 67108864ull);
  unsigned short* woth = (unsigned short*)(ws + 83886080ull);
  unsigned short* wotl = (unsigned short*)(ws + 85983232ull);
  unsigned short* wembb = (unsigned short*)(ws + 16777216ull);
  const size_t NEED = 88080384ull;  // 84 MB

  int kkeep = (T < 64) ? T : 64;
  int fk = (HEAD_DIM * kkeep + T - 1) / T;
  if (fk < 1) fk = 1;
  int nseg = T * N_HEADS;

  embed_kernel<<<T, 256, 0, stream>>>(ids, Wemb, Wpos, x);

  if (ws_size >= NEED && (T % 128) == 0 && (VOC % 128) == 0 &&
      (size_t)VOC * D * 2 <= 67108864ull) {
    // ---- bf16 MFMA path ----
    for (int l = 0; l < 2; ++l) {
      const float* wq = Wq + (size_t)l * D * D;
      const float* wk = Wk + (size_t)l * D * D;
      const float* wv = Wv + (size_t)l * D * D;
      const float* wo = Wo + (size_t)l * D * D;

      ln_kernel<<<T, 256, 0, stream>>>(x, xn, nullptr, nullptr,
                                       ln1_g + (size_t)l * D, ln1_b + (size_t)l * D);

      gemm_nn_qkv<<<dim3(3 * D / 64, T / 64), 256, 0, stream>>>(xn, wq, wk, wv, q, T, D);

      sparsify_kernel<<<(3 * nseg + 3) / 4, 256, 0, stream>>>(q, 3 * nseg, fk);

      transpose_kernel<<<dim3(D / 32, T / 32), 256, 0, stream>>>(k, kt, T, D);

      attn_kernel<<<T * N_HEADS, 64, 0, stream>>>(q, kt, v, nullptr, xnbh, xnbl, T);

      transpose_conv_pair_kernel<<<dim3(D / 32, D / 32), 256, 0, stream>>>(wo, woth, wotl, D, D);
      gemm3_bt<4, 0><<<dim3(D / 128, T / 128), 256, 0, stream>>>(
          xnbh, xnbl, woth, wotl, x, nullptr, nullptr, nullptr, x, T, D, D);

      ln_kernel<<<T, 256, 0, stream>>>(x, nullptr, xnbh, xnbl,
                                       ln2_g + (size_t)l * D, ln2_b + (size_t)l * D);

      transpose_conv_pair_kernel<<<dim3(HIDDEN / 32, D / 32), 256, 0, stream>>>(
          W1 + (size_t)l * D * HIDDEN, w1th, w1tl, D, HIDDEN);
      gemm3_bt<3, 1><<<dim3(HIDDEN / 128, T / 128), 256, 0, stream>>>(
          xnbh, xnbl, w1th, w1tl, nullptr, hbh, hbl,
          b1 + (size_t)l * HIDDEN, nullptr, T, HIDDEN, D);
      transpose_conv_pair_kernel<<<dim3(D / 32, HIDDEN / 32), 256, 0, stream>>>(
          W2 + (size_t)l * HIDDEN * D, w2th, w2tl, HIDDEN, D);
      gemm3_bt<5, 0><<<dim3(D / 128, T / 128), 256, 0, stream>>>(
          hbh, hbl, w2th, w2tl, x, nullptr, nullptr,
          b2 + (size_t)l * D, x, T, D, HIDDEN);
    }

    ln_kernel<<<T, 256, 0, stream>>>(x, nullptr, xnbh, nullptr, lnf_g, lnf_b);

    conv_bf16_kernel<<<4096, 256, 0, stream>>>(Wemb, wembb, (size_t)VOC * D);

    // swapped grid: blockIdx.x (fastest) = M-tile -> consecutive blocks share B panel
    gemm_bt_bf16<0, float, true><<<dim3(T / 128, VOC / 128), 256, 0, stream>>>(
        xnbh, wembb, (float*)d_out, nullptr, nullptr, T, VOC, D);
  } else {
    // ---- fp32 fallback ----
    float* hbuf = q;
    for (int l = 0; l < 2; ++l) {
      const float* wq = Wq + (size_t)l * D * D;
      const float* wk = Wk + (size_t)l * D * D;
      const float* wv = Wv + (size_t)l * D * D;
      const float* wo = Wo + (size_t)l * D * D;

      ln_kernel<<<T, 256, 0, stream>>>(x, xn, nullptr, nullptr,
                                       ln1_g + (size_t)l * D, ln1_b + (size_t)l * D);

      dim3 g1(D / 64, T / 64);
      gemm_nn<0><<<g1, 256, 0, stream>>>(xn, wq, q, nullptr, nullptr, T, D, D);
      gemm_nn<0><<<g1, 256, 0, stream>>>(xn, wk, k, nullptr, nullptr, T, D, D);
      gemm_nn<0><<<g1, 256, 0, stream>>>(xn, wv, v, nullptr, nullptr, T, D, D);

      sparsify_kernel<<<(nseg + 3) / 4, 256, 0, stream>>>(q, nseg, fk);
      sparsify_kernel<<<(nseg + 3) / 4, 256, 0, stream>>>(k, nseg, fk);
      sparsify_kernel<<<(nseg + 3) / 4, 256, 0, stream>>>(v, nseg, fk);

      transpose_kernel<<<dim3(D / 32, T / 32), 256, 0, stream>>>(k, kt, T, D);

      attn_kernel<<<T * N_HEADS, 64, 0, stream>>>(q, kt, v, xn, nullptr, nullptr, T);

      gemm_nn<4><<<g1, 256, 0, stream>>>(xn, wo, x, nullptr, x, T, D, D);

      ln_kernel<<<T, 256, 0, stream>>>(x, xn, nullptr, nullptr,
                                       ln2_g + (size_t)l * D, ln2_b + (size_t)l * D);

      gemm_nn<3><<<dim3(HIDDEN / 64, T / 64), 256, 0, stream>>>(
          xn, W1 + (size_t)l * D * HIDDEN, hbuf, b1 + (size_t)l * HIDDEN, nullptr, T, HIDDEN, D);
      gemm_nn<5><<<g1, 256, 0, stream>>>(
          hbuf, W2 + (size_t)l * HIDDEN * D, x, b2 + (size_t)l * D, x, T, D, HIDDEN);
    }

    ln_kernel<<<T, 256, 0, stream>>>(x, xn, nullptr, nullptr, lnf_g, lnf_b);

    gemm_nt<0><<<dim3(VOC / 64, T / 64), 256, 0, stream>>>(
        xn, Wemb, (float*)d_out, nullptr, nullptr, T, VOC, D);
  }
}

// Round 10
// 1427.822 us; speedup vs baseline: 1.3821x; 1.1552x over previous
//
#include <hip/hip_runtime.h>
#include <math.h>

#define D_MODEL 1024
#define N_HEADS 16
#define HEAD_DIM 64
#define HIDDEN 4096
#define TMAX 2048

typedef __attribute__((ext_vector_type(8))) short s16x8;
typedef __attribute__((ext_vector_type(4))) float f32x4;

// ---------------- wave helpers (wave64) ----------------
__device__ __forceinline__ float wave_max_f(float v) {
#pragma unroll
  for (int o = 32; o > 0; o >>= 1) v = fmaxf(v, __shfl_xor(v, o));
  return v;
}
__device__ __forceinline__ float wave_sum_f(float v) {
#pragma unroll
  for (int o = 32; o > 0; o >>= 1) v += __shfl_xor(v, o);
  return v;
}
__device__ __forceinline__ unsigned long long wave_max_u64(unsigned long long k) {
#pragma unroll
  for (int o = 32; o > 0; o >>= 1) {
    unsigned long long u = __shfl_xor(k, o);
    if (u > k) k = u;
  }
  return k;
}
__device__ __forceinline__ unsigned ford(float v) {
  unsigned u = __float_as_uint(v);
  return (u & 0x80000000u) ? ~u : (u | 0x80000000u);
}
// fp32 -> bf16 RNE
__device__ __forceinline__ unsigned short f2bf(float f) {
  unsigned u = __float_as_uint(f);
  u += 0x7FFFu + ((u >> 16) & 1u);
  return (unsigned short)(u >> 16);
}
__device__ __forceinline__ float bf2f(unsigned short h) {
  return __uint_as_float((unsigned)h << 16);
}

__device__ __forceinline__ void gload_lds16(const void* g, void* l) {
  __builtin_amdgcn_global_load_lds(
      (const __attribute__((address_space(1))) void*)g,
      (__attribute__((address_space(3))) void*)l, 16, 0, 0);
}

// ---------------- embedding ----------------
__global__ __launch_bounds__(256) void embed_kernel(const int* __restrict__ ids,
    const float* __restrict__ Wemb, const float* __restrict__ Wpos, float* __restrict__ X) {
  int t = blockIdx.x, tid = threadIdx.x;
  int id = ids[t];
  float4 e = ((const float4*)(Wemb + (size_t)id * D_MODEL))[tid];
  float4 p = ((const float4*)(Wpos + (size_t)t * D_MODEL))[tid];
  e.x += p.x; e.y += p.y; e.z += p.z; e.w += p.w;
  ((float4*)(X + (size_t)t * D_MODEL))[tid] = e;
}

// ---------------- layernorm; optional fp32 out + bf16 hi/lo out ----------------
__global__ __launch_bounds__(256) void ln_kernel(const float* __restrict__ X,
    float* __restrict__ Y, unsigned short* __restrict__ Ybh, unsigned short* __restrict__ Ybl,
    const float* __restrict__ g, const float* __restrict__ b) {
  int row = blockIdx.x, tid = threadIdx.x;
  int lane = tid & 63, wid = tid >> 6;
  __shared__ float red[8];
  float4 v = ((const float4*)(X + (size_t)row * D_MODEL))[tid];
  float s = v.x + v.y + v.z + v.w;
  s = wave_sum_f(s);
  if (lane == 0) red[wid] = s;
  __syncthreads();
  float mean = (red[0] + red[1] + red[2] + red[3]) * (1.0f / D_MODEL);
  float dx = v.x - mean, dy = v.y - mean, dz = v.z - mean, dw = v.w - mean;
  float q = dx * dx + dy * dy + dz * dz + dw * dw;
  q = wave_sum_f(q);
  if (lane == 0) red[4 + wid] = q;
  __syncthreads();
  float var = (red[4] + red[5] + red[6] + red[7]) * (1.0f / D_MODEL);
  float rs = rsqrtf(var + 1e-5f);
  float4 gg = ((const float4*)g)[tid], bb = ((const float4*)b)[tid];
  float4 y;
  y.x = dx * rs * gg.x + bb.x;
  y.y = dy * rs * gg.y + bb.y;
  y.z = dz * rs * gg.z + bb.z;
  y.w = dw * rs * gg.w + bb.w;
  if (Y) ((float4*)(Y + (size_t)row * D_MODEL))[tid] = y;
  if (Ybh) {
    ushort4 oh;
    oh.x = f2bf(y.x); oh.y = f2bf(y.y); oh.z = f2bf(y.z); oh.w = f2bf(y.w);
    ((ushort4*)(Ybh + (size_t)row * D_MODEL))[tid] = oh;
    if (Ybl) {
      ushort4 ol;
      ol.x = f2bf(y.x - bf2f(oh.x)); ol.y = f2bf(y.y - bf2f(oh.y));
      ol.z = f2bf(y.z - bf2f(oh.z)); ol.w = f2bf(y.w - bf2f(oh.w));
      ((ushort4*)(Ybl + (size_t)row * D_MODEL))[tid] = ol;
    }
  }
}

// ---------------- sparsify (exact top-fk by |value| per 64 segment) ----------------
__global__ __launch_bounds__(256) void sparsify_kernel(float* __restrict__ X, int nseg, int fk) {
  int seg = blockIdx.x * 4 + (threadIdx.x >> 6);
  if (seg >= nseg) return;
  int lane = threadIdx.x & 63;
  size_t idx = (size_t)seg * 64 + lane;
  float x = X[idx];
  float a = fabsf(x);
  float cur = INFINITY;
  int remaining = fk;
  float thr = 0.0f;
  for (;;) {
    float cand = (a < cur) ? a : -INFINITY;
    float mv = wave_max_f(cand);
    if (mv == -INFINITY) { thr = mv; break; }
    int c = __popcll(__ballot(a == mv));
    if (c >= remaining) { thr = mv; break; }
    remaining -= c; cur = mv;
  }
  if (!(a >= thr)) X[idx] = 0.0f;
}

// ---------------- transpose fp32 [R][C] -> [C][R] ----------------
__global__ __launch_bounds__(256) void transpose_kernel(const float* __restrict__ in,
    float* __restrict__ out, int R, int Cc) {
  __shared__ float tile[32][33];
  int c0 = blockIdx.x * 32, r0 = blockIdx.y * 32;
  int tx = threadIdx.x & 31, ty = threadIdx.x >> 5;
  for (int i = ty; i < 32; i += 8)
    tile[i][tx] = in[(size_t)(r0 + i) * Cc + c0 + tx];
  __syncthreads();
  for (int i = ty; i < 32; i += 8)
    out[(size_t)(c0 + i) * R + r0 + tx] = tile[tx][i];
}

// ---------------- transpose-convert fp32 [R][C] -> bf16 hi/lo [C][R] ----------------
__global__ __launch_bounds__(256) void transpose_conv_pair_kernel(const float* __restrict__ in,
    unsigned short* __restrict__ oh, unsigned short* __restrict__ ol, int R, int Cc) {
  __shared__ float tile[32][33];
  int c0 = blockIdx.x * 32, r0 = blockIdx.y * 32;
  int tx = threadIdx.x & 31, ty = threadIdx.x >> 5;
  for (int i = ty; i < 32; i += 8)
    tile[i][tx] = in[(size_t)(r0 + i) * Cc + c0 + tx];
  __syncthreads();
  for (int i = ty; i < 32; i += 8) {
    float v = tile[tx][i];
    unsigned short h = f2bf(v);
    size_t idx = (size_t)(c0 + i) * R + r0 + tx;
    oh[idx] = h;
    ol[idx] = f2bf(v - bf2f(h));
  }
}

// ---------------- fp32 -> bf16 elementwise ----------------
__global__ __launch_bounds__(256) void conv_bf16_kernel(const float* __restrict__ in,
    unsigned short* __restrict__ out, size_t n) {
  size_t i = ((size_t)blockIdx.x * 256 + threadIdx.x) * 4;
  size_t stride = (size_t)gridDim.x * 1024;
  for (; i < n; i += stride) {
    float4 v = *(const float4*)(in + i);
    ushort4 o;
    o.x = f2bf(v.x); o.y = f2bf(v.y); o.z = f2bf(v.z); o.w = f2bf(v.w);
    *(ushort4*)(out + i) = o;
  }
}

// ---------------- attention: one wave per (head, query-row) ----------------
// proven r9 kernel + longest-job-first reorder (t flipped; pure schedule change)
__global__ __launch_bounds__(64) void attn_kernel(const float* __restrict__ Q,
    const float* __restrict__ Kt, const float* __restrict__ V,
    float* __restrict__ Of, unsigned short* __restrict__ Oh, unsigned short* __restrict__ Ol,
    int T) {
  int t = T - 1 - (blockIdx.x % T);   // longest jobs dispatch first
  int h = blockIdx.x / T;
  int lane = threadIdx.x;
  unsigned long long lmlt = (1ull << lane) - 1ull;

  __shared__ float sc[TMAX];
  __shared__ float qval[HEAD_DIM];
  __shared__ int qdim[HEAD_DIM];
  constexpr int PCAP = 320;
  __shared__ float posv[PCAP];
  __shared__ int posi[PCAP];
  __shared__ int seli[64];
  __shared__ float selv[64];
  __shared__ float wsel[64];

  int hoff = h * HEAD_DIM;
  float qv = Q[(size_t)t * D_MODEL + hoff + lane];
  unsigned long long nzm = __ballot(qv != 0.0f);
  int nq = __popcll(nzm);
  if (qv != 0.0f) {
    int p = __popcll(nzm & lmlt);
    qval[p] = qv; qdim[p] = lane;
  }
  seli[lane] = 0;  // pad target for fixed-trip gather
  __syncthreads();

  int Vn = t + 1;
  // ---- score pass; nq==2 fast path ----
  if (nq == 2) {
    float qA = qval[0], qB = qval[1];
    const float* ktA = Kt + (size_t)(hoff + qdim[0]) * T;
    const float* ktB = Kt + (size_t)(hoff + qdim[1]) * T;
    for (int s = lane; s < Vn; s += 64)
      sc[s] = fmaf(qB, ktB[s], qA * ktA[s]) * 0.125f;
  } else {
    for (int s = lane; s < Vn; s += 64) {
      float acc = 0.0f;
      for (int j = 0; j < nq; ++j)
        acc += qval[j] * Kt[(size_t)(hoff + qdim[j]) * T + s];
      sc[s] = acc * 0.125f;
    }
  }
  __syncthreads();

  int nsel = 0;
  if (Vn <= 64) {
    nsel = Vn;
    if (lane < Vn) { seli[lane] = lane; selv[lane] = sc[lane]; }
    __syncthreads();
  } else {
    int base = 0;
    for (int s0 = 0; s0 < Vn; s0 += 64) {
      int s = s0 + lane;
      float v = (s < Vn) ? sc[s] : -1.0f;
      unsigned long long pm = __ballot(v > 0.0f);
      if (v > 0.0f) {
        int p = base + __popcll(pm & lmlt);
        if (p < PCAP) { posv[p] = v; posi[p] = s; }
      }
      base += __popcll(pm);
    }
    int P = base;
    __syncthreads();

    bool fullpath = false;
    if (P >= 64) {
      if (P <= 128) {
        unsigned long long key0, key1;
        {
          int e0 = lane, e1 = lane + 64;
          key0 = (e0 < P) ? (((unsigned long long)ford(posv[e0]) << 32) |
                             (unsigned long long)(0xFFFFFFFFu - (unsigned)e0)) : 0ull;
          key1 = (e1 < P) ? (((unsigned long long)ford(posv[e1]) << 32) |
                             (unsigned long long)(0xFFFFFFFFu - (unsigned)e1)) : 0ull;
        }
        for (int k = 2; k <= 128; k <<= 1) {
          for (int j = k >> 1; j > 0; j >>= 1) {
            if (j == 64) {
              if (key0 < key1) { unsigned long long tm = key0; key0 = key1; key1 = tm; }
            } else {
              bool iLower = (lane & j) == 0;
              {
                unsigned long long prt = __shfl_xor(key0, j);
                bool desc = ((lane & k) == 0);
                bool keepMax = (iLower == desc);
                key0 = keepMax ? (key0 > prt ? key0 : prt) : (key0 < prt ? key0 : prt);
              }
              {
                unsigned long long prt = __shfl_xor(key1, j);
                int e1 = lane + 64;
                bool desc = ((e1 & k) == 0);
                bool keepMax = (iLower == desc);
                key1 = keepMax ? (key1 > prt ? key1 : prt) : (key1 < prt ? key1 : prt);
              }
            }
          }
        }
        int e = (int)(0xFFFFFFFFu - (unsigned)(key0 & 0xFFFFFFFFull));
        seli[lane] = posi[e];
        selv[lane] = posv[e];
        nsel = 64;
        __syncthreads();
      } else if (P <= PCAP) {
        for (int r = 0; r < 64; ++r) {
          unsigned long long best = 0ull;
          for (int j = lane; j < P; j += 64) {
            float v = posv[j];
            if (v > 0.0f) {
              unsigned long long key =
                  ((unsigned long long)ford(v) << 32) | (unsigned)(0xFFFFFFFFu - (unsigned)j);
              if (key > best) best = key;
            }
          }
          best = wave_max_u64(best);
          int j = (int)(0xFFFFFFFFu - (unsigned)(best & 0xFFFFFFFFull));
          if (lane == (j & 63)) {
            seli[r] = posi[j]; selv[r] = posv[j]; posv[j] = -INFINITY;
          }
          __syncthreads();
        }
        nsel = 64;
      } else {
        fullpath = true;
      }
    } else {
      if (lane < P) { seli[lane] = posi[lane]; selv[lane] = posv[lane]; }
      int need = 64 - P;
      int zbase = 0;
      bool done = false;
      for (int s0 = 0; s0 < Vn && !done; s0 += 64) {
        int s = s0 + lane;
        bool isz = (s < Vn) && (sc[s] == 0.0f);
        unsigned long long zm = __ballot(isz);
        int pre = __popcll(zm & lmlt);
        if (isz && (zbase + pre) < need) {
          seli[P + zbase + pre] = s;
          selv[P + zbase + pre] = 0.0f;
        }
        zbase += __popcll(zm);
        if (zbase >= need) done = true;
      }
      if (zbase >= need) {
        nsel = 64;
        __syncthreads();
      } else {
        fullpath = true;
      }
    }

    if (fullpath) {
      __syncthreads();
      nsel = 64;
      for (int r = 0; r < 64; ++r) {
        unsigned long long best = 0ull;
        for (int s = lane; s < Vn; s += 64) {
          float v = sc[s];
          if (v != -INFINITY) {
            unsigned long long key =
                ((unsigned long long)ford(v) << 32) | (unsigned)(0x7FFFFFFFu - (unsigned)s);
            if (key > best) best = key;
          }
        }
        best = wave_max_u64(best);
        if (best == 0ull) { nsel = r; break; }
        int s = (int)(0x7FFFFFFFu - (unsigned)(best & 0xFFFFFFFFull));
        if (lane == (s & 63)) {
          seli[r] = s; selv[r] = sc[s]; sc[s] = -INFINITY;
        }
        __syncthreads();
      }
    }
  }

  float v = (lane < nsel) ? selv[lane] : -INFINITY;
  float m = wave_max_f(v);
  float w = (lane < nsel) ? expf(v - m) : 0.0f;
  float ds = wave_sum_f(w);
  wsel[lane] = w / ds;   // == 0 for lane >= nsel
  __syncthreads();

  float o = 0.0f;
#pragma unroll 4
  for (int r = 0; r < 64; ++r)
    o = fmaf(wsel[r], V[(size_t)seli[r] * D_MODEL + hoff + lane], o);

  size_t oidx = (size_t)t * D_MODEL + hoff + lane;
  if (Of) Of[oidx] = o;
  if (Oh) {
    unsigned short hh = f2bf(o);
    Oh[oidx] = hh;
    Ol[oidx] = f2bf(o - bf2f(hh));
  }
}

// ============ single bf16 MFMA GEMM (NT): C[M,N] = A @ B^T ============
template <int FLAGS, typename CT, bool SWAPXY = false>
__global__ __launch_bounds__(256) void gemm_bt_bf16(const unsigned short* __restrict__ A,
    const unsigned short* __restrict__ B, CT* __restrict__ C,
    const float* __restrict__ bias, const float* __restrict__ res, int M, int N, int K) {
  constexpr bool HAS_BIAS = (FLAGS & 1) != 0;
  constexpr bool HAS_GELU = (FLAGS & 2) != 0;
  constexpr bool HAS_RES = (FLAGS & 4) != 0;
  __shared__ unsigned short As[128 * 32];
  __shared__ unsigned short Bs[128 * 32];
  int tid = threadIdx.x;
  int lane = tid & 63, wid = tid >> 6;
  int wr = wid >> 1, wc = wid & 1;
  int m0 = (SWAPXY ? blockIdx.x : blockIdx.y) * 128;
  int n0 = (SWAPXY ? blockIdx.y : blockIdx.x) * 128;

  int r_in = lane >> 2;
  int slot = lane & 3;

  f32x4 acc[4][4] = {};

  int fr = lane & 15;
  int ksl = lane >> 4;

  for (int k0 = 0; k0 < K; k0 += 32) {
#pragma unroll
    for (int s = 0; s < 2; ++s) {
      int row = wid * 32 + s * 16 + r_in;
      int ksw = (slot ^ ((row >> 1) & 3)) * 8;
      const unsigned short* ga = A + (size_t)(m0 + row) * K + k0 + ksw;
      const unsigned short* gb = B + (size_t)(n0 + row) * K + k0 + ksw;
      gload_lds16(ga, &As[(wid * 32 + s * 16) * 32]);
      gload_lds16(gb, &Bs[(wid * 32 + s * 16) * 32]);
    }
    asm volatile("s_waitcnt vmcnt(0)" ::: "memory");
    __syncthreads();

    s16x8 av[4], bv[4];
#pragma unroll
    for (int mi = 0; mi < 4; ++mi) {
      int ar = wr * 64 + mi * 16 + fr;
      av[mi] = *(const s16x8*)&As[ar * 32 + ((ksl ^ ((ar >> 1) & 3)) * 8)];
    }
#pragma unroll
    for (int ni = 0; ni < 4; ++ni) {
      int br = wc * 64 + ni * 16 + fr;
      bv[ni] = *(const s16x8*)&Bs[br * 32 + ((ksl ^ ((br >> 1) & 3)) * 8)];
    }
#pragma unroll
    for (int mi = 0; mi < 4; ++mi)
#pragma unroll
      for (int ni = 0; ni < 4; ++ni)
        acc[mi][ni] = __builtin_amdgcn_mfma_f32_16x16x32_bf16(av[mi], bv[ni], acc[mi][ni], 0, 0, 0);
    __syncthreads();
  }

  int cr = lane >> 4, cc = lane & 15;
#pragma unroll
  for (int mi = 0; mi < 4; ++mi) {
#pragma unroll
    for (int j = 0; j < 4; ++j) {
      int row = m0 + wr * 64 + mi * 16 + cr * 4 + j;
#pragma unroll
      for (int ni = 0; ni < 4; ++ni) {
        int col = n0 + wc * 64 + ni * 16 + cc;
        float vv = acc[mi][ni][j];
        if (HAS_BIAS) vv += bias[col];
        if (HAS_GELU) vv = 0.5f * vv * (1.0f + erff(vv * 0.70710678118654752f));
        if (HAS_RES) vv += res[(size_t)row * N + col];
        if constexpr (sizeof(CT) == 2)
          C[(size_t)row * N + col] = (CT)f2bf(vv);
        else
          C[(size_t)row * N + col] = (CT)vv;
      }
    }
  }
}

// ============ bf16x3 split-precision MFMA GEMM (NT) ============
template <int FLAGS, int OUTMODE>
__global__ __launch_bounds__(256) void gemm3_bt(
    const unsigned short* __restrict__ Ah, const unsigned short* __restrict__ Al,
    const unsigned short* __restrict__ Bh, const unsigned short* __restrict__ Bl,
    float* __restrict__ Cf, unsigned short* __restrict__ Ch, unsigned short* __restrict__ Cl,
    const float* __restrict__ bias, const float* __restrict__ res, int M, int N, int K) {
  constexpr bool HAS_BIAS = (FLAGS & 1) != 0;
  constexpr bool HAS_GELU = (FLAGS & 2) != 0;
  constexpr bool HAS_RES = (FLAGS & 4) != 0;
  __shared__ unsigned short As[2][128 * 32];
  __shared__ unsigned short Bs[2][128 * 32];
  int tid = threadIdx.x;
  int lane = tid & 63, wid = tid >> 6;
  int wr = wid >> 1, wc = wid & 1;
  int m0 = blockIdx.y * 128, n0 = blockIdx.x * 128;

  int r_in = lane >> 2;
  int slot = lane & 3;

  f32x4 acc[4][4] = {};

  int fr = lane & 15;
  int ksl = lane >> 4;

  for (int k0 = 0; k0 < K; k0 += 32) {
#pragma unroll
    for (int s = 0; s < 2; ++s) {
      int row = wid * 32 + s * 16 + r_in;
      int ksw = (slot ^ ((row >> 1) & 3)) * 8;
      size_t ao = (size_t)(m0 + row) * K + k0 + ksw;
      size_t bo = (size_t)(n0 + row) * K + k0 + ksw;
      int ldst = (wid * 32 + s * 16) * 32;
      gload_lds16(Ah + ao, &As[0][ldst]);
      gload_lds16(Al + ao, &As[1][ldst]);
      gload_lds16(Bh + bo, &Bs[0][ldst]);
      gload_lds16(Bl + bo, &Bs[1][ldst]);
    }
    asm volatile("s_waitcnt vmcnt(0)" ::: "memory");
    __syncthreads();

    s16x8 avh[4], avl[4], bvh[4], bvl[4];
#pragma unroll
    for (int mi = 0; mi < 4; ++mi) {
      int ar = wr * 64 + mi * 16 + fr;
      int off = ar * 32 + ((ksl ^ ((ar >> 1) & 3)) * 8);
      avh[mi] = *(const s16x8*)&As[0][off];
      avl[mi] = *(const s16x8*)&As[1][off];
    }
#pragma unroll
    for (int ni = 0; ni < 4; ++ni) {
      int br = wc * 64 + ni * 16 + fr;
      int off = br * 32 + ((ksl ^ ((br >> 1) & 3)) * 8);
      bvh[ni] = *(const s16x8*)&Bs[0][off];
      bvl[ni] = *(const s16x8*)&Bs[1][off];
    }
#pragma unroll
    for (int mi = 0; mi < 4; ++mi)
#pragma unroll
      for (int ni = 0; ni < 4; ++ni) {
        acc[mi][ni] = __builtin_amdgcn_mfma_f32_16x16x32_bf16(avh[mi], bvh[ni], acc[mi][ni], 0, 0, 0);
        acc[mi][ni] = __builtin_amdgcn_mfma_f32_16x16x32_bf16(avl[mi], bvh[ni], acc[mi][ni], 0, 0, 0);
        acc[mi][ni] = __builtin_amdgcn_mfma_f32_16x16x32_bf16(avh[mi], bvl[ni], acc[mi][ni], 0, 0, 0);
      }
    __syncthreads();
  }

  int cr = lane >> 4, cc = lane & 15;
#pragma unroll
  for (int mi = 0; mi < 4; ++mi) {
#pragma unroll
    for (int j = 0; j < 4; ++j) {
      int row = m0 + wr * 64 + mi * 16 + cr * 4 + j;
#pragma unroll
      for (int ni = 0; ni < 4; ++ni) {
        int col = n0 + wc * 64 + ni * 16 + cc;
        float vv = acc[mi][ni][j];
        if (HAS_BIAS) vv += bias[col];
        if (HAS_GELU) vv = 0.5f * vv * (1.0f + erff(vv * 0.70710678118654752f));
        if (HAS_RES) vv += res[(size_t)row * N + col];
        if constexpr (OUTMODE == 0) {
          Cf[(size_t)row * N + col] = vv;
        } else {
          unsigned short h = f2bf(vv);
          Ch[(size_t)row * N + col] = h;
          Cl[(size_t)row * N + col] = f2bf(vv - bf2f(h));
        }
      }
    }
  }
}

// ============ bf16x3 fused QKV (NT): [q|k|v] = xn @ [Wq^T|Wk^T|Wv^T], fp32 out ====
// B matrices pre-transposed to [N][K] hi/lo. Each 128-wide N-tile lies in one matrix.
__global__ __launch_bounds__(256) void gemm3_qkv(
    const unsigned short* __restrict__ Ah, const unsigned short* __restrict__ Al,
    const unsigned short* __restrict__ Bqh, const unsigned short* __restrict__ Bql,
    const unsigned short* __restrict__ Bkh, const unsigned short* __restrict__ Bkl,
    const unsigned short* __restrict__ Bvh, const unsigned short* __restrict__ Bvl,
    float* __restrict__ C, int M, int K) {
  __shared__ unsigned short As[2][128 * 32];
  __shared__ unsigned short Bs[2][128 * 32];
  int tid = threadIdx.x;
  int lane = tid & 63, wid = tid >> 6;
  int wr = wid >> 1, wc = wid & 1;
  int m0 = blockIdx.y * 128;
  int n0g = blockIdx.x * 128;
  int mat = n0g >> 10;               // 0,1,2
  const unsigned short* Bh = (mat == 0) ? Bqh : (mat == 1 ? Bkh : Bvh);
  const unsigned short* Bl = (mat == 0) ? Bql : (mat == 1 ? Bkl : Bvl);
  float* Cb = C + (size_t)mat * ((size_t)M * 1024);
  int n0 = n0g & 1023;

  int r_in = lane >> 2;
  int slot = lane & 3;

  f32x4 acc[4][4] = {};

  int fr = lane & 15;
  int ksl = lane >> 4;

  for (int k0 = 0; k0 < K; k0 += 32) {
#pragma unroll
    for (int s = 0; s < 2; ++s) {
      int row = wid * 32 + s * 16 + r_in;
      int ksw = (slot ^ ((row >> 1) & 3)) * 8;
      size_t ao = (size_t)(m0 + row) * K + k0 + ksw;
      size_t bo = (size_t)(n0 + row) * K + k0 + ksw;
      int ldst = (wid * 32 + s * 16) * 32;
      gload_lds16(Ah + ao, &As[0][ldst]);
      gload_lds16(Al + ao, &As[1][ldst]);
      gload_lds16(Bh + bo, &Bs[0][ldst]);
      gload_lds16(Bl + bo, &Bs[1][ldst]);
    }
    asm volatile("s_waitcnt vmcnt(0)" ::: "memory");
    __syncthreads();

    s16x8 avh[4], avl[4], bvh[4], bvl[4];
#pragma unroll
    for (int mi = 0; mi < 4; ++mi) {
      int ar = wr * 64 + mi * 16 + fr;
      int off = ar * 32 + ((ksl ^ ((ar >> 1) & 3)) * 8);
      avh[mi] = *(const s16x8*)&As[0][off];
      avl[mi] = *(const s16x8*)&As[1][off];
    }
#pragma unroll
    for (int ni = 0; ni < 4; ++ni) {
      int br = wc * 64 + ni * 16 + fr;
      int off = br * 32 + ((ksl ^ ((br >> 1) & 3)) * 8);
      bvh[ni] = *(const s16x8*)&Bs[0][off];
      bvl[ni] = *(const s16x8*)&Bs[1][off];
    }
#pragma unroll
    for (int mi = 0; mi < 4; ++mi)
#pragma unroll
      for (int ni = 0; ni < 4; ++ni) {
        acc[mi][ni] = __builtin_amdgcn_mfma_f32_16x16x32_bf16(avh[mi], bvh[ni], acc[mi][ni], 0, 0, 0);
        acc[mi][ni] = __builtin_amdgcn_mfma_f32_16x16x32_bf16(avl[mi], bvh[ni], acc[mi][ni], 0, 0, 0);
        acc[mi][ni] = __builtin_amdgcn_mfma_f32_16x16x32_bf16(avh[mi], bvl[ni], acc[mi][ni], 0, 0, 0);
      }
    __syncthreads();
  }

  int cr = lane >> 4, cc = lane & 15;
#pragma unroll
  for (int mi = 0; mi < 4; ++mi) {
#pragma unroll
    for (int j = 0; j < 4; ++j) {
      int row = m0 + wr * 64 + mi * 16 + cr * 4 + j;
#pragma unroll
      for (int ni = 0; ni < 4; ++ni) {
        int col = n0 + wc * 64 + ni * 16 + cc;
        Cb[(size_t)row * 1024 + col] = acc[mi][ni][j];
      }
    }
  }
}

// ---------------- fp32 tiled GEMM (NN, fallback) ----------------
template <int FLAGS>
__global__ __launch_bounds__(256) void gemm_nn(const float* __restrict__ A,
    const float* __restrict__ B, float* __restrict__ C, const float* __restrict__ bias,
    const float* __restrict__ res, int M, int N, int K) {
  constexpr bool HAS_BIAS = (FLAGS & 1) != 0;
  constexpr bool HAS_GELU = (FLAGS & 2) != 0;
  constexpr bool HAS_RES = (FLAGS & 4) != 0;
  __shared__ float As[16][68];
  __shared__ float Bs[16][68];
  int tid = threadIdx.x;
  int m0 = blockIdx.y * 64, n0 = blockIdx.x * 64;
  int tx = tid & 15, ty = tid >> 4;
  int am = tid >> 2, ak = (tid & 3) * 4;
  int bk = tid >> 4, bn = (tid & 15) * 4;
  const float* Ap = A + (size_t)(m0 + am) * K + ak;
  const float* Bp = B + (size_t)bk * N + n0 + bn;
  float acc[4][4] = {};
  for (int k0 = 0; k0 < K; k0 += 16) {
    float4 a4 = *(const float4*)(Ap + k0);
    float4 b4 = *(const float4*)(Bp + (size_t)k0 * N);
    As[ak + 0][am] = a4.x; As[ak + 1][am] = a4.y;
    As[ak + 2][am] = a4.z; As[ak + 3][am] = a4.w;
    *(float4*)&Bs[bk][bn] = b4;
    __syncthreads();
#pragma unroll
    for (int k = 0; k < 16; ++k) {
      float4 bq = *(const float4*)&Bs[k][tx * 4];
#pragma unroll
      for (int i = 0; i < 4; ++i) {
        float av = As[k][ty * 4 + i];
        acc[i][0] += av * bq.x; acc[i][1] += av * bq.y;
        acc[i][2] += av * bq.z; acc[i][3] += av * bq.w;
      }
    }
    __syncthreads();
  }
#pragma unroll
  for (int i = 0; i < 4; ++i) {
    int row = m0 + ty * 4 + i;
#pragma unroll
    for (int j = 0; j < 4; ++j) {
      int col = n0 + tx * 4 + j;
      float vv = acc[i][j];
      if (HAS_BIAS) vv += bias[col];
      if (HAS_GELU) vv = 0.5f * vv * (1.0f + erff(vv * 0.70710678118654752f));
      if (HAS_RES) vv += res[(size_t)row * N + col];
      C[(size_t)row * N + col] = vv;
    }
  }
}

// ---------------- fp32 tiled GEMM (NT, fallback logits) ----------------
template <int FLAGS>
__global__ __launch_bounds__(256) void gemm_nt(const float* __restrict__ A,
    const float* __restrict__ B, float* __restrict__ C, const float* __restrict__ bias,
    const float* __restrict__ res, int M, int N, int K) {
  constexpr bool HAS_BIAS = (FLAGS & 1) != 0;
  constexpr bool HAS_GELU = (FLAGS & 2) != 0;
  constexpr bool HAS_RES = (FLAGS & 4) != 0;
  __shared__ float As[16][68];
  __shared__ float Bs[16][68];
  int tid = threadIdx.x;
  int m0 = blockIdx.y * 64, n0 = blockIdx.x * 64;
  int tx = tid & 15, ty = tid >> 4;
  int am = tid >> 2, ak = (tid & 3) * 4;
  int bn2 = tid >> 2, bk2 = (tid & 3) * 4;
  const float* Ap = A + (size_t)(m0 + am) * K + ak;
  const float* Bp = B + (size_t)(n0 + bn2) * K + bk2;
  float acc[4][4] = {};
  for (int k0 = 0; k0 < K; k0 += 16) {
    float4 a4 = *(const float4*)(Ap + k0);
    float4 b4 = *(const float4*)(Bp + k0);
    As[ak + 0][am] = a4.x; As[ak + 1][am] = a4.y;
    As[ak + 2][am] = a4.z; As[ak + 3][am] = a4.w;
    Bs[bk2 + 0][bn2] = b4.x; Bs[bk2 + 1][bn2] = b4.y;
    Bs[bk2 + 2][bn2] = b4.z; Bs[bk2 + 3][bn2] = b4.w;
    __syncthreads();
#pragma unroll
    for (int k = 0; k < 16; ++k) {
      float4 bq = *(const float4*)&Bs[k][tx * 4];
#pragma unroll
      for (int i = 0; i < 4; ++i) {
        float av = As[k][ty * 4 + i];
        acc[i][0] += av * bq.x; acc[i][1] += av * bq.y;
        acc[i][2] += av * bq.z; acc[i][3] += av * bq.w;
      }
    }
    __syncthreads();
  }
#pragma unroll
  for (int i = 0; i < 4; ++i) {
    int row = m0 + ty * 4 + i;
#pragma unroll
    for (int j = 0; j < 4; ++j) {
      int col = n0 + tx * 4 + j;
      float vv = acc[i][j];
      if (HAS_BIAS) vv += bias[col];
      if (HAS_GELU) vv = 0.5f * vv * (1.0f + erff(vv * 0.70710678118654752f));
      if (HAS_RES) vv += res[(size_t)row * N + col];
      C[(size_t)row * N + col] = vv;
    }
  }
}

// ---------------- host orchestration ----------------
extern "C" void kernel_launch(void* const* d_in, const int* in_sizes, int n_in,
                              void* d_out, int out_size, void* d_ws, size_t ws_size,
                              hipStream_t stream) {
  const int* ids = (const int*)d_in[0];
  const float* Wemb = (const float*)d_in[1];
  const float* Wpos = (const float*)d_in[2];
  const float* ln1_g = (const float*)d_in[3];
  const float* ln1_b = (const float*)d_in[4];
  const float* Wq = (const float*)d_in[5];
  const float* Wk = (const float*)d_in[6];
  const float* Wv = (const float*)d_in[7];
  const float* Wo = (const float*)d_in[8];
  const float* ln2_g = (const float*)d_in[9];
  const float* ln2_b = (const float*)d_in[10];
  const float* W1 = (const float*)d_in[11];
  const float* b1 = (const float*)d_in[12];
  const float* W2 = (const float*)d_in[13];
  const float* b2 = (const float*)d_in[14];
  const float* lnf_g = (const float*)d_in[15];
  const float* lnf_b = (const float*)d_in[16];

  const int T = in_sizes[0];          // 2048
  const int D = D_MODEL;
  const int VOC = in_sizes[1] / D;    // 32000

  // workspace layout (bytes):
  // 0    x (8MB)     8M  xnbh(4MB)+xnbl(4MB) | xn fp32 (fallback)
  // 16M  q (8MB)     24M k (8MB)   32M v (8MB)   40M kt (8MB)
  //      (w1th/w1tl/w2th/w2tl overlay 16M..48M during MLP)
  // 48M  hbh (16MB) | qkv weight hi/lo transposes (12MB) during attention phase
  // 64M  hbl (16MB)
  // 80M  woth (2MB)  82M wotl (2MB)
  // 16M..80M wembb (64MB, after layer loop)
  char* ws = (char*)d_ws;
  float* x = (float*)(ws);
  float* xn = (float*)(ws + 8388608ull);
  unsigned short* xnbh = (unsigned short*)(ws + 8388608ull);
  unsigned short* xnbl = (unsigned short*)(ws + 12582912ull);
  float* q = (float*)(ws + 16777216ull);
  float* k = (float*)(ws + 25165824ull);
  float* v = (float*)(ws + 33554432ull);
  float* kt = (float*)(ws + 41943040ull);
  unsigned short* w1th = (unsigned short*)(ws + 16777216ull);
  unsigned short* w1tl = (unsigned short*)(ws + 25165824ull);
  unsigned short* w2th = (unsigned short*)(ws + 33554432ull);
  unsigned short* w2tl = (unsigned short*)(ws + 41943040ull);
  unsigned short* hbh = (unsigned short*)(ws + 50331648ull);
  unsigned short* hbl = (unsigned short*)(ws + 67108864ull);
  unsigned short* wqth = (unsigned short*)(ws + 50331648ull);   // overlay hbh (dead)
  unsigned short* wqtl = (unsigned short*)(ws + 52428800ull);
  unsigned short* wkth = (unsigned short*)(ws + 54525952ull);
  unsigned short* wktl = (unsigned short*)(ws + 56623104ull);
  unsigned short* wvth = (unsigned short*)(ws + 58720256ull);
  unsigned short* wvtl = (unsigned short*)(ws + 60817408ull);
  unsigned short* woth = (unsigned short*)(ws + 83886080ull);
  unsigned short* wotl = (unsigned short*)(ws + 85983232ull);
  unsigned short* wembb = (unsigned short*)(ws + 16777216ull);
  const size_t NEED = 88080384ull;  // 84 MB

  int kkeep = (T < 64) ? T : 64;
  int fk = (HEAD_DIM * kkeep + T - 1) / T;
  if (fk < 1) fk = 1;
  int nseg = T * N_HEADS;

  embed_kernel<<<T, 256, 0, stream>>>(ids, Wemb, Wpos, x);

  if (ws_size >= NEED && (T % 128) == 0 && (VOC % 128) == 0 &&
      (size_t)VOC * D * 2 <= 67108864ull) {
    // ---- bf16 MFMA path ----
    for (int l = 0; l < 2; ++l) {
      const float* wq = Wq + (size_t)l * D * D;
      const float* wk = Wk + (size_t)l * D * D;
      const float* wv = Wv + (size_t)l * D * D;
      const float* wo = Wo + (size_t)l * D * D;

      // LN1 -> bf16 hi/lo
      ln_kernel<<<T, 256, 0, stream>>>(x, nullptr, xnbh, xnbl,
                                       ln1_g + (size_t)l * D, ln1_b + (size_t)l * D);

      // Wq/Wk/Wv -> [N][K] bf16 hi/lo
      transpose_conv_pair_kernel<<<dim3(D / 32, D / 32), 256, 0, stream>>>(wq, wqth, wqtl, D, D);
      transpose_conv_pair_kernel<<<dim3(D / 32, D / 32), 256, 0, stream>>>(wk, wkth, wktl, D, D);
      transpose_conv_pair_kernel<<<dim3(D / 32, D / 32), 256, 0, stream>>>(wv, wvth, wvtl, D, D);

      // fused bf16x3 QKV -> q,k,v fp32
      gemm3_qkv<<<dim3(3 * D / 128, T / 128), 256, 0, stream>>>(
          xnbh, xnbl, wqth, wqtl, wkth, wktl, wvth, wvtl, q, T, D);

      sparsify_kernel<<<(3 * nseg + 3) / 4, 256, 0, stream>>>(q, 3 * nseg, fk);

      transpose_kernel<<<dim3(D / 32, T / 32), 256, 0, stream>>>(k, kt, T, D);

      attn_kernel<<<T * N_HEADS, 64, 0, stream>>>(q, kt, v, nullptr, xnbh, xnbl, T);

      transpose_conv_pair_kernel<<<dim3(D / 32, D / 32), 256, 0, stream>>>(wo, woth, wotl, D, D);
      gemm3_bt<4, 0><<<dim3(D / 128, T / 128), 256, 0, stream>>>(
          xnbh, xnbl, woth, wotl, x, nullptr, nullptr, nullptr, x, T, D, D);

      ln_kernel<<<T, 256, 0, stream>>>(x, nullptr, xnbh, xnbl,
                                       ln2_g + (size_t)l * D, ln2_b + (size_t)l * D);

      transpose_conv_pair_kernel<<<dim3(HIDDEN / 32, D / 32), 256, 0, stream>>>(
          W1 + (size_t)l * D * HIDDEN, w1th, w1tl, D, HIDDEN);
      gemm3_bt<3, 1><<<dim3(HIDDEN / 128, T / 128), 256, 0, stream>>>(
          xnbh, xnbl, w1th, w1tl, nullptr, hbh, hbl,
          b1 + (size_t)l * HIDDEN, nullptr, T, HIDDEN, D);
      transpose_conv_pair_kernel<<<dim3(D / 32, HIDDEN / 32), 256, 0, stream>>>(
          W2 + (size_t)l * HIDDEN * D, w2th, w2tl, HIDDEN, D);
      gemm3_bt<5, 0><<<dim3(D / 128, T / 128), 256, 0, stream>>>(
          hbh, hbl, w2th, w2tl, x, nullptr, nullptr,
          b2 + (size_t)l * D, x, T, D, HIDDEN);
    }

    ln_kernel<<<T, 256, 0, stream>>>(x, nullptr, xnbh, nullptr, lnf_g, lnf_b);

    conv_bf16_kernel<<<4096, 256, 0, stream>>>(Wemb, wembb, (size_t)VOC * D);

    gemm_bt_bf16<0, float, true><<<dim3(T / 128, VOC / 128), 256, 0, stream>>>(
        xnbh, wembb, (float*)d_out, nullptr, nullptr, T, VOC, D);
  } else {
    // ---- fp32 fallback ----
    float* hbuf = q;
    for (int l = 0; l < 2; ++l) {
      const float* wq = Wq + (size_t)l * D * D;
      const float* wk = Wk + (size_t)l * D * D;
      const float* wv = Wv + (size_t)l * D * D;
      const float* wo = Wo + (size_t)l * D * D;

      ln_kernel<<<T, 256, 0, stream>>>(x, xn, nullptr, nullptr,
                                       ln1_g + (size_t)l * D, ln1_b + (size_t)l * D);

      dim3 g1(D / 64, T / 64);
      gemm_nn<0><<<g1, 256, 0, stream>>>(xn, wq, q, nullptr, nullptr, T, D, D);
      gemm_nn<0><<<g1, 256, 0, stream>>>(xn, wk, k, nullptr, nullptr, T, D, D);
      gemm_nn<0><<<g1, 256, 0, stream>>>(xn, wv, v, nullptr, nullptr, T, D, D);

      sparsify_kernel<<<(nseg + 3) / 4, 256, 0, stream>>>(q, nseg, fk);
      sparsify_kernel<<<(nseg + 3) / 4, 256, 0, stream>>>(k, nseg, fk);
      sparsify_kernel<<<(nseg + 3) / 4, 256, 0, stream>>>(v, nseg, fk);

      transpose_kernel<<<dim3(D / 32, T / 32), 256, 0, stream>>>(k, kt, T, D);

      attn_kernel<<<T * N_HEADS, 64, 0, stream>>>(q, kt, v, xn, nullptr, nullptr, T);

      gemm_nn<4><<<g1, 256, 0, stream>>>(xn, wo, x, nullptr, x, T, D, D);

      ln_kernel<<<T, 256, 0, stream>>>(x, xn, nullptr, nullptr,
                                       ln2_g + (size_t)l * D, ln2_b + (size_t)l * D);

      gemm_nn<3><<<dim3(HIDDEN / 64, T / 64), 256, 0, stream>>>(
          xn, W1 + (size_t)l * D * HIDDEN, hbuf, b1 + (size_t)l * HIDDEN, nullptr, T, HIDDEN, D);
      gemm_nn<5><<<g1, 256, 0, stream>>>(
          hbuf, W2 + (size_t)l * HIDDEN * D, x, b2 + (size_t)l * D, x, T, D, HIDDEN);
    }

    ln_kernel<<<T, 256, 0, stream>>>(x, xn, nullptr, nullptr, lnf_g, lnf_b);

    gemm_nt<0><<<dim3(VOC / 64, T / 64), 256, 0, stream>>>(
        xn, Wemb, (float*)d_out, nullptr, nullptr, T, VOC, D);
  }
}

// Round 11
// 1389.337 us; speedup vs baseline: 1.4204x; 1.0277x over previous
//
#include <hip/hip_runtime.h>
#include <math.h>

#define D_MODEL 1024
#define N_HEADS 16
#define HEAD_DIM 64
#define HIDDEN 4096
#define TMAX 2048

typedef __attribute__((ext_vector_type(8))) short s16x8;
typedef __attribute__((ext_vector_type(4))) float f32x4;

// ---------------- wave helpers (wave64) ----------------
__device__ __forceinline__ float wave_max_f(float v) {
#pragma unroll
  for (int o = 32; o > 0; o >>= 1) v = fmaxf(v, __shfl_xor(v, o));
  return v;
}
__device__ __forceinline__ float wave_sum_f(float v) {
#pragma unroll
  for (int o = 32; o > 0; o >>= 1) v += __shfl_xor(v, o);
  return v;
}
__device__ __forceinline__ unsigned long long wave_max_u64(unsigned long long k) {
#pragma unroll
  for (int o = 32; o > 0; o >>= 1) {
    unsigned long long u = __shfl_xor(k, o);
    if (u > k) k = u;
  }
  return k;
}
__device__ __forceinline__ unsigned ford(float v) {
  unsigned u = __float_as_uint(v);
  return (u & 0x80000000u) ? ~u : (u | 0x80000000u);
}
// fp32 -> bf16 RNE
__device__ __forceinline__ unsigned short f2bf(float f) {
  unsigned u = __float_as_uint(f);
  u += 0x7FFFu + ((u >> 16) & 1u);
  return (unsigned short)(u >> 16);
}
__device__ __forceinline__ float bf2f(unsigned short h) {
  return __uint_as_float((unsigned)h << 16);
}

__device__ __forceinline__ void gload_lds16(const void* g, void* l) {
  __builtin_amdgcn_global_load_lds(
      (const __attribute__((address_space(1))) void*)g,
      (__attribute__((address_space(3))) void*)l, 16, 0, 0);
}

// ---------------- embedding ----------------
__global__ __launch_bounds__(256) void embed_kernel(const int* __restrict__ ids,
    const float* __restrict__ Wemb, const float* __restrict__ Wpos, float* __restrict__ X) {
  int t = blockIdx.x, tid = threadIdx.x;
  int id = ids[t];
  float4 e = ((const float4*)(Wemb + (size_t)id * D_MODEL))[tid];
  float4 p = ((const float4*)(Wpos + (size_t)t * D_MODEL))[tid];
  e.x += p.x; e.y += p.y; e.z += p.z; e.w += p.w;
  ((float4*)(X + (size_t)t * D_MODEL))[tid] = e;
}

// ---------------- layernorm; optional fp32 out + bf16 hi/lo out ----------------
__global__ __launch_bounds__(256) void ln_kernel(const float* __restrict__ X,
    float* __restrict__ Y, unsigned short* __restrict__ Ybh, unsigned short* __restrict__ Ybl,
    const float* __restrict__ g, const float* __restrict__ b) {
  int row = blockIdx.x, tid = threadIdx.x;
  int lane = tid & 63, wid = tid >> 6;
  __shared__ float red[8];
  float4 v = ((const float4*)(X + (size_t)row * D_MODEL))[tid];
  float s = v.x + v.y + v.z + v.w;
  s = wave_sum_f(s);
  if (lane == 0) red[wid] = s;
  __syncthreads();
  float mean = (red[0] + red[1] + red[2] + red[3]) * (1.0f / D_MODEL);
  float dx = v.x - mean, dy = v.y - mean, dz = v.z - mean, dw = v.w - mean;
  float q = dx * dx + dy * dy + dz * dz + dw * dw;
  q = wave_sum_f(q);
  if (lane == 0) red[4 + wid] = q;
  __syncthreads();
  float var = (red[4] + red[5] + red[6] + red[7]) * (1.0f / D_MODEL);
  float rs = rsqrtf(var + 1e-5f);
  float4 gg = ((const float4*)g)[tid], bb = ((const float4*)b)[tid];
  float4 y;
  y.x = dx * rs * gg.x + bb.x;
  y.y = dy * rs * gg.y + bb.y;
  y.z = dz * rs * gg.z + bb.z;
  y.w = dw * rs * gg.w + bb.w;
  if (Y) ((float4*)(Y + (size_t)row * D_MODEL))[tid] = y;
  if (Ybh) {
    ushort4 oh;
    oh.x = f2bf(y.x); oh.y = f2bf(y.y); oh.z = f2bf(y.z); oh.w = f2bf(y.w);
    ((ushort4*)(Ybh + (size_t)row * D_MODEL))[tid] = oh;
    if (Ybl) {
      ushort4 ol;
      ol.x = f2bf(y.x - bf2f(oh.x)); ol.y = f2bf(y.y - bf2f(oh.y));
      ol.z = f2bf(y.z - bf2f(oh.z)); ol.w = f2bf(y.w - bf2f(oh.w));
      ((ushort4*)(Ybl + (size_t)row * D_MODEL))[tid] = ol;
    }
  }
}

// ---------------- sparsify (exact top-fk by |value| per 64 segment) ----------------
__global__ __launch_bounds__(256) void sparsify_kernel(float* __restrict__ X, int nseg, int fk) {
  int seg = blockIdx.x * 4 + (threadIdx.x >> 6);
  if (seg >= nseg) return;
  int lane = threadIdx.x & 63;
  size_t idx = (size_t)seg * 64 + lane;
  float x = X[idx];
  float a = fabsf(x);
  float cur = INFINITY;
  int remaining = fk;
  float thr = 0.0f;
  for (;;) {
    float cand = (a < cur) ? a : -INFINITY;
    float mv = wave_max_f(cand);
    if (mv == -INFINITY) { thr = mv; break; }
    int c = __popcll(__ballot(a == mv));
    if (c >= remaining) { thr = mv; break; }
    remaining -= c; cur = mv;
  }
  if (!(a >= thr)) X[idx] = 0.0f;
}

// ---------------- transpose fp32 [R][C] -> [C][R] ----------------
__global__ __launch_bounds__(256) void transpose_kernel(const float* __restrict__ in,
    float* __restrict__ out, int R, int Cc) {
  __shared__ float tile[32][33];
  int c0 = blockIdx.x * 32, r0 = blockIdx.y * 32;
  int tx = threadIdx.x & 31, ty = threadIdx.x >> 5;
  for (int i = ty; i < 32; i += 8)
    tile[i][tx] = in[(size_t)(r0 + i) * Cc + c0 + tx];
  __syncthreads();
  for (int i = ty; i < 32; i += 8)
    out[(size_t)(c0 + i) * R + r0 + tx] = tile[tx][i];
}

// ---------------- transpose-convert fp32 [R][C] -> bf16 hi/lo [C][R] ----------------
__global__ __launch_bounds__(256) void transpose_conv_pair_kernel(const float* __restrict__ in,
    unsigned short* __restrict__ oh, unsigned short* __restrict__ ol, int R, int Cc) {
  __shared__ float tile[32][33];
  int c0 = blockIdx.x * 32, r0 = blockIdx.y * 32;
  int tx = threadIdx.x & 31, ty = threadIdx.x >> 5;
  for (int i = ty; i < 32; i += 8)
    tile[i][tx] = in[(size_t)(r0 + i) * Cc + c0 + tx];
  __syncthreads();
  for (int i = ty; i < 32; i += 8) {
    float v = tile[tx][i];
    unsigned short h = f2bf(v);
    size_t idx = (size_t)(c0 + i) * R + r0 + tx;
    oh[idx] = h;
    ol[idx] = f2bf(v - bf2f(h));
  }
}

// ---------------- fp32 -> bf16 elementwise ----------------
__global__ __launch_bounds__(256) void conv_bf16_kernel(const float* __restrict__ in,
    unsigned short* __restrict__ out, size_t n) {
  size_t i = ((size_t)blockIdx.x * 256 + threadIdx.x) * 4;
  size_t stride = (size_t)gridDim.x * 1024;
  for (; i < n; i += stride) {
    float4 v = *(const float4*)(in + i);
    ushort4 o;
    o.x = f2bf(v.x); o.y = f2bf(v.y); o.z = f2bf(v.z); o.w = f2bf(v.w);
    *(ushort4*)(out + i) = o;
  }
}

// ---------------- attention: 2 waves per (head, query-row) job ----------------
// score pass + gather use both waves (128 lanes); selection runs verbatim on
// wave 0 (lockstep, no barriers needed); barrier count uniform on all paths.
__global__ __launch_bounds__(128) void attn_kernel(const float* __restrict__ Q,
    const float* __restrict__ Kt, const float* __restrict__ V,
    float* __restrict__ Of, unsigned short* __restrict__ Oh, unsigned short* __restrict__ Ol,
    int T) {
  int t = T - 1 - (blockIdx.x % T);   // longest jobs dispatch first
  int h = blockIdx.x / T;
  int tid = threadIdx.x;
  int lane = tid & 63;
  int wvid = tid >> 6;
  unsigned long long lmlt = (1ull << lane) - 1ull;

  __shared__ float sc[TMAX];
  __shared__ float qval[HEAD_DIM];
  __shared__ int qdim[HEAD_DIM];
  constexpr int PCAP = 320;
  __shared__ float posv[PCAP];
  __shared__ int posi[PCAP];
  __shared__ int seli[64];
  __shared__ float selv[64];
  __shared__ float wsel[64];
  __shared__ float partial[64];
  __shared__ int nq_sh;

  int hoff = h * HEAD_DIM;
  if (wvid == 0) {
    float qv = Q[(size_t)t * D_MODEL + hoff + lane];
    unsigned long long nzm = __ballot(qv != 0.0f);
    int nq0 = __popcll(nzm);
    if (qv != 0.0f) {
      int p = __popcll(nzm & lmlt);
      qval[p] = qv; qdim[p] = lane;
    }
    seli[lane] = 0;  // pad target for fixed-trip gather
    if (lane == 0) nq_sh = nq0;
  }
  __syncthreads();  // B1

  int nq = nq_sh;
  int Vn = t + 1;
  // ---- score pass over 128 lanes; per-score math identical ----
  if (nq == 2) {
    float qA = qval[0], qB = qval[1];
    const float* ktA = Kt + (size_t)(hoff + qdim[0]) * T;
    const float* ktB = Kt + (size_t)(hoff + qdim[1]) * T;
    for (int s = tid; s < Vn; s += 128)
      sc[s] = fmaf(qB, ktB[s], qA * ktA[s]) * 0.125f;
  } else {
    for (int s = tid; s < Vn; s += 128) {
      float acc = 0.0f;
      for (int j = 0; j < nq; ++j)
        acc += qval[j] * Kt[(size_t)(hoff + qdim[j]) * T + s];
      sc[s] = acc * 0.125f;
    }
  }
  __syncthreads();  // B2

  // ---- selection + softmax: wave 0 only (lockstep; no barriers inside) ----
  if (wvid == 0) {
    int nsel = 0;
    if (Vn <= 64) {
      nsel = Vn;
      if (lane < Vn) { seli[lane] = lane; selv[lane] = sc[lane]; }
    } else {
      // compact positive scores (list index order == s order)
      int base = 0;
      for (int s0 = 0; s0 < Vn; s0 += 64) {
        int s = s0 + lane;
        float v = (s < Vn) ? sc[s] : -1.0f;
        unsigned long long pm = __ballot(v > 0.0f);
        if (v > 0.0f) {
          int p = base + __popcll(pm & lmlt);
          if (p < PCAP) { posv[p] = v; posi[p] = s; }
        }
        base += __popcll(pm);
      }
      int P = base;

      bool fullpath = false;
      if (P >= 64) {
        if (P <= 128) {
          // ---- bitonic-128 top-64 ----
          unsigned long long key0, key1;
          {
            int e0 = lane, e1 = lane + 64;
            key0 = (e0 < P) ? (((unsigned long long)ford(posv[e0]) << 32) |
                               (unsigned long long)(0xFFFFFFFFu - (unsigned)e0)) : 0ull;
            key1 = (e1 < P) ? (((unsigned long long)ford(posv[e1]) << 32) |
                               (unsigned long long)(0xFFFFFFFFu - (unsigned)e1)) : 0ull;
          }
          for (int k = 2; k <= 128; k <<= 1) {
            for (int j = k >> 1; j > 0; j >>= 1) {
              if (j == 64) {
                if (key0 < key1) { unsigned long long tm = key0; key0 = key1; key1 = tm; }
              } else {
                bool iLower = (lane & j) == 0;
                {
                  unsigned long long prt = __shfl_xor(key0, j);
                  bool desc = ((lane & k) == 0);
                  bool keepMax = (iLower == desc);
                  key0 = keepMax ? (key0 > prt ? key0 : prt) : (key0 < prt ? key0 : prt);
                }
                {
                  unsigned long long prt = __shfl_xor(key1, j);
                  int e1 = lane + 64;
                  bool desc = ((e1 & k) == 0);
                  bool keepMax = (iLower == desc);
                  key1 = keepMax ? (key1 > prt ? key1 : prt) : (key1 < prt ? key1 : prt);
                }
              }
            }
          }
          int e = (int)(0xFFFFFFFFu - (unsigned)(key0 & 0xFFFFFFFFull));
          seli[lane] = posi[e];
          selv[lane] = posv[e];
          nsel = 64;
        } else if (P <= PCAP) {
          for (int r = 0; r < 64; ++r) {
            unsigned long long best = 0ull;
            for (int j = lane; j < P; j += 64) {
              float v = posv[j];
              if (v > 0.0f) {
                unsigned long long key =
                    ((unsigned long long)ford(v) << 32) | (unsigned)(0xFFFFFFFFu - (unsigned)j);
                if (key > best) best = key;
              }
            }
            best = wave_max_u64(best);
            int j = (int)(0xFFFFFFFFu - (unsigned)(best & 0xFFFFFFFFull));
            if (lane == (j & 63)) {
              seli[r] = posi[j]; selv[r] = posv[j]; posv[j] = -INFINITY;
            }
          }
          nsel = 64;
        } else {
          fullpath = true;
        }
      } else {
        if (lane < P) { seli[lane] = posi[lane]; selv[lane] = posv[lane]; }
        int need = 64 - P;
        int zbase = 0;
        bool done = false;
        for (int s0 = 0; s0 < Vn && !done; s0 += 64) {
          int s = s0 + lane;
          bool isz = (s < Vn) && (sc[s] == 0.0f);
          unsigned long long zm = __ballot(isz);
          int pre = __popcll(zm & lmlt);
          if (isz && (zbase + pre) < need) {
            seli[P + zbase + pre] = s;
            selv[P + zbase + pre] = 0.0f;
          }
          zbase += __popcll(zm);
          if (zbase >= need) done = true;
        }
        if (zbase >= need) {
          nsel = 64;
        } else {
          fullpath = true;
        }
      }

      if (fullpath) {
        nsel = 64;
        for (int r = 0; r < 64; ++r) {
          unsigned long long best = 0ull;
          for (int s = lane; s < Vn; s += 64) {
            float v = sc[s];
            if (v != -INFINITY) {
              unsigned long long key =
                  ((unsigned long long)ford(v) << 32) | (unsigned)(0x7FFFFFFFu - (unsigned)s);
              if (key > best) best = key;
            }
          }
          best = wave_max_u64(best);
          if (best == 0ull) { nsel = r; break; }
          int s = (int)(0x7FFFFFFFu - (unsigned)(best & 0xFFFFFFFFull));
          if (lane == (s & 63)) {
            seli[r] = s; selv[r] = sc[s]; sc[s] = -INFINITY;
          }
        }
      }
    }

    // softmax weights (wsel[lane]==0 for lane >= nsel)
    float v = (lane < nsel) ? selv[lane] : -INFINITY;
    float m = wave_max_f(v);
    float w = (lane < nsel) ? expf(v - m) : 0.0f;
    float ds = wave_sum_f(w);
    wsel[lane] = w / ds;
  }
  __syncthreads();  // B3

  // ---- gather: wave0 sums r=0..31, wave1 sums r=32..63 ----
  float o = 0.0f;
  int rbase = wvid * 32;
#pragma unroll 4
  for (int r = rbase; r < rbase + 32; ++r)
    o = fmaf(wsel[r], V[(size_t)seli[r] * D_MODEL + hoff + lane], o);
  if (wvid == 1) partial[lane] = o;
  __syncthreads();  // B4
  if (wvid == 0) {
    o += partial[lane];
    size_t oidx = (size_t)t * D_MODEL + hoff + lane;
    if (Of) Of[oidx] = o;
    if (Oh) {
      unsigned short hh = f2bf(o);
      Oh[oidx] = hh;
      Ol[oidx] = f2bf(o - bf2f(hh));
    }
  }
}

// ============ single bf16 MFMA GEMM (NT): C[M,N] = A @ B^T ============
template <int FLAGS, typename CT, bool SWAPXY = false>
__global__ __launch_bounds__(256) void gemm_bt_bf16(const unsigned short* __restrict__ A,
    const unsigned short* __restrict__ B, CT* __restrict__ C,
    const float* __restrict__ bias, const float* __restrict__ res, int M, int N, int K) {
  constexpr bool HAS_BIAS = (FLAGS & 1) != 0;
  constexpr bool HAS_GELU = (FLAGS & 2) != 0;
  constexpr bool HAS_RES = (FLAGS & 4) != 0;
  __shared__ unsigned short As[128 * 32];
  __shared__ unsigned short Bs[128 * 32];
  int tid = threadIdx.x;
  int lane = tid & 63, wid = tid >> 6;
  int wr = wid >> 1, wc = wid & 1;
  int m0 = (SWAPXY ? blockIdx.x : blockIdx.y) * 128;
  int n0 = (SWAPXY ? blockIdx.y : blockIdx.x) * 128;

  int r_in = lane >> 2;
  int slot = lane & 3;

  f32x4 acc[4][4] = {};

  int fr = lane & 15;
  int ksl = lane >> 4;

  for (int k0 = 0; k0 < K; k0 += 32) {
#pragma unroll
    for (int s = 0; s < 2; ++s) {
      int row = wid * 32 + s * 16 + r_in;
      int ksw = (slot ^ ((row >> 1) & 3)) * 8;
      const unsigned short* ga = A + (size_t)(m0 + row) * K + k0 + ksw;
      const unsigned short* gb = B + (size_t)(n0 + row) * K + k0 + ksw;
      gload_lds16(ga, &As[(wid * 32 + s * 16) * 32]);
      gload_lds16(gb, &Bs[(wid * 32 + s * 16) * 32]);
    }
    asm volatile("s_waitcnt vmcnt(0)" ::: "memory");
    __syncthreads();

    s16x8 av[4], bv[4];
#pragma unroll
    for (int mi = 0; mi < 4; ++mi) {
      int ar = wr * 64 + mi * 16 + fr;
      av[mi] = *(const s16x8*)&As[ar * 32 + ((ksl ^ ((ar >> 1) & 3)) * 8)];
    }
#pragma unroll
    for (int ni = 0; ni < 4; ++ni) {
      int br = wc * 64 + ni * 16 + fr;
      bv[ni] = *(const s16x8*)&Bs[br * 32 + ((ksl ^ ((br >> 1) & 3)) * 8)];
    }
#pragma unroll
    for (int mi = 0; mi < 4; ++mi)
#pragma unroll
      for (int ni = 0; ni < 4; ++ni)
        acc[mi][ni] = __builtin_amdgcn_mfma_f32_16x16x32_bf16(av[mi], bv[ni], acc[mi][ni], 0, 0, 0);
    __syncthreads();
  }

  int cr = lane >> 4, cc = lane & 15;
#pragma unroll
  for (int mi = 0; mi < 4; ++mi) {
#pragma unroll
    for (int j = 0; j < 4; ++j) {
      int row = m0 + wr * 64 + mi * 16 + cr * 4 + j;
#pragma unroll
      for (int ni = 0; ni < 4; ++ni) {
        int col = n0 + wc * 64 + ni * 16 + cc;
        float vv = acc[mi][ni][j];
        if (HAS_BIAS) vv += bias[col];
        if (HAS_GELU) vv = 0.5f * vv * (1.0f + erff(vv * 0.70710678118654752f));
        if (HAS_RES) vv += res[(size_t)row * N + col];
        if constexpr (sizeof(CT) == 2)
          C[(size_t)row * N + col] = (CT)f2bf(vv);
        else
          C[(size_t)row * N + col] = (CT)vv;
      }
    }
  }
}

// ============ bf16x3 split-precision MFMA GEMM (NT) ============
template <int FLAGS, int OUTMODE>
__global__ __launch_bounds__(256) void gemm3_bt(
    const unsigned short* __restrict__ Ah, const unsigned short* __restrict__ Al,
    const unsigned short* __restrict__ Bh, const unsigned short* __restrict__ Bl,
    float* __restrict__ Cf, unsigned short* __restrict__ Ch, unsigned short* __restrict__ Cl,
    const float* __restrict__ bias, const float* __restrict__ res, int M, int N, int K) {
  constexpr bool HAS_BIAS = (FLAGS & 1) != 0;
  constexpr bool HAS_GELU = (FLAGS & 2) != 0;
  constexpr bool HAS_RES = (FLAGS & 4) != 0;
  __shared__ unsigned short As[2][128 * 32];
  __shared__ unsigned short Bs[2][128 * 32];
  int tid = threadIdx.x;
  int lane = tid & 63, wid = tid >> 6;
  int wr = wid >> 1, wc = wid & 1;
  int m0 = blockIdx.y * 128, n0 = blockIdx.x * 128;

  int r_in = lane >> 2;
  int slot = lane & 3;

  f32x4 acc[4][4] = {};

  int fr = lane & 15;
  int ksl = lane >> 4;

  for (int k0 = 0; k0 < K; k0 += 32) {
#pragma unroll
    for (int s = 0; s < 2; ++s) {
      int row = wid * 32 + s * 16 + r_in;
      int ksw = (slot ^ ((row >> 1) & 3)) * 8;
      size_t ao = (size_t)(m0 + row) * K + k0 + ksw;
      size_t bo = (size_t)(n0 + row) * K + k0 + ksw;
      int ldst = (wid * 32 + s * 16) * 32;
      gload_lds16(Ah + ao, &As[0][ldst]);
      gload_lds16(Al + ao, &As[1][ldst]);
      gload_lds16(Bh + bo, &Bs[0][ldst]);
      gload_lds16(Bl + bo, &Bs[1][ldst]);
    }
    asm volatile("s_waitcnt vmcnt(0)" ::: "memory");
    __syncthreads();

    s16x8 avh[4], avl[4], bvh[4], bvl[4];
#pragma unroll
    for (int mi = 0; mi < 4; ++mi) {
      int ar = wr * 64 + mi * 16 + fr;
      int off = ar * 32 + ((ksl ^ ((ar >> 1) & 3)) * 8);
      avh[mi] = *(const s16x8*)&As[0][off];
      avl[mi] = *(const s16x8*)&As[1][off];
    }
#pragma unroll
    for (int ni = 0; ni < 4; ++ni) {
      int br = wc * 64 + ni * 16 + fr;
      int off = br * 32 + ((ksl ^ ((br >> 1) & 3)) * 8);
      bvh[ni] = *(const s16x8*)&Bs[0][off];
      bvl[ni] = *(const s16x8*)&Bs[1][off];
    }
#pragma unroll
    for (int mi = 0; mi < 4; ++mi)
#pragma unroll
      for (int ni = 0; ni < 4; ++ni) {
        acc[mi][ni] = __builtin_amdgcn_mfma_f32_16x16x32_bf16(avh[mi], bvh[ni], acc[mi][ni], 0, 0, 0);
        acc[mi][ni] = __builtin_amdgcn_mfma_f32_16x16x32_bf16(avl[mi], bvh[ni], acc[mi][ni], 0, 0, 0);
        acc[mi][ni] = __builtin_amdgcn_mfma_f32_16x16x32_bf16(avh[mi], bvl[ni], acc[mi][ni], 0, 0, 0);
      }
    __syncthreads();
  }

  int cr = lane >> 4, cc = lane & 15;
#pragma unroll
  for (int mi = 0; mi < 4; ++mi) {
#pragma unroll
    for (int j = 0; j < 4; ++j) {
      int row = m0 + wr * 64 + mi * 16 + cr * 4 + j;
#pragma unroll
      for (int ni = 0; ni < 4; ++ni) {
        int col = n0 + wc * 64 + ni * 16 + cc;
        float vv = acc[mi][ni][j];
        if (HAS_BIAS) vv += bias[col];
        if (HAS_GELU) vv = 0.5f * vv * (1.0f + erff(vv * 0.70710678118654752f));
        if (HAS_RES) vv += res[(size_t)row * N + col];
        if constexpr (OUTMODE == 0) {
          Cf[(size_t)row * N + col] = vv;
        } else {
          unsigned short h = f2bf(vv);
          Ch[(size_t)row * N + col] = h;
          Cl[(size_t)row * N + col] = f2bf(vv - bf2f(h));
        }
      }
    }
  }
}

// ============ bf16x3 fused QKV (NT): [q|k|v] = xn @ [Wq^T|Wk^T|Wv^T], fp32 out ====
__global__ __launch_bounds__(256) void gemm3_qkv(
    const unsigned short* __restrict__ Ah, const unsigned short* __restrict__ Al,
    const unsigned short* __restrict__ Bqh, const unsigned short* __restrict__ Bql,
    const unsigned short* __restrict__ Bkh, const unsigned short* __restrict__ Bkl,
    const unsigned short* __restrict__ Bvh, const unsigned short* __restrict__ Bvl,
    float* __restrict__ C, int M, int K) {
  __shared__ unsigned short As[2][128 * 32];
  __shared__ unsigned short Bs[2][128 * 32];
  int tid = threadIdx.x;
  int lane = tid & 63, wid = tid >> 6;
  int wr = wid >> 1, wc = wid & 1;
  int m0 = blockIdx.y * 128;
  int n0g = blockIdx.x * 128;
  int mat = n0g >> 10;               // 0,1,2
  const unsigned short* Bh = (mat == 0) ? Bqh : (mat == 1 ? Bkh : Bvh);
  const unsigned short* Bl = (mat == 0) ? Bql : (mat == 1 ? Bkl : Bvl);
  float* Cb = C + (size_t)mat * ((size_t)M * 1024);
  int n0 = n0g & 1023;

  int r_in = lane >> 2;
  int slot = lane & 3;

  f32x4 acc[4][4] = {};

  int fr = lane & 15;
  int ksl = lane >> 4;

  for (int k0 = 0; k0 < K; k0 += 32) {
#pragma unroll
    for (int s = 0; s < 2; ++s) {
      int row = wid * 32 + s * 16 + r_in;
      int ksw = (slot ^ ((row >> 1) & 3)) * 8;
      size_t ao = (size_t)(m0 + row) * K + k0 + ksw;
      size_t bo = (size_t)(n0 + row) * K + k0 + ksw;
      int ldst = (wid * 32 + s * 16) * 32;
      gload_lds16(Ah + ao, &As[0][ldst]);
      gload_lds16(Al + ao, &As[1][ldst]);
      gload_lds16(Bh + bo, &Bs[0][ldst]);
      gload_lds16(Bl + bo, &Bs[1][ldst]);
    }
    asm volatile("s_waitcnt vmcnt(0)" ::: "memory");
    __syncthreads();

    s16x8 avh[4], avl[4], bvh[4], bvl[4];
#pragma unroll
    for (int mi = 0; mi < 4; ++mi) {
      int ar = wr * 64 + mi * 16 + fr;
      int off = ar * 32 + ((ksl ^ ((ar >> 1) & 3)) * 8);
      avh[mi] = *(const s16x8*)&As[0][off];
      avl[mi] = *(const s16x8*)&As[1][off];
    }
#pragma unroll
    for (int ni = 0; ni < 4; ++ni) {
      int br = wc * 64 + ni * 16 + fr;
      int off = br * 32 + ((ksl ^ ((br >> 1) & 3)) * 8);
      bvh[ni] = *(const s16x8*)&Bs[0][off];
      bvl[ni] = *(const s16x8*)&Bs[1][off];
    }
#pragma unroll
    for (int mi = 0; mi < 4; ++mi)
#pragma unroll
      for (int ni = 0; ni < 4; ++ni) {
        acc[mi][ni] = __builtin_amdgcn_mfma_f32_16x16x32_bf16(avh[mi], bvh[ni], acc[mi][ni], 0, 0, 0);
        acc[mi][ni] = __builtin_amdgcn_mfma_f32_16x16x32_bf16(avl[mi], bvh[ni], acc[mi][ni], 0, 0, 0);
        acc[mi][ni] = __builtin_amdgcn_mfma_f32_16x16x32_bf16(avh[mi], bvl[ni], acc[mi][ni], 0, 0, 0);
      }
    __syncthreads();
  }

  int cr = lane >> 4, cc = lane & 15;
#pragma unroll
  for (int mi = 0; mi < 4; ++mi) {
#pragma unroll
    for (int j = 0; j < 4; ++j) {
      int row = m0 + wr * 64 + mi * 16 + cr * 4 + j;
#pragma unroll
      for (int ni = 0; ni < 4; ++ni) {
        int col = n0 + wc * 64 + ni * 16 + cc;
        Cb[(size_t)row * 1024 + col] = acc[mi][ni][j];
      }
    }
  }
}

// ---------------- fp32 tiled GEMM (NN, fallback) ----------------
template <int FLAGS>
__global__ __launch_bounds__(256) void gemm_nn(const float* __restrict__ A,
    const float* __restrict__ B, float* __restrict__ C, const float* __restrict__ bias,
    const float* __restrict__ res, int M, int N, int K) {
  constexpr bool HAS_BIAS = (FLAGS & 1) != 0;
  constexpr bool HAS_GELU = (FLAGS & 2) != 0;
  constexpr bool HAS_RES = (FLAGS & 4) != 0;
  __shared__ float As[16][68];
  __shared__ float Bs[16][68];
  int tid = threadIdx.x;
  int m0 = blockIdx.y * 64, n0 = blockIdx.x * 64;
  int tx = tid & 15, ty = tid >> 4;
  int am = tid >> 2, ak = (tid & 3) * 4;
  int bk = tid >> 4, bn = (tid & 15) * 4;
  const float* Ap = A + (size_t)(m0 + am) * K + ak;
  const float* Bp = B + (size_t)bk * N + n0 + bn;
  float acc[4][4] = {};
  for (int k0 = 0; k0 < K; k0 += 16) {
    float4 a4 = *(const float4*)(Ap + k0);
    float4 b4 = *(const float4*)(Bp + (size_t)k0 * N);
    As[ak + 0][am] = a4.x; As[ak + 1][am] = a4.y;
    As[ak + 2][am] = a4.z; As[ak + 3][am] = a4.w;
    *(float4*)&Bs[bk][bn] = b4;
    __syncthreads();
#pragma unroll
    for (int k = 0; k < 16; ++k) {
      float4 bq = *(const float4*)&Bs[k][tx * 4];
#pragma unroll
      for (int i = 0; i < 4; ++i) {
        float av = As[k][ty * 4 + i];
        acc[i][0] += av * bq.x; acc[i][1] += av * bq.y;
        acc[i][2] += av * bq.z; acc[i][3] += av * bq.w;
      }
    }
    __syncthreads();
  }
#pragma unroll
  for (int i = 0; i < 4; ++i) {
    int row = m0 + ty * 4 + i;
#pragma unroll
    for (int j = 0; j < 4; ++j) {
      int col = n0 + tx * 4 + j;
      float vv = acc[i][j];
      if (HAS_BIAS) vv += bias[col];
      if (HAS_GELU) vv = 0.5f * vv * (1.0f + erff(vv * 0.70710678118654752f));
      if (HAS_RES) vv += res[(size_t)row * N + col];
      C[(size_t)row * N + col] = vv;
    }
  }
}

// ---------------- fp32 tiled GEMM (NT, fallback logits) ----------------
template <int FLAGS>
__global__ __launch_bounds__(256) void gemm_nt(const float* __restrict__ A,
    const float* __restrict__ B, float* __restrict__ C, const float* __restrict__ bias,
    const float* __restrict__ res, int M, int N, int K) {
  constexpr bool HAS_BIAS = (FLAGS & 1) != 0;
  constexpr bool HAS_GELU = (FLAGS & 2) != 0;
  constexpr bool HAS_RES = (FLAGS & 4) != 0;
  __shared__ float As[16][68];
  __shared__ float Bs[16][68];
  int tid = threadIdx.x;
  int m0 = blockIdx.y * 64, n0 = blockIdx.x * 64;
  int tx = tid & 15, ty = tid >> 4;
  int am = tid >> 2, ak = (tid & 3) * 4;
  int bn2 = tid >> 2, bk2 = (tid & 3) * 4;
  const float* Ap = A + (size_t)(m0 + am) * K + ak;
  const float* Bp = B + (size_t)(n0 + bn2) * K + bk2;
  float acc[4][4] = {};
  for (int k0 = 0; k0 < K; k0 += 16) {
    float4 a4 = *(const float4*)(Ap + k0);
    float4 b4 = *(const float4*)(Bp + k0);
    As[ak + 0][am] = a4.x; As[ak + 1][am] = a4.y;
    As[ak + 2][am] = a4.z; As[ak + 3][am] = a4.w;
    Bs[bk2 + 0][bn2] = b4.x; Bs[bk2 + 1][bn2] = b4.y;
    Bs[bk2 + 2][bn2] = b4.z; Bs[bk2 + 3][bn2] = b4.w;
    __syncthreads();
#pragma unroll
    for (int k = 0; k < 16; ++k) {
      float4 bq = *(const float4*)&Bs[k][tx * 4];
#pragma unroll
      for (int i = 0; i < 4; ++i) {
        float av = As[k][ty * 4 + i];
        acc[i][0] += av * bq.x; acc[i][1] += av * bq.y;
        acc[i][2] += av * bq.z; acc[i][3] += av * bq.w;
      }
    }
    __syncthreads();
  }
#pragma unroll
  for (int i = 0; i < 4; ++i) {
    int row = m0 + ty * 4 + i;
#pragma unroll
    for (int j = 0; j < 4; ++j) {
      int col = n0 + tx * 4 + j;
      float vv = acc[i][j];
      if (HAS_BIAS) vv += bias[col];
      if (HAS_GELU) vv = 0.5f * vv * (1.0f + erff(vv * 0.70710678118654752f));
      if (HAS_RES) vv += res[(size_t)row * N + col];
      C[(size_t)row * N + col] = vv;
    }
  }
}

// ---------------- host orchestration ----------------
extern "C" void kernel_launch(void* const* d_in, const int* in_sizes, int n_in,
                              void* d_out, int out_size, void* d_ws, size_t ws_size,
                              hipStream_t stream) {
  const int* ids = (const int*)d_in[0];
  const float* Wemb = (const float*)d_in[1];
  const float* Wpos = (const float*)d_in[2];
  const float* ln1_g = (const float*)d_in[3];
  const float* ln1_b = (const float*)d_in[4];
  const float* Wq = (const float*)d_in[5];
  const float* Wk = (const float*)d_in[6];
  const float* Wv = (const float*)d_in[7];
  const float* Wo = (const float*)d_in[8];
  const float* ln2_g = (const float*)d_in[9];
  const float* ln2_b = (const float*)d_in[10];
  const float* W1 = (const float*)d_in[11];
  const float* b1 = (const float*)d_in[12];
  const float* W2 = (const float*)d_in[13];
  const float* b2 = (const float*)d_in[14];
  const float* lnf_g = (const float*)d_in[15];
  const float* lnf_b = (const float*)d_in[16];

  const int T = in_sizes[0];          // 2048
  const int D = D_MODEL;
  const int VOC = in_sizes[1] / D;    // 32000

  char* ws = (char*)d_ws;
  float* x = (float*)(ws);
  float* xn = (float*)(ws + 8388608ull);
  unsigned short* xnbh = (unsigned short*)(ws + 8388608ull);
  unsigned short* xnbl = (unsigned short*)(ws + 12582912ull);
  float* q = (float*)(ws + 16777216ull);
  float* k = (float*)(ws + 25165824ull);
  float* v = (float*)(ws + 33554432ull);
  float* kt = (float*)(ws + 41943040ull);
  unsigned short* w1th = (unsigned short*)(ws + 16777216ull);
  unsigned short* w1tl = (unsigned short*)(ws + 25165824ull);
  unsigned short* w2th = (unsigned short*)(ws + 33554432ull);
  unsigned short* w2tl = (unsigned short*)(ws + 41943040ull);
  unsigned short* hbh = (unsigned short*)(ws + 50331648ull);
  unsigned short* hbl = (unsigned short*)(ws + 67108864ull);
  unsigned short* wqth = (unsigned short*)(ws + 50331648ull);   // overlay hbh (dead)
  unsigned short* wqtl = (unsigned short*)(ws + 52428800ull);
  unsigned short* wkth = (unsigned short*)(ws + 54525952ull);
  unsigned short* wktl = (unsigned short*)(ws + 56623104ull);
  unsigned short* wvth = (unsigned short*)(ws + 58720256ull);
  unsigned short* wvtl = (unsigned short*)(ws + 60817408ull);
  unsigned short* woth = (unsigned short*)(ws + 83886080ull);
  unsigned short* wotl = (unsigned short*)(ws + 85983232ull);
  unsigned short* wembb = (unsigned short*)(ws + 16777216ull);
  const size_t NEED = 88080384ull;  // 84 MB

  int kkeep = (T < 64) ? T : 64;
  int fk = (HEAD_DIM * kkeep + T - 1) / T;
  if (fk < 1) fk = 1;
  int nseg = T * N_HEADS;

  embed_kernel<<<T, 256, 0, stream>>>(ids, Wemb, Wpos, x);

  if (ws_size >= NEED && (T % 128) == 0 && (VOC % 128) == 0 &&
      (size_t)VOC * D * 2 <= 67108864ull) {
    // ---- bf16 MFMA path ----
    for (int l = 0; l < 2; ++l) {
      const float* wq = Wq + (size_t)l * D * D;
      const float* wk = Wk + (size_t)l * D * D;
      const float* wv = Wv + (size_t)l * D * D;
      const float* wo = Wo + (size_t)l * D * D;

      ln_kernel<<<T, 256, 0, stream>>>(x, nullptr, xnbh, xnbl,
                                       ln1_g + (size_t)l * D, ln1_b + (size_t)l * D);

      transpose_conv_pair_kernel<<<dim3(D / 32, D / 32), 256, 0, stream>>>(wq, wqth, wqtl, D, D);
      transpose_conv_pair_kernel<<<dim3(D / 32, D / 32), 256, 0, stream>>>(wk, wkth, wktl, D, D);
      transpose_conv_pair_kernel<<<dim3(D / 32, D / 32), 256, 0, stream>>>(wv, wvth, wvtl, D, D);

      gemm3_qkv<<<dim3(3 * D / 128, T / 128), 256, 0, stream>>>(
          xnbh, xnbl, wqth, wqtl, wkth, wktl, wvth, wvtl, q, T, D);

      sparsify_kernel<<<(3 * nseg + 3) / 4, 256, 0, stream>>>(q, 3 * nseg, fk);

      transpose_kernel<<<dim3(D / 32, T / 32), 256, 0, stream>>>(k, kt, T, D);

      attn_kernel<<<T * N_HEADS, 128, 0, stream>>>(q, kt, v, nullptr, xnbh, xnbl, T);

      transpose_conv_pair_kernel<<<dim3(D / 32, D / 32), 256, 0, stream>>>(wo, woth, wotl, D, D);
      gemm3_bt<4, 0><<<dim3(D / 128, T / 128), 256, 0, stream>>>(
          xnbh, xnbl, woth, wotl, x, nullptr, nullptr, nullptr, x, T, D, D);

      ln_kernel<<<T, 256, 0, stream>>>(x, nullptr, xnbh, xnbl,
                                       ln2_g + (size_t)l * D, ln2_b + (size_t)l * D);

      transpose_conv_pair_kernel<<<dim3(HIDDEN / 32, D / 32), 256, 0, stream>>>(
          W1 + (size_t)l * D * HIDDEN, w1th, w1tl, D, HIDDEN);
      gemm3_bt<3, 1><<<dim3(HIDDEN / 128, T / 128), 256, 0, stream>>>(
          xnbh, xnbl, w1th, w1tl, nullptr, hbh, hbl,
          b1 + (size_t)l * HIDDEN, nullptr, T, HIDDEN, D);
      transpose_conv_pair_kernel<<<dim3(D / 32, HIDDEN / 32), 256, 0, stream>>>(
          W2 + (size_t)l * HIDDEN * D, w2th, w2tl, HIDDEN, D);
      gemm3_bt<5, 0><<<dim3(D / 128, T / 128), 256, 0, stream>>>(
          hbh, hbl, w2th, w2tl, x, nullptr, nullptr,
          b2 + (size_t)l * D, x, T, D, HIDDEN);
    }

    ln_kernel<<<T, 256, 0, stream>>>(x, nullptr, xnbh, nullptr, lnf_g, lnf_b);

    conv_bf16_kernel<<<4096, 256, 0, stream>>>(Wemb, wembb, (size_t)VOC * D);

    gemm_bt_bf16<0, float, true><<<dim3(T / 128, VOC / 128), 256, 0, stream>>>(
        xnbh, wembb, (float*)d_out, nullptr, nullptr, T, VOC, D);
  } else {
    // ---- fp32 fallback ----
    float* hbuf = q;
    for (int l = 0; l < 2; ++l) {
      const float* wq = Wq + (size_t)l * D * D;
      const float* wk = Wk + (size_t)l * D * D;
      const float* wv = Wv + (size_t)l * D * D;
      const float* wo = Wo + (size_t)l * D * D;

      ln_kernel<<<T, 256, 0, stream>>>(x, xn, nullptr, nullptr,
                                       ln1_g + (size_t)l * D, ln1_b + (size_t)l * D);

      dim3 g1(D / 64, T / 64);
      gemm_nn<0><<<g1, 256, 0, stream>>>(xn, wq, q, nullptr, nullptr, T, D, D);
      gemm_nn<0><<<g1, 256, 0, stream>>>(xn, wk, k, nullptr, nullptr, T, D, D);
      gemm_nn<0><<<g1, 256, 0, stream>>>(xn, wv, v, nullptr, nullptr, T, D, D);

      sparsify_kernel<<<(nseg + 3) / 4, 256, 0, stream>>>(q, nseg, fk);
      sparsify_kernel<<<(nseg + 3) / 4, 256, 0, stream>>>(k, nseg, fk);
      sparsify_kernel<<<(nseg + 3) / 4, 256, 0, stream>>>(v, nseg, fk);

      transpose_kernel<<<dim3(D / 32, T / 32), 256, 0, stream>>>(k, kt, T, D);

      attn_kernel<<<T * N_HEADS, 128, 0, stream>>>(q, kt, v, xn, nullptr, nullptr, T);

      gemm_nn<4><<<g1, 256, 0, stream>>>(xn, wo, x, nullptr, x, T, D, D);

      ln_kernel<<<T, 256, 0, stream>>>(x, xn, nullptr, nullptr,
                                       ln2_g + (size_t)l * D, ln2_b + (size_t)l * D);

      gemm_nn<3><<<dim3(HIDDEN / 64, T / 64), 256, 0, stream>>>(
          xn, W1 + (size_t)l * D * HIDDEN, hbuf, b1 + (size_t)l * HIDDEN, nullptr, T, HIDDEN, D);
      gemm_nn<5><<<g1, 256, 0, stream>>>(
          hbuf, W2 + (size_t)l * HIDDEN * D, x, b2 + (size_t)l * D, x, T, D, HIDDEN);
    }

    ln_kernel<<<T, 256, 0, stream>>>(x, xn, nullptr, nullptr, lnf_g, lnf_b);

    gemm_nt<0><<<dim3(VOC / 64, T / 64), 256, 0, stream>>>(
        xn, Wemb, (float*)d_out, nullptr, nullptr, T, VOC, D);
  }
}

// Round 12
// 1361.517 us; speedup vs baseline: 1.4494x; 1.0204x over previous
//
#include <hip/hip_runtime.h>
#include <math.h>

#define D_MODEL 1024
#define N_HEADS 16
#define HEAD_DIM 64
#define HIDDEN 4096
#define TMAX 2048

typedef __attribute__((ext_vector_type(8))) short s16x8;
typedef __attribute__((ext_vector_type(4))) float f32x4;

// ---------------- wave helpers (wave64) ----------------
__device__ __forceinline__ float wave_max_f(float v) {
#pragma unroll
  for (int o = 32; o > 0; o >>= 1) v = fmaxf(v, __shfl_xor(v, o));
  return v;
}
__device__ __forceinline__ float wave_sum_f(float v) {
#pragma unroll
  for (int o = 32; o > 0; o >>= 1) v += __shfl_xor(v, o);
  return v;
}
__device__ __forceinline__ unsigned long long wave_max_u64(unsigned long long k) {
#pragma unroll
  for (int o = 32; o > 0; o >>= 1) {
    unsigned long long u = __shfl_xor(k, o);
    if (u > k) k = u;
  }
  return k;
}
__device__ __forceinline__ unsigned ford(float v) {
  unsigned u = __float_as_uint(v);
  return (u & 0x80000000u) ? ~u : (u | 0x80000000u);
}
// fp32 -> bf16 RNE
__device__ __forceinline__ unsigned short f2bf(float f) {
  unsigned u = __float_as_uint(f);
  u += 0x7FFFu + ((u >> 16) & 1u);
  return (unsigned short)(u >> 16);
}
__device__ __forceinline__ float bf2f(unsigned short h) {
  return __uint_as_float((unsigned)h << 16);
}

__device__ __forceinline__ void gload_lds16(const void* g, void* l) {
  __builtin_amdgcn_global_load_lds(
      (const __attribute__((address_space(1))) void*)g,
      (__attribute__((address_space(3))) void*)l, 16, 0, 0);
}

// ---------------- embedding ----------------
__global__ __launch_bounds__(256) void embed_kernel(const int* __restrict__ ids,
    const float* __restrict__ Wemb, const float* __restrict__ Wpos, float* __restrict__ X) {
  int t = blockIdx.x, tid = threadIdx.x;
  int id = ids[t];
  float4 e = ((const float4*)(Wemb + (size_t)id * D_MODEL))[tid];
  float4 p = ((const float4*)(Wpos + (size_t)t * D_MODEL))[tid];
  e.x += p.x; e.y += p.y; e.z += p.z; e.w += p.w;
  ((float4*)(X + (size_t)t * D_MODEL))[tid] = e;
}

// ---------------- layernorm; optional fp32 out + bf16 hi/lo out ----------------
__global__ __launch_bounds__(256) void ln_kernel(const float* __restrict__ X,
    float* __restrict__ Y, unsigned short* __restrict__ Ybh, unsigned short* __restrict__ Ybl,
    const float* __restrict__ g, const float* __restrict__ b) {
  int row = blockIdx.x, tid = threadIdx.x;
  int lane = tid & 63, wid = tid >> 6;
  __shared__ float red[8];
  float4 v = ((const float4*)(X + (size_t)row * D_MODEL))[tid];
  float s = v.x + v.y + v.z + v.w;
  s = wave_sum_f(s);
  if (lane == 0) red[wid] = s;
  __syncthreads();
  float mean = (red[0] + red[1] + red[2] + red[3]) * (1.0f / D_MODEL);
  float dx = v.x - mean, dy = v.y - mean, dz = v.z - mean, dw = v.w - mean;
  float q = dx * dx + dy * dy + dz * dz + dw * dw;
  q = wave_sum_f(q);
  if (lane == 0) red[4 + wid] = q;
  __syncthreads();
  float var = (red[4] + red[5] + red[6] + red[7]) * (1.0f / D_MODEL);
  float rs = rsqrtf(var + 1e-5f);
  float4 gg = ((const float4*)g)[tid], bb = ((const float4*)b)[tid];
  float4 y;
  y.x = dx * rs * gg.x + bb.x;
  y.y = dy * rs * gg.y + bb.y;
  y.z = dz * rs * gg.z + bb.z;
  y.w = dw * rs * gg.w + bb.w;
  if (Y) ((float4*)(Y + (size_t)row * D_MODEL))[tid] = y;
  if (Ybh) {
    ushort4 oh;
    oh.x = f2bf(y.x); oh.y = f2bf(y.y); oh.z = f2bf(y.z); oh.w = f2bf(y.w);
    ((ushort4*)(Ybh + (size_t)row * D_MODEL))[tid] = oh;
    if (Ybl) {
      ushort4 ol;
      ol.x = f2bf(y.x - bf2f(oh.x)); ol.y = f2bf(y.y - bf2f(oh.y));
      ol.z = f2bf(y.z - bf2f(oh.z)); ol.w = f2bf(y.w - bf2f(oh.w));
      ((ushort4*)(Ybl + (size_t)row * D_MODEL))[tid] = ol;
    }
  }
}

// ---------------- sparsify (exact top-fk by |value| per 64 segment) ----------------
__global__ __launch_bounds__(256) void sparsify_kernel(float* __restrict__ X, int nseg, int fk) {
  int seg = blockIdx.x * 4 + (threadIdx.x >> 6);
  if (seg >= nseg) return;
  int lane = threadIdx.x & 63;
  size_t idx = (size_t)seg * 64 + lane;
  float x = X[idx];
  float a = fabsf(x);
  float cur = INFINITY;
  int remaining = fk;
  float thr = 0.0f;
  for (;;) {
    float cand = (a < cur) ? a : -INFINITY;
    float mv = wave_max_f(cand);
    if (mv == -INFINITY) { thr = mv; break; }
    int c = __popcll(__ballot(a == mv));
    if (c >= remaining) { thr = mv; break; }
    remaining -= c; cur = mv;
  }
  if (!(a >= thr)) X[idx] = 0.0f;
}

// ---------------- transpose fp32 [R][C] -> [C][R] ----------------
__global__ __launch_bounds__(256) void transpose_kernel(const float* __restrict__ in,
    float* __restrict__ out, int R, int Cc) {
  __shared__ float tile[32][33];
  int c0 = blockIdx.x * 32, r0 = blockIdx.y * 32;
  int tx = threadIdx.x & 31, ty = threadIdx.x >> 5;
  for (int i = ty; i < 32; i += 8)
    tile[i][tx] = in[(size_t)(r0 + i) * Cc + c0 + tx];
  __syncthreads();
  for (int i = ty; i < 32; i += 8)
    out[(size_t)(c0 + i) * R + r0 + tx] = tile[tx][i];
}

// ---------------- transpose-convert fp32 [R][C] -> bf16 hi/lo [C][R] ----------------
__global__ __launch_bounds__(256) void transpose_conv_pair_kernel(const float* __restrict__ in,
    unsigned short* __restrict__ oh, unsigned short* __restrict__ ol, int R, int Cc) {
  __shared__ float tile[32][33];
  int c0 = blockIdx.x * 32, r0 = blockIdx.y * 32;
  int tx = threadIdx.x & 31, ty = threadIdx.x >> 5;
  for (int i = ty; i < 32; i += 8)
    tile[i][tx] = in[(size_t)(r0 + i) * Cc + c0 + tx];
  __syncthreads();
  for (int i = ty; i < 32; i += 8) {
    float v = tile[tx][i];
    unsigned short h = f2bf(v);
    size_t idx = (size_t)(c0 + i) * R + r0 + tx;
    oh[idx] = h;
    ol[idx] = f2bf(v - bf2f(h));
  }
}

// ---------------- fp32 -> bf16 elementwise ----------------
__global__ __launch_bounds__(256) void conv_bf16_kernel(const float* __restrict__ in,
    unsigned short* __restrict__ out, size_t n) {
  size_t i = ((size_t)blockIdx.x * 256 + threadIdx.x) * 4;
  size_t stride = (size_t)gridDim.x * 1024;
  for (; i < n; i += stride) {
    float4 v = *(const float4*)(in + i);
    ushort4 o;
    o.x = f2bf(v.x); o.y = f2bf(v.y); o.z = f2bf(v.z); o.w = f2bf(v.w);
    *(ushort4*)(out + i) = o;
  }
}

// ---------------- attention: 2 waves per (head, query-row) job ----------------
// r11 structure + strip-mined score pass (8 loads in flight) + batch-8 gather.
__global__ __launch_bounds__(128) void attn_kernel(const float* __restrict__ Q,
    const float* __restrict__ Kt, const float* __restrict__ V,
    float* __restrict__ Of, unsigned short* __restrict__ Oh, unsigned short* __restrict__ Ol,
    int T) {
  int t = T - 1 - (blockIdx.x % T);   // longest jobs dispatch first
  int h = blockIdx.x / T;
  int tid = threadIdx.x;
  int lane = tid & 63;
  int wvid = tid >> 6;
  unsigned long long lmlt = (1ull << lane) - 1ull;

  __shared__ float sc[TMAX];
  __shared__ float qval[HEAD_DIM];
  __shared__ int qdim[HEAD_DIM];
  constexpr int PCAP = 320;
  __shared__ float posv[PCAP];
  __shared__ int posi[PCAP];
  __shared__ int seli[64];
  __shared__ float selv[64];
  __shared__ float wsel[64];
  __shared__ float partial[64];
  __shared__ int nq_sh;

  int hoff = h * HEAD_DIM;
  if (wvid == 0) {
    float qv = Q[(size_t)t * D_MODEL + hoff + lane];
    unsigned long long nzm = __ballot(qv != 0.0f);
    int nq0 = __popcll(nzm);
    if (qv != 0.0f) {
      int p = __popcll(nzm & lmlt);
      qval[p] = qv; qdim[p] = lane;
    }
    seli[lane] = 0;  // pad target for fixed-trip gather
    if (lane == 0) nq_sh = nq0;
  }
  __syncthreads();  // B1

  int nq = nq_sh;
  int Vn = t + 1;
  // ---- score pass over 128 lanes; strip-mined x4 (8 loads in flight) ----
  if (nq == 2) {
    float qA = qval[0], qB = qval[1];
    const float* ktA = Kt + (size_t)(hoff + qdim[0]) * T;
    const float* ktB = Kt + (size_t)(hoff + qdim[1]) * T;
    int s = tid;
    for (; s + 384 < Vn; s += 512) {
      float a0 = ktA[s],       b0 = ktB[s];
      float a1 = ktA[s + 128], b1 = ktB[s + 128];
      float a2 = ktA[s + 256], b2 = ktB[s + 256];
      float a3 = ktA[s + 384], b3 = ktB[s + 384];
      sc[s]       = fmaf(qB, b0, qA * a0) * 0.125f;
      sc[s + 128] = fmaf(qB, b1, qA * a1) * 0.125f;
      sc[s + 256] = fmaf(qB, b2, qA * a2) * 0.125f;
      sc[s + 384] = fmaf(qB, b3, qA * a3) * 0.125f;
    }
    for (; s < Vn; s += 128)
      sc[s] = fmaf(qB, ktB[s], qA * ktA[s]) * 0.125f;
  } else {
    for (int s = tid; s < Vn; s += 128) {
      float acc = 0.0f;
      for (int j = 0; j < nq; ++j)
        acc += qval[j] * Kt[(size_t)(hoff + qdim[j]) * T + s];
      sc[s] = acc * 0.125f;
    }
  }
  __syncthreads();  // B2

  // ---- selection + softmax: wave 0 only (lockstep; no barriers inside) ----
  if (wvid == 0) {
    int nsel = 0;
    if (Vn <= 64) {
      nsel = Vn;
      if (lane < Vn) { seli[lane] = lane; selv[lane] = sc[lane]; }
    } else {
      // compact positive scores (list index order == s order)
      int base = 0;
      for (int s0 = 0; s0 < Vn; s0 += 64) {
        int s = s0 + lane;
        float v = (s < Vn) ? sc[s] : -1.0f;
        unsigned long long pm = __ballot(v > 0.0f);
        if (v > 0.0f) {
          int p = base + __popcll(pm & lmlt);
          if (p < PCAP) { posv[p] = v; posi[p] = s; }
        }
        base += __popcll(pm);
      }
      int P = base;

      bool fullpath = false;
      if (P >= 64) {
        if (P <= 128) {
          // ---- bitonic-128 top-64 ----
          unsigned long long key0, key1;
          {
            int e0 = lane, e1 = lane + 64;
            key0 = (e0 < P) ? (((unsigned long long)ford(posv[e0]) << 32) |
                               (unsigned long long)(0xFFFFFFFFu - (unsigned)e0)) : 0ull;
            key1 = (e1 < P) ? (((unsigned long long)ford(posv[e1]) << 32) |
                               (unsigned long long)(0xFFFFFFFFu - (unsigned)e1)) : 0ull;
          }
          for (int k = 2; k <= 128; k <<= 1) {
            for (int j = k >> 1; j > 0; j >>= 1) {
              if (j == 64) {
                if (key0 < key1) { unsigned long long tm = key0; key0 = key1; key1 = tm; }
              } else {
                bool iLower = (lane & j) == 0;
                {
                  unsigned long long prt = __shfl_xor(key0, j);
                  bool desc = ((lane & k) == 0);
                  bool keepMax = (iLower == desc);
                  key0 = keepMax ? (key0 > prt ? key0 : prt) : (key0 < prt ? key0 : prt);
                }
                {
                  unsigned long long prt = __shfl_xor(key1, j);
                  int e1 = lane + 64;
                  bool desc = ((e1 & k) == 0);
                  bool keepMax = (iLower == desc);
                  key1 = keepMax ? (key1 > prt ? key1 : prt) : (key1 < prt ? key1 : prt);
                }
              }
            }
          }
          int e = (int)(0xFFFFFFFFu - (unsigned)(key0 & 0xFFFFFFFFull));
          seli[lane] = posi[e];
          selv[lane] = posv[e];
          nsel = 64;
        } else if (P <= PCAP) {
          for (int r = 0; r < 64; ++r) {
            unsigned long long best = 0ull;
            for (int j = lane; j < P; j += 64) {
              float v = posv[j];
              if (v > 0.0f) {
                unsigned long long key =
                    ((unsigned long long)ford(v) << 32) | (unsigned)(0xFFFFFFFFu - (unsigned)j);
                if (key > best) best = key;
              }
            }
            best = wave_max_u64(best);
            int j = (int)(0xFFFFFFFFu - (unsigned)(best & 0xFFFFFFFFull));
            if (lane == (j & 63)) {
              seli[r] = posi[j]; selv[r] = posv[j]; posv[j] = -INFINITY;
            }
          }
          nsel = 64;
        } else {
          fullpath = true;
        }
      } else {
        if (lane < P) { seli[lane] = posi[lane]; selv[lane] = posv[lane]; }
        int need = 64 - P;
        int zbase = 0;
        bool done = false;
        for (int s0 = 0; s0 < Vn && !done; s0 += 64) {
          int s = s0 + lane;
          bool isz = (s < Vn) && (sc[s] == 0.0f);
          unsigned long long zm = __ballot(isz);
          int pre = __popcll(zm & lmlt);
          if (isz && (zbase + pre) < need) {
            seli[P + zbase + pre] = s;
            selv[P + zbase + pre] = 0.0f;
          }
          zbase += __popcll(zm);
          if (zbase >= need) done = true;
        }
        if (zbase >= need) {
          nsel = 64;
        } else {
          fullpath = true;
        }
      }

      if (fullpath) {
        nsel = 64;
        for (int r = 0; r < 64; ++r) {
          unsigned long long best = 0ull;
          for (int s = lane; s < Vn; s += 64) {
            float v = sc[s];
            if (v != -INFINITY) {
              unsigned long long key =
                  ((unsigned long long)ford(v) << 32) | (unsigned)(0x7FFFFFFFu - (unsigned)s);
              if (key > best) best = key;
            }
          }
          best = wave_max_u64(best);
          if (best == 0ull) { nsel = r; break; }
          int s = (int)(0x7FFFFFFFu - (unsigned)(best & 0xFFFFFFFFull));
          if (lane == (s & 63)) {
            seli[r] = s; selv[r] = sc[s]; sc[s] = -INFINITY;
          }
        }
      }
    }

    // softmax weights (wsel[lane]==0 for lane >= nsel)
    float v = (lane < nsel) ? selv[lane] : -INFINITY;
    float m = wave_max_f(v);
    float w = (lane < nsel) ? expf(v - m) : 0.0f;
    float ds = wave_sum_f(w);
    wsel[lane] = w / ds;
  }
  __syncthreads();  // B3

  // ---- gather: wave0 sums r=0..31, wave1 sums r=32..63; batch-8 loads ----
  float o = 0.0f;
  int rbase = wvid * 32;
  const float* Vb = V + hoff + lane;
#pragma unroll
  for (int r0 = 0; r0 < 32; r0 += 8) {
    float wv[8];
    int ib[8];
#pragma unroll
    for (int i = 0; i < 8; ++i) {
      wv[i] = wsel[rbase + r0 + i];
      ib[i] = seli[rbase + r0 + i];
    }
    float vv[8];
#pragma unroll
    for (int i = 0; i < 8; ++i) vv[i] = Vb[(size_t)ib[i] * D_MODEL];
#pragma unroll
    for (int i = 0; i < 8; ++i) o = fmaf(wv[i], vv[i], o);
  }
  if (wvid == 1) partial[lane] = o;
  __syncthreads();  // B4
  if (wvid == 0) {
    o += partial[lane];
    size_t oidx = (size_t)t * D_MODEL + hoff + lane;
    if (Of) Of[oidx] = o;
    if (Oh) {
      unsigned short hh = f2bf(o);
      Oh[oidx] = hh;
      Ol[oidx] = f2bf(o - bf2f(hh));
    }
  }
}

// ============ single bf16 MFMA GEMM (NT): C[M,N] = A @ B^T ============
template <int FLAGS, typename CT, bool SWAPXY = false>
__global__ __launch_bounds__(256) void gemm_bt_bf16(const unsigned short* __restrict__ A,
    const unsigned short* __restrict__ B, CT* __restrict__ C,
    const float* __restrict__ bias, const float* __restrict__ res, int M, int N, int K) {
  constexpr bool HAS_BIAS = (FLAGS & 1) != 0;
  constexpr bool HAS_GELU = (FLAGS & 2) != 0;
  constexpr bool HAS_RES = (FLAGS & 4) != 0;
  __shared__ unsigned short As[128 * 32];
  __shared__ unsigned short Bs[128 * 32];
  int tid = threadIdx.x;
  int lane = tid & 63, wid = tid >> 6;
  int wr = wid >> 1, wc = wid & 1;
  int m0 = (SWAPXY ? blockIdx.x : blockIdx.y) * 128;
  int n0 = (SWAPXY ? blockIdx.y : blockIdx.x) * 128;

  int r_in = lane >> 2;
  int slot = lane & 3;

  f32x4 acc[4][4] = {};

  int fr = lane & 15;
  int ksl = lane >> 4;

  for (int k0 = 0; k0 < K; k0 += 32) {
#pragma unroll
    for (int s = 0; s < 2; ++s) {
      int row = wid * 32 + s * 16 + r_in;
      int ksw = (slot ^ ((row >> 1) & 3)) * 8;
      const unsigned short* ga = A + (size_t)(m0 + row) * K + k0 + ksw;
      const unsigned short* gb = B + (size_t)(n0 + row) * K + k0 + ksw;
      gload_lds16(ga, &As[(wid * 32 + s * 16) * 32]);
      gload_lds16(gb, &Bs[(wid * 32 + s * 16) * 32]);
    }
    asm volatile("s_waitcnt vmcnt(0)" ::: "memory");
    __syncthreads();

    s16x8 av[4], bv[4];
#pragma unroll
    for (int mi = 0; mi < 4; ++mi) {
      int ar = wr * 64 + mi * 16 + fr;
      av[mi] = *(const s16x8*)&As[ar * 32 + ((ksl ^ ((ar >> 1) & 3)) * 8)];
    }
#pragma unroll
    for (int ni = 0; ni < 4; ++ni) {
      int br = wc * 64 + ni * 16 + fr;
      bv[ni] = *(const s16x8*)&Bs[br * 32 + ((ksl ^ ((br >> 1) & 3)) * 8)];
    }
#pragma unroll
    for (int mi = 0; mi < 4; ++mi)
#pragma unroll
      for (int ni = 0; ni < 4; ++ni)
        acc[mi][ni] = __builtin_amdgcn_mfma_f32_16x16x32_bf16(av[mi], bv[ni], acc[mi][ni], 0, 0, 0);
    __syncthreads();
  }

  int cr = lane >> 4, cc = lane & 15;
#pragma unroll
  for (int mi = 0; mi < 4; ++mi) {
#pragma unroll
    for (int j = 0; j < 4; ++j) {
      int row = m0 + wr * 64 + mi * 16 + cr * 4 + j;
#pragma unroll
      for (int ni = 0; ni < 4; ++ni) {
        int col = n0 + wc * 64 + ni * 16 + cc;
        float vv = acc[mi][ni][j];
        if (HAS_BIAS) vv += bias[col];
        if (HAS_GELU) vv = 0.5f * vv * (1.0f + erff(vv * 0.70710678118654752f));
        if (HAS_RES) vv += res[(size_t)row * N + col];
        if constexpr (sizeof(CT) == 2)
          C[(size_t)row * N + col] = (CT)f2bf(vv);
        else
          C[(size_t)row * N + col] = (CT)vv;
      }
    }
  }
}

// ============ bf16x3 split-precision MFMA GEMM (NT) ============
template <int FLAGS, int OUTMODE>
__global__ __launch_bounds__(256) void gemm3_bt(
    const unsigned short* __restrict__ Ah, const unsigned short* __restrict__ Al,
    const unsigned short* __restrict__ Bh, const unsigned short* __restrict__ Bl,
    float* __restrict__ Cf, unsigned short* __restrict__ Ch, unsigned short* __restrict__ Cl,
    const float* __restrict__ bias, const float* __restrict__ res, int M, int N, int K) {
  constexpr bool HAS_BIAS = (FLAGS & 1) != 0;
  constexpr bool HAS_GELU = (FLAGS & 2) != 0;
  constexpr bool HAS_RES = (FLAGS & 4) != 0;
  __shared__ unsigned short As[2][128 * 32];
  __shared__ unsigned short Bs[2][128 * 32];
  int tid = threadIdx.x;
  int lane = tid & 63, wid = tid >> 6;
  int wr = wid >> 1, wc = wid & 1;
  int m0 = blockIdx.y * 128, n0 = blockIdx.x * 128;

  int r_in = lane >> 2;
  int slot = lane & 3;

  f32x4 acc[4][4] = {};

  int fr = lane & 15;
  int ksl = lane >> 4;

  for (int k0 = 0; k0 < K; k0 += 32) {
#pragma unroll
    for (int s = 0; s < 2; ++s) {
      int row = wid * 32 + s * 16 + r_in;
      int ksw = (slot ^ ((row >> 1) & 3)) * 8;
      size_t ao = (size_t)(m0 + row) * K + k0 + ksw;
      size_t bo = (size_t)(n0 + row) * K + k0 + ksw;
      int ldst = (wid * 32 + s * 16) * 32;
      gload_lds16(Ah + ao, &As[0][ldst]);
      gload_lds16(Al + ao, &As[1][ldst]);
      gload_lds16(Bh + bo, &Bs[0][ldst]);
      gload_lds16(Bl + bo, &Bs[1][ldst]);
    }
    asm volatile("s_waitcnt vmcnt(0)" ::: "memory");
    __syncthreads();

    s16x8 avh[4], avl[4], bvh[4], bvl[4];
#pragma unroll
    for (int mi = 0; mi < 4; ++mi) {
      int ar = wr * 64 + mi * 16 + fr;
      int off = ar * 32 + ((ksl ^ ((ar >> 1) & 3)) * 8);
      avh[mi] = *(const s16x8*)&As[0][off];
      avl[mi] = *(const s16x8*)&As[1][off];
    }
#pragma unroll
    for (int ni = 0; ni < 4; ++ni) {
      int br = wc * 64 + ni * 16 + fr;
      int off = br * 32 + ((ksl ^ ((br >> 1) & 3)) * 8);
      bvh[ni] = *(const s16x8*)&Bs[0][off];
      bvl[ni] = *(const s16x8*)&Bs[1][off];
    }
#pragma unroll
    for (int mi = 0; mi < 4; ++mi)
#pragma unroll
      for (int ni = 0; ni < 4; ++ni) {
        acc[mi][ni] = __builtin_amdgcn_mfma_f32_16x16x32_bf16(avh[mi], bvh[ni], acc[mi][ni], 0, 0, 0);
        acc[mi][ni] = __builtin_amdgcn_mfma_f32_16x16x32_bf16(avl[mi], bvh[ni], acc[mi][ni], 0, 0, 0);
        acc[mi][ni] = __builtin_amdgcn_mfma_f32_16x16x32_bf16(avh[mi], bvl[ni], acc[mi][ni], 0, 0, 0);
      }
    __syncthreads();
  }

  int cr = lane >> 4, cc = lane & 15;
#pragma unroll
  for (int mi = 0; mi < 4; ++mi) {
#pragma unroll
    for (int j = 0; j < 4; ++j) {
      int row = m0 + wr * 64 + mi * 16 + cr * 4 + j;
#pragma unroll
      for (int ni = 0; ni < 4; ++ni) {
        int col = n0 + wc * 64 + ni * 16 + cc;
        float vv = acc[mi][ni][j];
        if (HAS_BIAS) vv += bias[col];
        if (HAS_GELU) vv = 0.5f * vv * (1.0f + erff(vv * 0.70710678118654752f));
        if (HAS_RES) vv += res[(size_t)row * N + col];
        if constexpr (OUTMODE == 0) {
          Cf[(size_t)row * N + col] = vv;
        } else {
          unsigned short h = f2bf(vv);
          Ch[(size_t)row * N + col] = h;
          Cl[(size_t)row * N + col] = f2bf(vv - bf2f(h));
        }
      }
    }
  }
}

// ============ bf16x3 fused QKV (NT): [q|k|v] = xn @ [Wq^T|Wk^T|Wv^T], fp32 out ====
__global__ __launch_bounds__(256) void gemm3_qkv(
    const unsigned short* __restrict__ Ah, const unsigned short* __restrict__ Al,
    const unsigned short* __restrict__ Bqh, const unsigned short* __restrict__ Bql,
    const unsigned short* __restrict__ Bkh, const unsigned short* __restrict__ Bkl,
    const unsigned short* __restrict__ Bvh, const unsigned short* __restrict__ Bvl,
    float* __restrict__ C, int M, int K) {
  __shared__ unsigned short As[2][128 * 32];
  __shared__ unsigned short Bs[2][128 * 32];
  int tid = threadIdx.x;
  int lane = tid & 63, wid = tid >> 6;
  int wr = wid >> 1, wc = wid & 1;
  int m0 = blockIdx.y * 128;
  int n0g = blockIdx.x * 128;
  int mat = n0g >> 10;               // 0,1,2
  const unsigned short* Bh = (mat == 0) ? Bqh : (mat == 1 ? Bkh : Bvh);
  const unsigned short* Bl = (mat == 0) ? Bql : (mat == 1 ? Bkl : Bvl);
  float* Cb = C + (size_t)mat * ((size_t)M * 1024);
  int n0 = n0g & 1023;

  int r_in = lane >> 2;
  int slot = lane & 3;

  f32x4 acc[4][4] = {};

  int fr = lane & 15;
  int ksl = lane >> 4;

  for (int k0 = 0; k0 < K; k0 += 32) {
#pragma unroll
    for (int s = 0; s < 2; ++s) {
      int row = wid * 32 + s * 16 + r_in;
      int ksw = (slot ^ ((row >> 1) & 3)) * 8;
      size_t ao = (size_t)(m0 + row) * K + k0 + ksw;
      size_t bo = (size_t)(n0 + row) * K + k0 + ksw;
      int ldst = (wid * 32 + s * 16) * 32;
      gload_lds16(Ah + ao, &As[0][ldst]);
      gload_lds16(Al + ao, &As[1][ldst]);
      gload_lds16(Bh + bo, &Bs[0][ldst]);
      gload_lds16(Bl + bo, &Bs[1][ldst]);
    }
    asm volatile("s_waitcnt vmcnt(0)" ::: "memory");
    __syncthreads();

    s16x8 avh[4], avl[4], bvh[4], bvl[4];
#pragma unroll
    for (int mi = 0; mi < 4; ++mi) {
      int ar = wr * 64 + mi * 16 + fr;
      int off = ar * 32 + ((ksl ^ ((ar >> 1) & 3)) * 8);
      avh[mi] = *(const s16x8*)&As[0][off];
      avl[mi] = *(const s16x8*)&As[1][off];
    }
#pragma unroll
    for (int ni = 0; ni < 4; ++ni) {
      int br = wc * 64 + ni * 16 + fr;
      int off = br * 32 + ((ksl ^ ((br >> 1) & 3)) * 8);
      bvh[ni] = *(const s16x8*)&Bs[0][off];
      bvl[ni] = *(const s16x8*)&Bs[1][off];
    }
#pragma unroll
    for (int mi = 0; mi < 4; ++mi)
#pragma unroll
      for (int ni = 0; ni < 4; ++ni) {
        acc[mi][ni] = __builtin_amdgcn_mfma_f32_16x16x32_bf16(avh[mi], bvh[ni], acc[mi][ni], 0, 0, 0);
        acc[mi][ni] = __builtin_amdgcn_mfma_f32_16x16x32_bf16(avl[mi], bvh[ni], acc[mi][ni], 0, 0, 0);
        acc[mi][ni] = __builtin_amdgcn_mfma_f32_16x16x32_bf16(avh[mi], bvl[ni], acc[mi][ni], 0, 0, 0);
      }
    __syncthreads();
  }

  int cr = lane >> 4, cc = lane & 15;
#pragma unroll
  for (int mi = 0; mi < 4; ++mi) {
#pragma unroll
    for (int j = 0; j < 4; ++j) {
      int row = m0 + wr * 64 + mi * 16 + cr * 4 + j;
#pragma unroll
      for (int ni = 0; ni < 4; ++ni) {
        int col = n0 + wc * 64 + ni * 16 + cc;
        Cb[(size_t)row * 1024 + col] = acc[mi][ni][j];
      }
    }
  }
}

// ---------------- fp32 tiled GEMM (NN, fallback) ----------------
template <int FLAGS>
__global__ __launch_bounds__(256) void gemm_nn(const float* __restrict__ A,
    const float* __restrict__ B, float* __restrict__ C, const float* __restrict__ bias,
    const float* __restrict__ res, int M, int N, int K) {
  constexpr bool HAS_BIAS = (FLAGS & 1) != 0;
  constexpr bool HAS_GELU = (FLAGS & 2) != 0;
  constexpr bool HAS_RES = (FLAGS & 4) != 0;
  __shared__ float As[16][68];
  __shared__ float Bs[16][68];
  int tid = threadIdx.x;
  int m0 = blockIdx.y * 64, n0 = blockIdx.x * 64;
  int tx = tid & 15, ty = tid >> 4;
  int am = tid >> 2, ak = (tid & 3) * 4;
  int bk = tid >> 4, bn = (tid & 15) * 4;
  const float* Ap = A + (size_t)(m0 + am) * K + ak;
  const float* Bp = B + (size_t)bk * N + n0 + bn;
  float acc[4][4] = {};
  for (int k0 = 0; k0 < K; k0 += 16) {
    float4 a4 = *(const float4*)(Ap + k0);
    float4 b4 = *(const float4*)(Bp + (size_t)k0 * N);
    As[ak + 0][am] = a4.x; As[ak + 1][am] = a4.y;
    As[ak + 2][am] = a4.z; As[ak + 3][am] = a4.w;
    *(float4*)&Bs[bk][bn] = b4;
    __syncthreads();
#pragma unroll
    for (int k = 0; k < 16; ++k) {
      float4 bq = *(const float4*)&Bs[k][tx * 4];
#pragma unroll
      for (int i = 0; i < 4; ++i) {
        float av = As[k][ty * 4 + i];
        acc[i][0] += av * bq.x; acc[i][1] += av * bq.y;
        acc[i][2] += av * bq.z; acc[i][3] += av * bq.w;
      }
    }
    __syncthreads();
  }
#pragma unroll
  for (int i = 0; i < 4; ++i) {
    int row = m0 + ty * 4 + i;
#pragma unroll
    for (int j = 0; j < 4; ++j) {
      int col = n0 + tx * 4 + j;
      float vv = acc[i][j];
      if (HAS_BIAS) vv += bias[col];
      if (HAS_GELU) vv = 0.5f * vv * (1.0f + erff(vv * 0.70710678118654752f));
      if (HAS_RES) vv += res[(size_t)row * N + col];
      C[(size_t)row * N + col] = vv;
    }
  }
}

// ---------------- fp32 tiled GEMM (NT, fallback logits) ----------------
template <int FLAGS>
__global__ __launch_bounds__(256) void gemm_nt(const float* __restrict__ A,
    const float* __restrict__ B, float* __restrict__ C, const float* __restrict__ bias,
    const float* __restrict__ res, int M, int N, int K) {
  constexpr bool HAS_BIAS = (FLAGS & 1) != 0;
  constexpr bool HAS_GELU = (FLAGS & 2) != 0;
  constexpr bool HAS_RES = (FLAGS & 4) != 0;
  __shared__ float As[16][68];
  __shared__ float Bs[16][68];
  int tid = threadIdx.x;
  int m0 = blockIdx.y * 64, n0 = blockIdx.x * 64;
  int tx = tid & 15, ty = tid >> 4;
  int am = tid >> 2, ak = (tid & 3) * 4;
  int bn2 = tid >> 2, bk2 = (tid & 3) * 4;
  const float* Ap = A + (size_t)(m0 + am) * K + ak;
  const float* Bp = B + (size_t)(n0 + bn2) * K + bk2;
  float acc[4][4] = {};
  for (int k0 = 0; k0 < K; k0 += 16) {
    float4 a4 = *(const float4*)(Ap + k0);
    float4 b4 = *(const float4*)(Bp + k0);
    As[ak + 0][am] = a4.x; As[ak + 1][am] = a4.y;
    As[ak + 2][am] = a4.z; As[ak + 3][am] = a4.w;
    Bs[bk2 + 0][bn2] = b4.x; Bs[bk2 + 1][bn2] = b4.y;
    Bs[bk2 + 2][bn2] = b4.z; Bs[bk2 + 3][bn2] = b4.w;
    __syncthreads();
#pragma unroll
    for (int k = 0; k < 16; ++k) {
      float4 bq = *(const float4*)&Bs[k][tx * 4];
#pragma unroll
      for (int i = 0; i < 4; ++i) {
        float av = As[k][ty * 4 + i];
        acc[i][0] += av * bq.x; acc[i][1] += av * bq.y;
        acc[i][2] += av * bq.z; acc[i][3] += av * bq.w;
      }
    }
    __syncthreads();
  }
#pragma unroll
  for (int i = 0; i < 4; ++i) {
    int row = m0 + ty * 4 + i;
#pragma unroll
    for (int j = 0; j < 4; ++j) {
      int col = n0 + tx * 4 + j;
      float vv = acc[i][j];
      if (HAS_BIAS) vv += bias[col];
      if (HAS_GELU) vv = 0.5f * vv * (1.0f + erff(vv * 0.70710678118654752f));
      if (HAS_RES) vv += res[(size_t)row * N + col];
      C[(size_t)row * N + col] = vv;
    }
  }
}

// ---------------- host orchestration ----------------
extern "C" void kernel_launch(void* const* d_in, const int* in_sizes, int n_in,
                              void* d_out, int out_size, void* d_ws, size_t ws_size,
                              hipStream_t stream) {
  const int* ids = (const int*)d_in[0];
  const float* Wemb = (const float*)d_in[1];
  const float* Wpos = (const float*)d_in[2];
  const float* ln1_g = (const float*)d_in[3];
  const float* ln1_b = (const float*)d_in[4];
  const float* Wq = (const float*)d_in[5];
  const float* Wk = (const float*)d_in[6];
  const float* Wv = (const float*)d_in[7];
  const float* Wo = (const float*)d_in[8];
  const float* ln2_g = (const float*)d_in[9];
  const float* ln2_b = (const float*)d_in[10];
  const float* W1 = (const float*)d_in[11];
  const float* b1 = (const float*)d_in[12];
  const float* W2 = (const float*)d_in[13];
  const float* b2 = (const float*)d_in[14];
  const float* lnf_g = (const float*)d_in[15];
  const float* lnf_b = (const float*)d_in[16];

  const int T = in_sizes[0];          // 2048
  const int D = D_MODEL;
  const int VOC = in_sizes[1] / D;    // 32000

  char* ws = (char*)d_ws;
  float* x = (float*)(ws);
  float* xn = (float*)(ws + 8388608ull);
  unsigned short* xnbh = (unsigned short*)(ws + 8388608ull);
  unsigned short* xnbl = (unsigned short*)(ws + 12582912ull);
  float* q = (float*)(ws + 16777216ull);
  float* k = (float*)(ws + 25165824ull);
  float* v = (float*)(ws + 33554432ull);
  float* kt = (float*)(ws + 41943040ull);
  unsigned short* w1th = (unsigned short*)(ws + 16777216ull);
  unsigned short* w1tl = (unsigned short*)(ws + 25165824ull);
  unsigned short* w2th = (unsigned short*)(ws + 33554432ull);
  unsigned short* w2tl = (unsigned short*)(ws + 41943040ull);
  unsigned short* hbh = (unsigned short*)(ws + 50331648ull);
  unsigned short* hbl = (unsigned short*)(ws + 67108864ull);
  unsigned short* wqth = (unsigned short*)(ws + 50331648ull);   // overlay hbh (dead)
  unsigned short* wqtl = (unsigned short*)(ws + 52428800ull);
  unsigned short* wkth = (unsigned short*)(ws + 54525952ull);
  unsigned short* wktl = (unsigned short*)(ws + 56623104ull);
  unsigned short* wvth = (unsigned short*)(ws + 58720256ull);
  unsigned short* wvtl = (unsigned short*)(ws + 60817408ull);
  unsigned short* woth = (unsigned short*)(ws + 83886080ull);
  unsigned short* wotl = (unsigned short*)(ws + 85983232ull);
  unsigned short* wembb = (unsigned short*)(ws + 16777216ull);
  const size_t NEED = 88080384ull;  // 84 MB

  int kkeep = (T < 64) ? T : 64;
  int fk = (HEAD_DIM * kkeep + T - 1) / T;
  if (fk < 1) fk = 1;
  int nseg = T * N_HEADS;

  embed_kernel<<<T, 256, 0, stream>>>(ids, Wemb, Wpos, x);

  if (ws_size >= NEED && (T % 128) == 0 && (VOC % 128) == 0 &&
      (size_t)VOC * D * 2 <= 67108864ull) {
    // ---- bf16 MFMA path ----
    for (int l = 0; l < 2; ++l) {
      const float* wq = Wq + (size_t)l * D * D;
      const float* wk = Wk + (size_t)l * D * D;
      const float* wv = Wv + (size_t)l * D * D;
      const float* wo = Wo + (size_t)l * D * D;

      ln_kernel<<<T, 256, 0, stream>>>(x, nullptr, xnbh, xnbl,
                                       ln1_g + (size_t)l * D, ln1_b + (size_t)l * D);

      transpose_conv_pair_kernel<<<dim3(D / 32, D / 32), 256, 0, stream>>>(wq, wqth, wqtl, D, D);
      transpose_conv_pair_kernel<<<dim3(D / 32, D / 32), 256, 0, stream>>>(wk, wkth, wktl, D, D);
      transpose_conv_pair_kernel<<<dim3(D / 32, D / 32), 256, 0, stream>>>(wv, wvth, wvtl, D, D);

      gemm3_qkv<<<dim3(3 * D / 128, T / 128), 256, 0, stream>>>(
          xnbh, xnbl, wqth, wqtl, wkth, wktl, wvth, wvtl, q, T, D);

      sparsify_kernel<<<(3 * nseg + 3) / 4, 256, 0, stream>>>(q, 3 * nseg, fk);

      transpose_kernel<<<dim3(D / 32, T / 32), 256, 0, stream>>>(k, kt, T, D);

      attn_kernel<<<T * N_HEADS, 128, 0, stream>>>(q, kt, v, nullptr, xnbh, xnbl, T);

      transpose_conv_pair_kernel<<<dim3(D / 32, D / 32), 256, 0, stream>>>(wo, woth, wotl, D, D);
      gemm3_bt<4, 0><<<dim3(D / 128, T / 128), 256, 0, stream>>>(
          xnbh, xnbl, woth, wotl, x, nullptr, nullptr, nullptr, x, T, D, D);

      ln_kernel<<<T, 256, 0, stream>>>(x, nullptr, xnbh, xnbl,
                                       ln2_g + (size_t)l * D, ln2_b + (size_t)l * D);

      transpose_conv_pair_kernel<<<dim3(HIDDEN / 32, D / 32), 256, 0, stream>>>(
          W1 + (size_t)l * D * HIDDEN, w1th, w1tl, D, HIDDEN);
      gemm3_bt<3, 1><<<dim3(HIDDEN / 128, T / 128), 256, 0, stream>>>(
          xnbh, xnbl, w1th, w1tl, nullptr, hbh, hbl,
          b1 + (size_t)l * HIDDEN, nullptr, T, HIDDEN, D);
      transpose_conv_pair_kernel<<<dim3(D / 32, HIDDEN / 32), 256, 0, stream>>>(
          W2 + (size_t)l * HIDDEN * D, w2th, w2tl, HIDDEN, D);
      gemm3_bt<5, 0><<<dim3(D / 128, T / 128), 256, 0, stream>>>(
          hbh, hbl, w2th, w2tl, x, nullptr, nullptr,
          b2 + (size_t)l * D, x, T, D, HIDDEN);
    }

    ln_kernel<<<T, 256, 0, stream>>>(x, nullptr, xnbh, nullptr, lnf_g, lnf_b);

    conv_bf16_kernel<<<4096, 256, 0, stream>>>(Wemb, wembb, (size_t)VOC * D);

    gemm_bt_bf16<0, float, true><<<dim3(T / 128, VOC / 128), 256, 0, stream>>>(
        xnbh, wembb, (float*)d_out, nullptr, nullptr, T, VOC, D);
  } else {
    // ---- fp32 fallback ----
    float* hbuf = q;
    for (int l = 0; l < 2; ++l) {
      const float* wq = Wq + (size_t)l * D * D;
      const float* wk = Wk + (size_t)l * D * D;
      const float* wv = Wv + (size_t)l * D * D;
      const float* wo = Wo + (size_t)l * D * D;

      ln_kernel<<<T, 256, 0, stream>>>(x, xn, nullptr, nullptr,
                                       ln1_g + (size_t)l * D, ln1_b + (size_t)l * D);

      dim3 g1(D / 64, T / 64);
      gemm_nn<0><<<g1, 256, 0, stream>>>(xn, wq, q, nullptr, nullptr, T, D, D);
      gemm_nn<0><<<g1, 256, 0, stream>>>(xn, wk, k, nullptr, nullptr, T, D, D);
      gemm_nn<0><<<g1, 256, 0, stream>>>(xn, wv, v, nullptr, nullptr, T, D, D);

      sparsify_kernel<<<(nseg + 3) / 4, 256, 0, stream>>>(q, nseg, fk);
      sparsify_kernel<<<(nseg + 3) / 4, 256, 0, stream>>>(k, nseg, fk);
      sparsify_kernel<<<(nseg + 3) / 4, 256, 0, stream>>>(v, nseg, fk);

      transpose_kernel<<<dim3(D / 32, T / 32), 256, 0, stream>>>(k, kt, T, D);

      attn_kernel<<<T * N_HEADS, 128, 0, stream>>>(q, kt, v, xn, nullptr, nullptr, T);

      gemm_nn<4><<<g1, 256, 0, stream>>>(xn, wo, x, nullptr, x, T, D, D);

      ln_kernel<<<T, 256, 0, stream>>>(x, xn, nullptr, nullptr,
                                       ln2_g + (size_t)l * D, ln2_b + (size_t)l * D);

      gemm_nn<3><<<dim3(HIDDEN / 64, T / 64), 256, 0, stream>>>(
          xn, W1 + (size_t)l * D * HIDDEN, hbuf, b1 + (size_t)l * HIDDEN, nullptr, T, HIDDEN, D);
      gemm_nn<5><<<g1, 256, 0, stream>>>(
          hbuf, W2 + (size_t)l * HIDDEN * D, x, b2 + (size_t)l * D, x, T, D, HIDDEN);
    }

    ln_kernel<<<T, 256, 0, stream>>>(x, xn, nullptr, nullptr, lnf_g, lnf_b);

    gemm_nt<0><<<dim3(VOC / 64, T / 64), 256, 0, stream>>>(
        xn, Wemb, (float*)d_out, nullptr, nullptr, T, VOC, D);
  }
}

// Round 14
// 1341.380 us; speedup vs baseline: 1.4711x; 1.0150x over previous
//
#include <hip/hip_runtime.h>
#include <math.h>

#define D_MODEL 1024
#define N_HEADS 16
#define HEAD_DIM 64
#define HIDDEN 4096
#define TMAX 2048

typedef __attribute__((ext_vector_type(8))) short s16x8;
typedef __attribute__((ext_vector_type(4))) float f32x4;

// ---------------- wave helpers (wave64) ----------------
__device__ __forceinline__ float wave_max_f(float v) {
#pragma unroll
  for (int o = 32; o > 0; o >>= 1) v = fmaxf(v, __shfl_xor(v, o));
  return v;
}
__device__ __forceinline__ float wave_sum_f(float v) {
#pragma unroll
  for (int o = 32; o > 0; o >>= 1) v += __shfl_xor(v, o);
  return v;
}
__device__ __forceinline__ unsigned long long wave_max_u64(unsigned long long k) {
#pragma unroll
  for (int o = 32; o > 0; o >>= 1) {
    unsigned long long u = __shfl_xor(k, o);
    if (u > k) k = u;
  }
  return k;
}
__device__ __forceinline__ unsigned ford(float v) {
  unsigned u = __float_as_uint(v);
  return (u & 0x80000000u) ? ~u : (u | 0x80000000u);
}
// fp32 -> bf16 RNE
__device__ __forceinline__ unsigned short f2bf(float f) {
  unsigned u = __float_as_uint(f);
  u += 0x7FFFu + ((u >> 16) & 1u);
  return (unsigned short)(u >> 16);
}
__device__ __forceinline__ float bf2f(unsigned short h) {
  return __uint_as_float((unsigned)h << 16);
}

__device__ __forceinline__ void gload_lds16(const void* g, void* l) {
  __builtin_amdgcn_global_load_lds(
      (const __attribute__((address_space(1))) void*)g,
      (__attribute__((address_space(3))) void*)l, 16, 0, 0);
}

// ---------------- embedding ----------------
__global__ __launch_bounds__(256) void embed_kernel(const int* __restrict__ ids,
    const float* __restrict__ Wemb, const float* __restrict__ Wpos, float* __restrict__ X) {
  int t = blockIdx.x, tid = threadIdx.x;
  int id = ids[t];
  float4 e = ((const float4*)(Wemb + (size_t)id * D_MODEL))[tid];
  float4 p = ((const float4*)(Wpos + (size_t)t * D_MODEL))[tid];
  e.x += p.x; e.y += p.y; e.z += p.z; e.w += p.w;
  ((float4*)(X + (size_t)t * D_MODEL))[tid] = e;
}

// ---------------- layernorm; optional fp32 out + bf16 hi/lo out ----------------
__global__ __launch_bounds__(256) void ln_kernel(const float* __restrict__ X,
    float* __restrict__ Y, unsigned short* __restrict__ Ybh, unsigned short* __restrict__ Ybl,
    const float* __restrict__ g, const float* __restrict__ b) {
  int row = blockIdx.x, tid = threadIdx.x;
  int lane = tid & 63, wid = tid >> 6;
  __shared__ float red[8];
  float4 v = ((const float4*)(X + (size_t)row * D_MODEL))[tid];
  float s = v.x + v.y + v.z + v.w;
  s = wave_sum_f(s);
  if (lane == 0) red[wid] = s;
  __syncthreads();
  float mean = (red[0] + red[1] + red[2] + red[3]) * (1.0f / D_MODEL);
  float dx = v.x - mean, dy = v.y - mean, dz = v.z - mean, dw = v.w - mean;
  float q = dx * dx + dy * dy + dz * dz + dw * dw;
  q = wave_sum_f(q);
  if (lane == 0) red[4 + wid] = q;
  __syncthreads();
  float var = (red[4] + red[5] + red[6] + red[7]) * (1.0f / D_MODEL);
  float rs = rsqrtf(var + 1e-5f);
  float4 gg = ((const float4*)g)[tid], bb = ((const float4*)b)[tid];
  float4 y;
  y.x = dx * rs * gg.x + bb.x;
  y.y = dy * rs * gg.y + bb.y;
  y.z = dz * rs * gg.z + bb.z;
  y.w = dw * rs * gg.w + bb.w;
  if (Y) ((float4*)(Y + (size_t)row * D_MODEL))[tid] = y;
  if (Ybh) {
    ushort4 oh;
    oh.x = f2bf(y.x); oh.y = f2bf(y.y); oh.z = f2bf(y.z); oh.w = f2bf(y.w);
    ((ushort4*)(Ybh + (size_t)row * D_MODEL))[tid] = oh;
    if (Ybl) {
      ushort4 ol;
      ol.x = f2bf(y.x - bf2f(oh.x)); ol.y = f2bf(y.y - bf2f(oh.y));
      ol.z = f2bf(y.z - bf2f(oh.z)); ol.w = f2bf(y.w - bf2f(oh.w));
      ((ushort4*)(Ybl + (size_t)row * D_MODEL))[tid] = ol;
    }
  }
}

// ---------------- sparsify (exact top-fk by |value| per 64 segment) ----------------
__global__ __launch_bounds__(256) void sparsify_kernel(float* __restrict__ X, int nseg, int fk) {
  int seg = blockIdx.x * 4 + (threadIdx.x >> 6);
  if (seg >= nseg) return;
  int lane = threadIdx.x & 63;
  size_t idx = (size_t)seg * 64 + lane;
  float x = X[idx];
  float a = fabsf(x);
  float cur = INFINITY;
  int remaining = fk;
  float thr = 0.0f;
  for (;;) {
    float cand = (a < cur) ? a : -INFINITY;
    float mv = wave_max_f(cand);
    if (mv == -INFINITY) { thr = mv; break; }
    int c = __popcll(__ballot(a == mv));
    if (c >= remaining) { thr = mv; break; }
    remaining -= c; cur = mv;
  }
  if (!(a >= thr)) X[idx] = 0.0f;
}

// ---------------- transpose fp32 [R][C] -> [C][R] ----------------
__global__ __launch_bounds__(256) void transpose_kernel(const float* __restrict__ in,
    float* __restrict__ out, int R, int Cc) {
  __shared__ float tile[32][33];
  int c0 = blockIdx.x * 32, r0 = blockIdx.y * 32;
  int tx = threadIdx.x & 31, ty = threadIdx.x >> 5;
  for (int i = ty; i < 32; i += 8)
    tile[i][tx] = in[(size_t)(r0 + i) * Cc + c0 + tx];
  __syncthreads();
  for (int i = ty; i < 32; i += 8)
    out[(size_t)(c0 + i) * R + r0 + tx] = tile[tx][i];
}

// ---------------- transpose-convert fp32 [R][C] -> bf16 hi/lo [C][R] ----------------
__global__ __launch_bounds__(256) void transpose_conv_pair_kernel(const float* __restrict__ in,
    unsigned short* __restrict__ oh, unsigned short* __restrict__ ol, int R, int Cc) {
  __shared__ float tile[32][33];
  int c0 = blockIdx.x * 32, r0 = blockIdx.y * 32;
  int tx = threadIdx.x & 31, ty = threadIdx.x >> 5;
  for (int i = ty; i < 32; i += 8)
    tile[i][tx] = in[(size_t)(r0 + i) * Cc + c0 + tx];
  __syncthreads();
  for (int i = ty; i < 32; i += 8) {
    float v = tile[tx][i];
    unsigned short h = f2bf(v);
    size_t idx = (size_t)(c0 + i) * R + r0 + tx;
    oh[idx] = h;
    ol[idx] = f2bf(v - bf2f(h));
  }
}

// ---------------- fused 4x square transpose-convert (blockIdx.z selects) ----------------
__global__ __launch_bounds__(256) void transpose_conv_pair4_kernel(
    const float* __restrict__ s0, unsigned short* __restrict__ h0, unsigned short* __restrict__ l0,
    const float* __restrict__ s1, unsigned short* __restrict__ h1, unsigned short* __restrict__ l1,
    const float* __restrict__ s2, unsigned short* __restrict__ h2, unsigned short* __restrict__ l2,
    const float* __restrict__ s3, unsigned short* __restrict__ h3, unsigned short* __restrict__ l3,
    int R, int Cc) {
  const float* in = s0; unsigned short* oh = h0; unsigned short* ol = l0;
  if (blockIdx.z == 1) { in = s1; oh = h1; ol = l1; }
  else if (blockIdx.z == 2) { in = s2; oh = h2; ol = l2; }
  else if (blockIdx.z == 3) { in = s3; oh = h3; ol = l3; }
  __shared__ float tile[32][33];
  int c0 = blockIdx.x * 32, r0 = blockIdx.y * 32;
  int tx = threadIdx.x & 31, ty = threadIdx.x >> 5;
  for (int i = ty; i < 32; i += 8)
    tile[i][tx] = in[(size_t)(r0 + i) * Cc + c0 + tx];
  __syncthreads();
  for (int i = ty; i < 32; i += 8) {
    float v = tile[tx][i];
    unsigned short h = f2bf(v);
    size_t idx = (size_t)(c0 + i) * R + r0 + tx;
    oh[idx] = h;
    ol[idx] = f2bf(v - bf2f(h));
  }
}

// ---------------- fp32 -> bf16 elementwise ----------------
__global__ __launch_bounds__(256) void conv_bf16_kernel(const float* __restrict__ in,
    unsigned short* __restrict__ out, size_t n) {
  size_t i = ((size_t)blockIdx.x * 256 + threadIdx.x) * 4;
  size_t stride = (size_t)gridDim.x * 1024;
  for (; i < n; i += stride) {
    float4 v = *(const float4*)(in + i);
    ushort4 o;
    o.x = f2bf(v.x); o.y = f2bf(v.y); o.z = f2bf(v.z); o.w = f2bf(v.w);
    *(ushort4*)(out + i) = o;
  }
}

// ---------------- attention: 2 waves per (head, query-row) job ----------------
// r12-proven selection (wave-0 compaction); strip-mined score pass; batch-16 gather.
__global__ __launch_bounds__(128) void attn_kernel(const float* __restrict__ Q,
    const float* __restrict__ Kt, const float* __restrict__ V,
    float* __restrict__ Of, unsigned short* __restrict__ Oh, unsigned short* __restrict__ Ol,
    int T) {
  int t = T - 1 - (blockIdx.x % T);   // longest jobs dispatch first
  int h = blockIdx.x / T;
  int tid = threadIdx.x;
  int lane = tid & 63;
  int wvid = tid >> 6;
  unsigned long long lmlt = (1ull << lane) - 1ull;

  __shared__ float sc[TMAX];
  __shared__ float qval[HEAD_DIM];
  __shared__ int qdim[HEAD_DIM];
  constexpr int PCAP = 320;
  __shared__ float posv[PCAP];
  __shared__ int posi[PCAP];
  __shared__ int seli[64];
  __shared__ float selv[64];
  __shared__ float wsel[64];
  __shared__ float partial[64];
  __shared__ int nq_sh;

  int hoff = h * HEAD_DIM;
  if (wvid == 0) {
    float qv = Q[(size_t)t * D_MODEL + hoff + lane];
    unsigned long long nzm = __ballot(qv != 0.0f);
    int nq0 = __popcll(nzm);
    if (qv != 0.0f) {
      int p = __popcll(nzm & lmlt);
      qval[p] = qv; qdim[p] = lane;
    }
    seli[lane] = 0;  // pad target for fixed-trip gather
    if (lane == 0) nq_sh = nq0;
  }
  __syncthreads();  // B1

  int nq = nq_sh;
  int Vn = t + 1;
  // ---- score pass over 128 lanes; strip-mined x4 (8 loads in flight) ----
  if (nq == 2) {
    float qA = qval[0], qB = qval[1];
    const float* ktA = Kt + (size_t)(hoff + qdim[0]) * T;
    const float* ktB = Kt + (size_t)(hoff + qdim[1]) * T;
    int s = tid;
    for (; s + 384 < Vn; s += 512) {
      float a0 = ktA[s],       b0 = ktB[s];
      float a1 = ktA[s + 128], b1 = ktB[s + 128];
      float a2 = ktA[s + 256], b2 = ktB[s + 256];
      float a3 = ktA[s + 384], b3 = ktB[s + 384];
      sc[s]       = fmaf(qB, b0, qA * a0) * 0.125f;
      sc[s + 128] = fmaf(qB, b1, qA * a1) * 0.125f;
      sc[s + 256] = fmaf(qB, b2, qA * a2) * 0.125f;
      sc[s + 384] = fmaf(qB, b3, qA * a3) * 0.125f;
    }
    for (; s < Vn; s += 128)
      sc[s] = fmaf(qB, ktB[s], qA * ktA[s]) * 0.125f;
  } else {
    for (int s = tid; s < Vn; s += 128) {
      float acc = 0.0f;
      for (int j = 0; j < nq; ++j)
        acc += qval[j] * Kt[(size_t)(hoff + qdim[j]) * T + s];
      sc[s] = acc * 0.125f;
    }
  }
  __syncthreads();  // B2

  // ---- selection + softmax: wave 0 only (lockstep; no barriers inside) ----
  if (wvid == 0) {
    int nsel = 0;
    if (Vn <= 64) {
      nsel = Vn;
      if (lane < Vn) { seli[lane] = lane; selv[lane] = sc[lane]; }
    } else {
      // compact positive scores (list index order == s order)
      int base = 0;
      for (int s0 = 0; s0 < Vn; s0 += 64) {
        int s = s0 + lane;
        float v = (s < Vn) ? sc[s] : -1.0f;
        unsigned long long pm = __ballot(v > 0.0f);
        if (v > 0.0f) {
          int p = base + __popcll(pm & lmlt);
          if (p < PCAP) { posv[p] = v; posi[p] = s; }
        }
        base += __popcll(pm);
      }
      int P = base;

      bool fullpath = false;
      if (P >= 64) {
        if (P <= 128) {
          // ---- bitonic-128 top-64 ----
          unsigned long long key0, key1;
          {
            int e0 = lane, e1 = lane + 64;
            key0 = (e0 < P) ? (((unsigned long long)ford(posv[e0]) << 32) |
                               (unsigned long long)(0xFFFFFFFFu - (unsigned)e0)) : 0ull;
            key1 = (e1 < P) ? (((unsigned long long)ford(posv[e1]) << 32) |
                               (unsigned long long)(0xFFFFFFFFu - (unsigned)e1)) : 0ull;
          }
          for (int k = 2; k <= 128; k <<= 1) {
            for (int j = k >> 1; j > 0; j >>= 1) {
              if (j == 64) {
                if (key0 < key1) { unsigned long long tm = key0; key0 = key1; key1 = tm; }
              } else {
                bool iLower = (lane & j) == 0;
                {
                  unsigned long long prt = __shfl_xor(key0, j);
                  bool desc = ((lane & k) == 0);
                  bool keepMax = (iLower == desc);
                  key0 = keepMax ? (key0 > prt ? key0 : prt) : (key0 < prt ? key0 : prt);
                }
                {
                  unsigned long long prt = __shfl_xor(key1, j);
                  int e1 = lane + 64;
                  bool desc = ((e1 & k) == 0);
                  bool keepMax = (iLower == desc);
                  key1 = keepMax ? (key1 > prt ? key1 : prt) : (key1 < prt ? key1 : prt);
                }
              }
            }
          }
          int e = (int)(0xFFFFFFFFu - (unsigned)(key0 & 0xFFFFFFFFull));
          seli[lane] = posi[e];
          selv[lane] = posv[e];
          nsel = 64;
        } else if (P <= PCAP) {
          for (int r = 0; r < 64; ++r) {
            unsigned long long best = 0ull;
            for (int j = lane; j < P; j += 64) {
              float v = posv[j];
              if (v > 0.0f) {
                unsigned long long key =
                    ((unsigned long long)ford(v) << 32) | (unsigned)(0xFFFFFFFFu - (unsigned)j);
                if (key > best) best = key;
              }
            }
            best = wave_max_u64(best);
            int j = (int)(0xFFFFFFFFu - (unsigned)(best & 0xFFFFFFFFull));
            if (lane == (j & 63)) {
              seli[r] = posi[j]; selv[r] = posv[j]; posv[j] = -INFINITY;
            }
          }
          nsel = 64;
        } else {
          fullpath = true;
        }
      } else {
        if (lane < P) { seli[lane] = posi[lane]; selv[lane] = posv[lane]; }
        int need = 64 - P;
        int zbase = 0;
        bool done = false;
        for (int s0 = 0; s0 < Vn && !done; s0 += 64) {
          int s = s0 + lane;
          bool isz = (s < Vn) && (sc[s] == 0.0f);
          unsigned long long zm = __ballot(isz);
          int pre = __popcll(zm & lmlt);
          if (isz && (zbase + pre) < need) {
            seli[P + zbase + pre] = s;
            selv[P + zbase + pre] = 0.0f;
          }
          zbase += __popcll(zm);
          if (zbase >= need) done = true;
        }
        if (zbase >= need) {
          nsel = 64;
        } else {
          fullpath = true;
        }
      }

      if (fullpath) {
        nsel = 64;
        for (int r = 0; r < 64; ++r) {
          unsigned long long best = 0ull;
          for (int s = lane; s < Vn; s += 64) {
            float v = sc[s];
            if (v != -INFINITY) {
              unsigned long long key =
                  ((unsigned long long)ford(v) << 32) | (unsigned)(0x7FFFFFFFu - (unsigned)s);
              if (key > best) best = key;
            }
          }
          best = wave_max_u64(best);
          if (best == 0ull) { nsel = r; break; }
          int s = (int)(0x7FFFFFFFu - (unsigned)(best & 0xFFFFFFFFull));
          if (lane == (s & 63)) {
            seli[r] = s; selv[r] = sc[s]; sc[s] = -INFINITY;
          }
        }
      }
    }

    // softmax weights (wsel[lane]==0 for lane >= nsel)
    float v = (lane < nsel) ? selv[lane] : -INFINITY;
    float m = wave_max_f(v);
    float w = (lane < nsel) ? expf(v - m) : 0.0f;
    float ds = wave_sum_f(w);
    wsel[lane] = w / ds;
  }
  __syncthreads();  // B3

  // ---- gather: wave0 sums r=0..31, wave1 sums r=32..63; batch-16 loads ----
  float o = 0.0f;
  int rbase = wvid * 32;
  const float* Vb = V + hoff + lane;
#pragma unroll
  for (int r0 = 0; r0 < 32; r0 += 16) {
    float wv[16];
    int ib[16];
#pragma unroll
    for (int i = 0; i < 16; ++i) {
      wv[i] = wsel[rbase + r0 + i];
      ib[i] = seli[rbase + r0 + i];
    }
    float vv[16];
#pragma unroll
    for (int i = 0; i < 16; ++i) vv[i] = Vb[(size_t)ib[i] * D_MODEL];
#pragma unroll
    for (int i = 0; i < 16; ++i) o = fmaf(wv[i], vv[i], o);
  }
  if (wvid == 1) partial[lane] = o;
  __syncthreads();  // B4
  if (wvid == 0) {
    o += partial[lane];
    size_t oidx = (size_t)t * D_MODEL + hoff + lane;
    if (Of) Of[oidx] = o;
    if (Oh) {
      unsigned short hh = f2bf(o);
      Oh[oidx] = hh;
      Ol[oidx] = f2bf(o - bf2f(hh));
    }
  }
}

// ============ single bf16 MFMA GEMM (NT): C[M,N] = A @ B^T ============
template <int FLAGS, typename CT, bool SWAPXY = false>
__global__ __launch_bounds__(256) void gemm_bt_bf16(const unsigned short* __restrict__ A,
    const unsigned short* __restrict__ B, CT* __restrict__ C,
    const float* __restrict__ bias, const float* __restrict__ res, int M, int N, int K) {
  constexpr bool HAS_BIAS = (FLAGS & 1) != 0;
  constexpr bool HAS_GELU = (FLAGS & 2) != 0;
  constexpr bool HAS_RES = (FLAGS & 4) != 0;
  __shared__ unsigned short As[128 * 32];
  __shared__ unsigned short Bs[128 * 32];
  int tid = threadIdx.x;
  int lane = tid & 63, wid = tid >> 6;
  int wr = wid >> 1, wc = wid & 1;
  int m0 = (SWAPXY ? blockIdx.x : blockIdx.y) * 128;
  int n0 = (SWAPXY ? blockIdx.y : blockIdx.x) * 128;

  int r_in = lane >> 2;
  int slot = lane & 3;

  f32x4 acc[4][4] = {};

  int fr = lane & 15;
  int ksl = lane >> 4;

  for (int k0 = 0; k0 < K; k0 += 32) {
#pragma unroll
    for (int s = 0; s < 2; ++s) {
      int row = wid * 32 + s * 16 + r_in;
      int ksw = (slot ^ ((row >> 1) & 3)) * 8;
      const unsigned short* ga = A + (size_t)(m0 + row) * K + k0 + ksw;
      const unsigned short* gb = B + (size_t)(n0 + row) * K + k0 + ksw;
      gload_lds16(ga, &As[(wid * 32 + s * 16) * 32]);
      gload_lds16(gb, &Bs[(wid * 32 + s * 16) * 32]);
    }
    asm volatile("s_waitcnt vmcnt(0)" ::: "memory");
    __syncthreads();

    s16x8 av[4], bv[4];
#pragma unroll
    for (int mi = 0; mi < 4; ++mi) {
      int ar = wr * 64 + mi * 16 + fr;
      av[mi] = *(const s16x8*)&As[ar * 32 + ((ksl ^ ((ar >> 1) & 3)) * 8)];
    }
#pragma unroll
    for (int ni = 0; ni < 4; ++ni) {
      int br = wc * 64 + ni * 16 + fr;
      bv[ni] = *(const s16x8*)&Bs[br * 32 + ((ksl ^ ((br >> 1) & 3)) * 8)];
    }
#pragma unroll
    for (int mi = 0; mi < 4; ++mi)
#pragma unroll
      for (int ni = 0; ni < 4; ++ni)
        acc[mi][ni] = __builtin_amdgcn_mfma_f32_16x16x32_bf16(av[mi], bv[ni], acc[mi][ni], 0, 0, 0);
    __syncthreads();
  }

  int cr = lane >> 4, cc = lane & 15;
#pragma unroll
  for (int mi = 0; mi < 4; ++mi) {
#pragma unroll
    for (int j = 0; j < 4; ++j) {
      int row = m0 + wr * 64 + mi * 16 + cr * 4 + j;
#pragma unroll
      for (int ni = 0; ni < 4; ++ni) {
        int col = n0 + wc * 64 + ni * 16 + cc;
        float vv = acc[mi][ni][j];
        if (HAS_BIAS) vv += bias[col];
        if (HAS_GELU) vv = 0.5f * vv * (1.0f + erff(vv * 0.70710678118654752f));
        if (HAS_RES) vv += res[(size_t)row * N + col];
        if constexpr (sizeof(CT) == 2)
          C[(size_t)row * N + col] = (CT)f2bf(vv);
        else
          C[(size_t)row * N + col] = (CT)vv;
      }
    }
  }
}

// ============ bf16x3 split-precision MFMA GEMM (NT) ============
template <int FLAGS, int OUTMODE>
__global__ __launch_bounds__(256) void gemm3_bt(
    const unsigned short* __restrict__ Ah, const unsigned short* __restrict__ Al,
    const unsigned short* __restrict__ Bh, const unsigned short* __restrict__ Bl,
    float* __restrict__ Cf, unsigned short* __restrict__ Ch, unsigned short* __restrict__ Cl,
    const float* __restrict__ bias, const float* __restrict__ res, int M, int N, int K) {
  constexpr bool HAS_BIAS = (FLAGS & 1) != 0;
  constexpr bool HAS_GELU = (FLAGS & 2) != 0;
  constexpr bool HAS_RES = (FLAGS & 4) != 0;
  __shared__ unsigned short As[2][128 * 32];
  __shared__ unsigned short Bs[2][128 * 32];
  int tid = threadIdx.x;
  int lane = tid & 63, wid = tid >> 6;
  int wr = wid >> 1, wc = wid & 1;
  int m0 = blockIdx.y * 128, n0 = blockIdx.x * 128;

  int r_in = lane >> 2;
  int slot = lane & 3;

  f32x4 acc[4][4] = {};

  int fr = lane & 15;
  int ksl = lane >> 4;

  for (int k0 = 0; k0 < K; k0 += 32) {
#pragma unroll
    for (int s = 0; s < 2; ++s) {
      int row = wid * 32 + s * 16 + r_in;
      int ksw = (slot ^ ((row >> 1) & 3)) * 8;
      size_t ao = (size_t)(m0 + row) * K + k0 + ksw;
      size_t bo = (size_t)(n0 + row) * K + k0 + ksw;
      int ldst = (wid * 32 + s * 16) * 32;
      gload_lds16(Ah + ao, &As[0][ldst]);
      gload_lds16(Al + ao, &As[1][ldst]);
      gload_lds16(Bh + bo, &Bs[0][ldst]);
      gload_lds16(Bl + bo, &Bs[1][ldst]);
    }
    asm volatile("s_waitcnt vmcnt(0)" ::: "memory");
    __syncthreads();

    s16x8 avh[4], avl[4], bvh[4], bvl[4];
#pragma unroll
    for (int mi = 0; mi < 4; ++mi) {
      int ar = wr * 64 + mi * 16 + fr;
      int off = ar * 32 + ((ksl ^ ((ar >> 1) & 3)) * 8);
      avh[mi] = *(const s16x8*)&As[0][off];
      avl[mi] = *(const s16x8*)&As[1][off];
    }
#pragma unroll
    for (int ni = 0; ni < 4; ++ni) {
      int br = wc * 64 + ni * 16 + fr;
      int off = br * 32 + ((ksl ^ ((br >> 1) & 3)) * 8);
      bvh[ni] = *(const s16x8*)&Bs[0][off];
      bvl[ni] = *(const s16x8*)&Bs[1][off];
    }
#pragma unroll
    for (int mi = 0; mi < 4; ++mi)
#pragma unroll
      for (int ni = 0; ni < 4; ++ni) {
        acc[mi][ni] = __builtin_amdgcn_mfma_f32_16x16x32_bf16(avh[mi], bvh[ni], acc[mi][ni], 0, 0, 0);
        acc[mi][ni] = __builtin_amdgcn_mfma_f32_16x16x32_bf16(avl[mi], bvh[ni], acc[mi][ni], 0, 0, 0);
        acc[mi][ni] = __builtin_amdgcn_mfma_f32_16x16x32_bf16(avh[mi], bvl[ni], acc[mi][ni], 0, 0, 0);
      }
    __syncthreads();
  }

  int cr = lane >> 4, cc = lane & 15;
#pragma unroll
  for (int mi = 0; mi < 4; ++mi) {
#pragma unroll
    for (int j = 0; j < 4; ++j) {
      int row = m0 + wr * 64 + mi * 16 + cr * 4 + j;
#pragma unroll
      for (int ni = 0; ni < 4; ++ni) {
        int col = n0 + wc * 64 + ni * 16 + cc;
        float vv = acc[mi][ni][j];
        if (HAS_BIAS) vv += bias[col];
        if (HAS_GELU) vv = 0.5f * vv * (1.0f + erff(vv * 0.70710678118654752f));
        if (HAS_RES) vv += res[(size_t)row * N + col];
        if constexpr (OUTMODE == 0) {
          Cf[(size_t)row * N + col] = vv;
        } else {
          unsigned short h = f2bf(vv);
          Ch[(size_t)row * N + col] = h;
          Cl[(size_t)row * N + col] = f2bf(vv - bf2f(h));
        }
      }
    }
  }
}

// ============ bf16x3 fused QKV (NT): [q|k|v] = xn @ [Wq^T|Wk^T|Wv^T], fp32 out ====
__global__ __launch_bounds__(256) void gemm3_qkv(
    const unsigned short* __restrict__ Ah, const unsigned short* __restrict__ Al,
    const unsigned short* __restrict__ Bqh, const unsigned short* __restrict__ Bql,
    const unsigned short* __restrict__ Bkh, const unsigned short* __restrict__ Bkl,
    const unsigned short* __restrict__ Bvh, const unsigned short* __restrict__ Bvl,
    float* __restrict__ C, int M, int K) {
  __shared__ unsigned short As[2][128 * 32];
  __shared__ unsigned short Bs[2][128 * 32];
  int tid = threadIdx.x;
  int lane = tid & 63, wid = tid >> 6;
  int wr = wid >> 1, wc = wid & 1;
  int m0 = blockIdx.y * 128;
  int n0g = blockIdx.x * 128;
  int mat = n0g >> 10;               // 0,1,2
  const unsigned short* Bh = (mat == 0) ? Bqh : (mat == 1 ? Bkh : Bvh);
  const unsigned short* Bl = (mat == 0) ? Bql : (mat == 1 ? Bkl : Bvl);
  float* Cb = C + (size_t)mat * ((size_t)M * 1024);
  int n0 = n0g & 1023;

  int r_in = lane >> 2;
  int slot = lane & 3;

  f32x4 acc[4][4] = {};

  int fr = lane & 15;
  int ksl = lane >> 4;

  for (int k0 = 0; k0 < K; k0 += 32) {
#pragma unroll
    for (int s = 0; s < 2; ++s) {
      int row = wid * 32 + s * 16 + r_in;
      int ksw = (slot ^ ((row >> 1) & 3)) * 8;
      size_t ao = (size_t)(m0 + row) * K + k0 + ksw;
      size_t bo = (size_t)(n0 + row) * K + k0 + ksw;
      int ldst = (wid * 32 + s * 16) * 32;
      gload_lds16(Ah + ao, &As[0][ldst]);
      gload_lds16(Al + ao, &As[1][ldst]);
      gload_lds16(Bh + bo, &Bs[0][ldst]);
      gload_lds16(Bl + bo, &Bs[1][ldst]);
    }
    asm volatile("s_waitcnt vmcnt(0)" ::: "memory");
    __syncthreads();

    s16x8 avh[4], avl[4], bvh[4], bvl[4];
#pragma unroll
    for (int mi = 0; mi < 4; ++mi) {
      int ar = wr * 64 + mi * 16 + fr;
      int off = ar * 32 + ((ksl ^ ((ar >> 1) & 3)) * 8);
      avh[mi] = *(const s16x8*)&As[0][off];
      avl[mi] = *(const s16x8*)&As[1][off];
    }
#pragma unroll
    for (int ni = 0; ni < 4; ++ni) {
      int br = wc * 64 + ni * 16 + fr;
      int off = br * 32 + ((ksl ^ ((br >> 1) & 3)) * 8);
      bvh[ni] = *(const s16x8*)&Bs[0][off];
      bvl[ni] = *(const s16x8*)&Bs[1][off];
    }
#pragma unroll
    for (int mi = 0; mi < 4; ++mi)
#pragma unroll
      for (int ni = 0; ni < 4; ++ni) {
        acc[mi][ni] = __builtin_amdgcn_mfma_f32_16x16x32_bf16(avh[mi], bvh[ni], acc[mi][ni], 0, 0, 0);
        acc[mi][ni] = __builtin_amdgcn_mfma_f32_16x16x32_bf16(avl[mi], bvh[ni], acc[mi][ni], 0, 0, 0);
        acc[mi][ni] = __builtin_amdgcn_mfma_f32_16x16x32_bf16(avh[mi], bvl[ni], acc[mi][ni], 0, 0, 0);
      }
    __syncthreads();
  }

  int cr = lane >> 4, cc = lane & 15;
#pragma unroll
  for (int mi = 0; mi < 4; ++mi) {
#pragma unroll
    for (int j = 0; j < 4; ++j) {
      int row = m0 + wr * 64 + mi * 16 + cr * 4 + j;
#pragma unroll
      for (int ni = 0; ni < 4; ++ni) {
        int col = n0 + wc * 64 + ni * 16 + cc;
        Cb[(size_t)row * 1024 + col] = acc[mi][ni][j];
      }
    }
  }
}

// ---------------- fp32 tiled GEMM (NN, fallback) ----------------
template <int FLAGS>
__global__ __launch_bounds__(256) void gemm_nn(const float* __restrict__ A,
    const float* __restrict__ B, float* __restrict__ C, const float* __restrict__ bias,
    const float* __restrict__ res, int M, int N, int K) {
  constexpr bool HAS_BIAS = (FLAGS & 1) != 0;
  constexpr bool HAS_GELU = (FLAGS & 2) != 0;
  constexpr bool HAS_RES = (FLAGS & 4) != 0;
  __shared__ float As[16][68];
  __shared__ float Bs[16][68];
  int tid = threadIdx.x;
  int m0 = blockIdx.y * 64, n0 = blockIdx.x * 64;
  int tx = tid & 15, ty = tid >> 4;
  int am = tid >> 2, ak = (tid & 3) * 4;
  int bk = tid >> 4, bn = (tid & 15) * 4;
  const float* Ap = A + (size_t)(m0 + am) * K + ak;
  const float* Bp = B + (size_t)bk * N + n0 + bn;
  float acc[4][4] = {};
  for (int k0 = 0; k0 < K; k0 += 16) {
    float4 a4 = *(const float4*)(Ap + k0);
    float4 b4 = *(const float4*)(Bp + (size_t)k0 * N);
    As[ak + 0][am] = a4.x; As[ak + 1][am] = a4.y;
    As[ak + 2][am] = a4.z; As[ak + 3][am] = a4.w;
    *(float4*)&Bs[bk][bn] = b4;
    __syncthreads();
#pragma unroll
    for (int k = 0; k < 16; ++k) {
      float4 bq = *(const float4*)&Bs[k][tx * 4];
#pragma unroll
      for (int i = 0; i < 4; ++i) {
        float av = As[k][ty * 4 + i];
        acc[i][0] += av * bq.x; acc[i][1] += av * bq.y;
        acc[i][2] += av * bq.z; acc[i][3] += av * bq.w;
      }
    }
    __syncthreads();
  }
#pragma unroll
  for (int i = 0; i < 4; ++i) {
    int row = m0 + ty * 4 + i;
#pragma unroll
    for (int j = 0; j < 4; ++j) {
      int col = n0 + tx * 4 + j;
      float vv = acc[i][j];
      if (HAS_BIAS) vv += bias[col];
      if (HAS_GELU) vv = 0.5f * vv * (1.0f + erff(vv * 0.70710678118654752f));
      if (HAS_RES) vv += res[(size_t)row * N + col];
      C[(size_t)row * N + col] = vv;
    }
  }
}

// ---------------- fp32 tiled GEMM (NT, fallback logits) ----------------
template <int FLAGS>
__global__ __launch_bounds__(256) void gemm_nt(const float* __restrict__ A,
    const float* __restrict__ B, float* __restrict__ C, const float* __restrict__ bias,
    const float* __restrict__ res, int M, int N, int K) {
  constexpr bool HAS_BIAS = (FLAGS & 1) != 0;
  constexpr bool HAS_GELU = (FLAGS & 2) != 0;
  constexpr bool HAS_RES = (FLAGS & 4) != 0;
  __shared__ float As[16][68];
  __shared__ float Bs[16][68];
  int tid = threadIdx.x;
  int m0 = blockIdx.y * 64, n0 = blockIdx.x * 64;
  int tx = tid & 15, ty = tid >> 4;
  int am = tid >> 2, ak = (tid & 3) * 4;
  int bn2 = tid >> 2, bk2 = (tid & 3) * 4;
  const float* Ap = A + (size_t)(m0 + am) * K + ak;
  const float* Bp = B + (size_t)(n0 + bn2) * K + bk2;
  float acc[4][4] = {};
  for (int k0 = 0; k0 < K; k0 += 16) {
    float4 a4 = *(const float4*)(Ap + k0);
    float4 b4 = *(const float4*)(Bp + k0);
    As[ak + 0][am] = a4.x; As[ak + 1][am] = a4.y;
    As[ak + 2][am] = a4.z; As[ak + 3][am] = a4.w;
    Bs[bk2 + 0][bn2] = b4.x; Bs[bk2 + 1][bn2] = b4.y;
    Bs[bk2 + 2][bn2] = b4.z; Bs[bk2 + 3][bn2] = b4.w;
    __syncthreads();
#pragma unroll
    for (int k = 0; k < 16; ++k) {
      float4 bq = *(const float4*)&Bs[k][tx * 4];
#pragma unroll
      for (int i = 0; i < 4; ++i) {
        float av = As[k][ty * 4 + i];
        acc[i][0] += av * bq.x; acc[i][1] += av * bq.y;
        acc[i][2] += av * bq.z; acc[i][3] += av * bq.w;
      }
    }
    __syncthreads();
  }
#pragma unroll
  for (int i = 0; i < 4; ++i) {
    int row = m0 + ty * 4 + i;
#pragma unroll
    for (int j = 0; j < 4; ++j) {
      int col = n0 + tx * 4 + j;
      float vv = acc[i][j];
      if (HAS_BIAS) vv += bias[col];
      if (HAS_GELU) vv = 0.5f * vv * (1.0f + erff(vv * 0.70710678118654752f));
      if (HAS_RES) vv += res[(size_t)row * N + col];
      C[(size_t)row * N + col] = vv;
    }
  }
}

// ---------------- host orchestration ----------------
extern "C" void kernel_launch(void* const* d_in, const int* in_sizes, int n_in,
                              void* d_out, int out_size, void* d_ws, size_t ws_size,
                              hipStream_t stream) {
  const int* ids = (const int*)d_in[0];
  const float* Wemb = (const float*)d_in[1];
  const float* Wpos = (const float*)d_in[2];
  const float* ln1_g = (const float*)d_in[3];
  const float* ln1_b = (const float*)d_in[4];
  const float* Wq = (const float*)d_in[5];
  const float* Wk = (const float*)d_in[6];
  const float* Wv = (const float*)d_in[7];
  const float* Wo = (const float*)d_in[8];
  const float* ln2_g = (const float*)d_in[9];
  const float* ln2_b = (const float*)d_in[10];
  const float* W1 = (const float*)d_in[11];
  const float* b1 = (const float*)d_in[12];
  const float* W2 = (const float*)d_in[13];
  const float* b2 = (const float*)d_in[14];
  const float* lnf_g = (const float*)d_in[15];
  const float* lnf_b = (const float*)d_in[16];

  const int T = in_sizes[0];          // 2048
  const int D = D_MODEL;
  const int VOC = in_sizes[1] / D;    // 32000

  char* ws = (char*)d_ws;
  float* x = (float*)(ws);
  float* xn = (float*)(ws + 8388608ull);
  unsigned short* xnbh = (unsigned short*)(ws + 8388608ull);
  unsigned short* xnbl = (unsigned short*)(ws + 12582912ull);
  float* q = (float*)(ws + 16777216ull);
  float* k = (float*)(ws + 25165824ull);
  float* v = (float*)(ws + 33554432ull);
  float* kt = (float*)(ws + 41943040ull);
  unsigned short* w1th = (unsigned short*)(ws + 16777216ull);
  unsigned short* w1tl = (unsigned short*)(ws + 25165824ull);
  unsigned short* w2th = (unsigned short*)(ws + 33554432ull);
  unsigned short* w2tl = (unsigned short*)(ws + 41943040ull);
  unsigned short* hbh = (unsigned short*)(ws + 50331648ull);
  unsigned short* hbl = (unsigned short*)(ws + 67108864ull);
  unsigned short* wqth = (unsigned short*)(ws + 50331648ull);   // overlay hbh (dead)
  unsigned short* wqtl = (unsigned short*)(ws + 52428800ull);
  unsigned short* wkth = (unsigned short*)(ws + 54525952ull);
  unsigned short* wktl = (unsigned short*)(ws + 56623104ull);
  unsigned short* wvth = (unsigned short*)(ws + 58720256ull);
  unsigned short* wvtl = (unsigned short*)(ws + 60817408ull);
  unsigned short* woth = (unsigned short*)(ws + 83886080ull);
  unsigned short* wotl = (unsigned short*)(ws + 85983232ull);
  unsigned short* wembb = (unsigned short*)(ws + 16777216ull);
  const size_t NEED = 88080384ull;  // 84 MB

  int kkeep = (T < 64) ? T : 64;
  int fk = (HEAD_DIM * kkeep + T - 1) / T;
  if (fk < 1) fk = 1;
  int nseg = T * N_HEADS;

  embed_kernel<<<T, 256, 0, stream>>>(ids, Wemb, Wpos, x);

  if (ws_size >= NEED && (T % 128) == 0 && (VOC % 128) == 0 &&
      (size_t)VOC * D * 2 <= 67108864ull) {
    // ---- bf16 MFMA path ----
    for (int l = 0; l < 2; ++l) {
      const float* wq = Wq + (size_t)l * D * D;
      const float* wk = Wk + (size_t)l * D * D;
      const float* wv = Wv + (size_t)l * D * D;
      const float* wo = Wo + (size_t)l * D * D;

      ln_kernel<<<T, 256, 0, stream>>>(x, nullptr, xnbh, xnbl,
                                       ln1_g + (size_t)l * D, ln1_b + (size_t)l * D);

      // fused transpose of all 4 DxD weights (wq,wk,wv,wo)
      transpose_conv_pair4_kernel<<<dim3(D / 32, D / 32, 4), 256, 0, stream>>>(
          wq, wqth, wqtl, wk, wkth, wktl, wv, wvth, wvtl, wo, woth, wotl, D, D);

      gemm3_qkv<<<dim3(3 * D / 128, T / 128), 256, 0, stream>>>(
          xnbh, xnbl, wqth, wqtl, wkth, wktl, wvth, wvtl, q, T, D);

      sparsify_kernel<<<(3 * nseg + 3) / 4, 256, 0, stream>>>(q, 3 * nseg, fk);

      transpose_kernel<<<dim3(D / 32, T / 32), 256, 0, stream>>>(k, kt, T, D);

      attn_kernel<<<T * N_HEADS, 128, 0, stream>>>(q, kt, v, nullptr, xnbh, xnbl, T);

      gemm3_bt<4, 0><<<dim3(D / 128, T / 128), 256, 0, stream>>>(
          xnbh, xnbl, woth, wotl, x, nullptr, nullptr, nullptr, x, T, D, D);

      ln_kernel<<<T, 256, 0, stream>>>(x, nullptr, xnbh, xnbl,
                                       ln2_g + (size_t)l * D, ln2_b + (size_t)l * D);

      transpose_conv_pair_kernel<<<dim3(HIDDEN / 32, D / 32), 256, 0, stream>>>(
          W1 + (size_t)l * D * HIDDEN, w1th, w1tl, D, HIDDEN);
      gemm3_bt<3, 1><<<dim3(HIDDEN / 128, T / 128), 256, 0, stream>>>(
          xnbh, xnbl, w1th, w1tl, nullptr, hbh, hbl,
          b1 + (size_t)l * HIDDEN, nullptr, T, HIDDEN, D);
      transpose_conv_pair_kernel<<<dim3(D / 32, HIDDEN / 32), 256, 0, stream>>>(
          W2 + (size_t)l * HIDDEN * D, w2th, w2tl, HIDDEN, D);
      gemm3_bt<5, 0><<<dim3(D / 128, T / 128), 256, 0, stream>>>(
          hbh, hbl, w2th, w2tl, x, nullptr, nullptr,
          b2 + (size_t)l * D, x, T, D, HIDDEN);
    }

    ln_kernel<<<T, 256, 0, stream>>>(x, nullptr, xnbh, nullptr, lnf_g, lnf_b);

    conv_bf16_kernel<<<4096, 256, 0, stream>>>(Wemb, wembb, (size_t)VOC * D);

    gemm_bt_bf16<0, float, true><<<dim3(T / 128, VOC / 128), 256, 0, stream>>>(
        xnbh, wembb, (float*)d_out, nullptr, nullptr, T, VOC, D);
  } else {
    // ---- fp32 fallback ----
    float* hbuf = q;
    for (int l = 0; l < 2; ++l) {
      const float* wq = Wq + (size_t)l * D * D;
      const float* wk = Wk + (size_t)l * D * D;
      const float* wv = Wv + (size_t)l * D * D;
      const float* wo = Wo + (size_t)l * D * D;

      ln_kernel<<<T, 256, 0, stream>>>(x, xn, nullptr, nullptr,
                                       ln1_g + (size_t)l * D, ln1_b + (size_t)l * D);

      dim3 g1(D / 64, T / 64);
      gemm_nn<0><<<g1, 256, 0, stream>>>(xn, wq, q, nullptr, nullptr, T, D, D);
      gemm_nn<0><<<g1, 256, 0, stream>>>(xn, wk, k, nullptr, nullptr, T, D, D);
      gemm_nn<0><<<g1, 256, 0, stream>>>(xn, wv, v, nullptr, nullptr, T, D, D);

      sparsify_kernel<<<(nseg + 3) / 4, 256, 0, stream>>>(q, nseg, fk);
      sparsify_kernel<<<(nseg + 3) / 4, 256, 0, stream>>>(k, nseg, fk);
      sparsify_kernel<<<(nseg + 3) / 4, 256, 0, stream>>>(v, nseg, fk);

      transpose_kernel<<<dim3(D / 32, T / 32), 256, 0, stream>>>(k, kt, T, D);

      attn_kernel<<<T * N_HEADS, 128, 0, stream>>>(q, kt, v, xn, nullptr, nullptr, T);

      gemm_nn<4><<<g1, 256, 0, stream>>>(xn, wo, x, nullptr, x, T, D, D);

      ln_kernel<<<T, 256, 0, stream>>>(x, xn, nullptr, nullptr,
                                       ln2_g + (size_t)l * D, ln2_b + (size_t)l * D);

      gemm_nn<3><<<dim3(HIDDEN / 64, T / 64), 256, 0, stream>>>(
          xn, W1 + (size_t)l * D * HIDDEN, hbuf, b1 + (size_t)l * HIDDEN, nullptr, T, HIDDEN, D);
      gemm_nn<5><<<g1, 256, 0, stream>>>(
          hbuf, W2 + (size_t)l * HIDDEN * D, x, b2 + (size_t)l * D, x, T, D, HIDDEN);
    }

    ln_kernel<<<T, 256, 0, stream>>>(x, xn, nullptr, nullptr, lnf_g, lnf_b);

    gemm_nt<0><<<dim3(VOC / 64, T / 64), 256, 0, stream>>>(
        xn, Wemb, (float*)d_out, nullptr, nullptr, T, VOC, D);
  }
}

// Round 15
// 1339.343 us; speedup vs baseline: 1.4734x; 1.0015x over previous
//
#include <hip/hip_runtime.h>
#include <math.h>

#define D_MODEL 1024
#define N_HEADS 16
#define HEAD_DIM 64
#define HIDDEN 4096
#define TMAX 2048

typedef __attribute__((ext_vector_type(8))) short s16x8;
typedef __attribute__((ext_vector_type(4))) float f32x4;

// ---------------- wave helpers (wave64) ----------------
__device__ __forceinline__ float wave_max_f(float v) {
#pragma unroll
  for (int o = 32; o > 0; o >>= 1) v = fmaxf(v, __shfl_xor(v, o));
  return v;
}
__device__ __forceinline__ float wave_sum_f(float v) {
#pragma unroll
  for (int o = 32; o > 0; o >>= 1) v += __shfl_xor(v, o);
  return v;
}
__device__ __forceinline__ unsigned long long wave_max_u64(unsigned long long k) {
#pragma unroll
  for (int o = 32; o > 0; o >>= 1) {
    unsigned long long u = __shfl_xor(k, o);
    if (u > k) k = u;
  }
  return k;
}
__device__ __forceinline__ unsigned ford(float v) {
  unsigned u = __float_as_uint(v);
  return (u & 0x80000000u) ? ~u : (u | 0x80000000u);
}
// fp32 -> bf16 RNE
__device__ __forceinline__ unsigned short f2bf(float f) {
  unsigned u = __float_as_uint(f);
  u += 0x7FFFu + ((u >> 16) & 1u);
  return (unsigned short)(u >> 16);
}
__device__ __forceinline__ float bf2f(unsigned short h) {
  return __uint_as_float((unsigned)h << 16);
}

__device__ __forceinline__ void gload_lds16(const void* g, void* l) {
  __builtin_amdgcn_global_load_lds(
      (const __attribute__((address_space(1))) void*)g,
      (__attribute__((address_space(3))) void*)l, 16, 0, 0);
}

// ---------------- embedding ----------------
__global__ __launch_bounds__(256) void embed_kernel(const int* __restrict__ ids,
    const float* __restrict__ Wemb, const float* __restrict__ Wpos, float* __restrict__ X) {
  int t = blockIdx.x, tid = threadIdx.x;
  int id = ids[t];
  float4 e = ((const float4*)(Wemb + (size_t)id * D_MODEL))[tid];
  float4 p = ((const float4*)(Wpos + (size_t)t * D_MODEL))[tid];
  e.x += p.x; e.y += p.y; e.z += p.z; e.w += p.w;
  ((float4*)(X + (size_t)t * D_MODEL))[tid] = e;
}

// ---------------- layernorm; optional fp32 out + bf16 hi/lo out ----------------
__global__ __launch_bounds__(256) void ln_kernel(const float* __restrict__ X,
    float* __restrict__ Y, unsigned short* __restrict__ Ybh, unsigned short* __restrict__ Ybl,
    const float* __restrict__ g, const float* __restrict__ b) {
  int row = blockIdx.x, tid = threadIdx.x;
  int lane = tid & 63, wid = tid >> 6;
  __shared__ float red[8];
  float4 v = ((const float4*)(X + (size_t)row * D_MODEL))[tid];
  float s = v.x + v.y + v.z + v.w;
  s = wave_sum_f(s);
  if (lane == 0) red[wid] = s;
  __syncthreads();
  float mean = (red[0] + red[1] + red[2] + red[3]) * (1.0f / D_MODEL);
  float dx = v.x - mean, dy = v.y - mean, dz = v.z - mean, dw = v.w - mean;
  float q = dx * dx + dy * dy + dz * dz + dw * dw;
  q = wave_sum_f(q);
  if (lane == 0) red[4 + wid] = q;
  __syncthreads();
  float var = (red[4] + red[5] + red[6] + red[7]) * (1.0f / D_MODEL);
  float rs = rsqrtf(var + 1e-5f);
  float4 gg = ((const float4*)g)[tid], bb = ((const float4*)b)[tid];
  float4 y;
  y.x = dx * rs * gg.x + bb.x;
  y.y = dy * rs * gg.y + bb.y;
  y.z = dz * rs * gg.z + bb.z;
  y.w = dw * rs * gg.w + bb.w;
  if (Y) ((float4*)(Y + (size_t)row * D_MODEL))[tid] = y;
  if (Ybh) {
    ushort4 oh;
    oh.x = f2bf(y.x); oh.y = f2bf(y.y); oh.z = f2bf(y.z); oh.w = f2bf(y.w);
    ((ushort4*)(Ybh + (size_t)row * D_MODEL))[tid] = oh;
    if (Ybl) {
      ushort4 ol;
      ol.x = f2bf(y.x - bf2f(oh.x)); ol.y = f2bf(y.y - bf2f(oh.y));
      ol.z = f2bf(y.z - bf2f(oh.z)); ol.w = f2bf(y.w - bf2f(oh.w));
      ((ushort4*)(Ybl + (size_t)row * D_MODEL))[tid] = ol;
    }
  }
}

// ---------------- sparsify (exact top-fk by |value| per 64 segment) ----------------
__global__ __launch_bounds__(256) void sparsify_kernel(float* __restrict__ X, int nseg, int fk) {
  int seg = blockIdx.x * 4 + (threadIdx.x >> 6);
  if (seg >= nseg) return;
  int lane = threadIdx.x & 63;
  size_t idx = (size_t)seg * 64 + lane;
  float x = X[idx];
  float a = fabsf(x);
  float cur = INFINITY;
  int remaining = fk;
  float thr = 0.0f;
  for (;;) {
    float cand = (a < cur) ? a : -INFINITY;
    float mv = wave_max_f(cand);
    if (mv == -INFINITY) { thr = mv; break; }
    int c = __popcll(__ballot(a == mv));
    if (c >= remaining) { thr = mv; break; }
    remaining -= c; cur = mv;
  }
  if (!(a >= thr)) X[idx] = 0.0f;
}

// ---------------- transpose fp32 [R][C] -> [C][R] ----------------
__global__ __launch_bounds__(256) void transpose_kernel(const float* __restrict__ in,
    float* __restrict__ out, int R, int Cc) {
  __shared__ float tile[32][33];
  int c0 = blockIdx.x * 32, r0 = blockIdx.y * 32;
  int tx = threadIdx.x & 31, ty = threadIdx.x >> 5;
  for (int i = ty; i < 32; i += 8)
    tile[i][tx] = in[(size_t)(r0 + i) * Cc + c0 + tx];
  __syncthreads();
  for (int i = ty; i < 32; i += 8)
    out[(size_t)(c0 + i) * R + r0 + tx] = tile[tx][i];
}

// ---------------- transpose-convert fp32 [R][C] -> bf16 hi/lo [C][R] ----------------
__global__ __launch_bounds__(256) void transpose_conv_pair_kernel(const float* __restrict__ in,
    unsigned short* __restrict__ oh, unsigned short* __restrict__ ol, int R, int Cc) {
  __shared__ float tile[32][33];
  int c0 = blockIdx.x * 32, r0 = blockIdx.y * 32;
  int tx = threadIdx.x & 31, ty = threadIdx.x >> 5;
  for (int i = ty; i < 32; i += 8)
    tile[i][tx] = in[(size_t)(r0 + i) * Cc + c0 + tx];
  __syncthreads();
  for (int i = ty; i < 32; i += 8) {
    float v = tile[tx][i];
    unsigned short h = f2bf(v);
    size_t idx = (size_t)(c0 + i) * R + r0 + tx;
    oh[idx] = h;
    ol[idx] = f2bf(v - bf2f(h));
  }
}

// ---------------- fused 4x square transpose-convert (blockIdx.z selects) ----------------
__global__ __launch_bounds__(256) void transpose_conv_pair4_kernel(
    const float* __restrict__ s0, unsigned short* __restrict__ h0, unsigned short* __restrict__ l0,
    const float* __restrict__ s1, unsigned short* __restrict__ h1, unsigned short* __restrict__ l1,
    const float* __restrict__ s2, unsigned short* __restrict__ h2, unsigned short* __restrict__ l2,
    const float* __restrict__ s3, unsigned short* __restrict__ h3, unsigned short* __restrict__ l3,
    int R, int Cc) {
  const float* in = s0; unsigned short* oh = h0; unsigned short* ol = l0;
  if (blockIdx.z == 1) { in = s1; oh = h1; ol = l1; }
  else if (blockIdx.z == 2) { in = s2; oh = h2; ol = l2; }
  else if (blockIdx.z == 3) { in = s3; oh = h3; ol = l3; }
  __shared__ float tile[32][33];
  int c0 = blockIdx.x * 32, r0 = blockIdx.y * 32;
  int tx = threadIdx.x & 31, ty = threadIdx.x >> 5;
  for (int i = ty; i < 32; i += 8)
    tile[i][tx] = in[(size_t)(r0 + i) * Cc + c0 + tx];
  __syncthreads();
  for (int i = ty; i < 32; i += 8) {
    float v = tile[tx][i];
    unsigned short h = f2bf(v);
    size_t idx = (size_t)(c0 + i) * R + r0 + tx;
    oh[idx] = h;
    ol[idx] = f2bf(v - bf2f(h));
  }
}

// ---------------- fp32 -> bf16 elementwise ----------------
__global__ __launch_bounds__(256) void conv_bf16_kernel(const float* __restrict__ in,
    unsigned short* __restrict__ out, size_t n) {
  size_t i = ((size_t)blockIdx.x * 256 + threadIdx.x) * 4;
  size_t stride = (size_t)gridDim.x * 1024;
  for (; i < n; i += stride) {
    float4 v = *(const float4*)(in + i);
    ushort4 o;
    o.x = f2bf(v.x); o.y = f2bf(v.y); o.z = f2bf(v.z); o.w = f2bf(v.w);
    *(ushort4*)(out + i) = o;
  }
}

// ---------------- attention: 2 waves, 2 complementary jobs per block ----------------
// block p runs job t=T-1-p then t=p (work sum uniform = T+1). Per-job code is the
// r14-proven path (wave-0 selection, strip-mined scores, batch-16 gather).
__global__ __launch_bounds__(128) void attn_kernel(const float* __restrict__ Q,
    const float* __restrict__ Kt, const float* __restrict__ V,
    float* __restrict__ Of, unsigned short* __restrict__ Oh, unsigned short* __restrict__ Ol,
    int T) {
  int p = blockIdx.x % (T / 2);
  int h = blockIdx.x / (T / 2);
  int tid = threadIdx.x;
  int lane = tid & 63;
  int wvid = tid >> 6;
  unsigned long long lmlt = (1ull << lane) - 1ull;

  __shared__ float sc[TMAX];
  __shared__ float qval[HEAD_DIM];
  __shared__ int qdim[HEAD_DIM];
  constexpr int PCAP = 320;
  __shared__ float posv[PCAP];
  __shared__ int posi[PCAP];
  __shared__ int seli[64];
  __shared__ float selv[64];
  __shared__ float wsel[64];
  __shared__ float partial[64];
  __shared__ int nq_sh;

  int hoff = h * HEAD_DIM;

  for (int job = 0; job < 2; ++job) {
    int t = job == 0 ? (T - 1 - p) : p;   // long job first

    if (wvid == 0) {
      float qv = Q[(size_t)t * D_MODEL + hoff + lane];
      unsigned long long nzm = __ballot(qv != 0.0f);
      int nq0 = __popcll(nzm);
      if (qv != 0.0f) {
        int pp = __popcll(nzm & lmlt);
        qval[pp] = qv; qdim[pp] = lane;
      }
      seli[lane] = 0;  // pad target for fixed-trip gather
      if (lane == 0) nq_sh = nq0;
    }
    __syncthreads();  // B1

    int nq = nq_sh;
    int Vn = t + 1;
    // ---- score pass over 128 lanes; strip-mined x4 (8 loads in flight) ----
    if (nq == 2) {
      float qA = qval[0], qB = qval[1];
      const float* ktA = Kt + (size_t)(hoff + qdim[0]) * T;
      const float* ktB = Kt + (size_t)(hoff + qdim[1]) * T;
      int s = tid;
      for (; s + 384 < Vn; s += 512) {
        float a0 = ktA[s],       b0 = ktB[s];
        float a1 = ktA[s + 128], b1 = ktB[s + 128];
        float a2 = ktA[s + 256], b2 = ktB[s + 256];
        float a3 = ktA[s + 384], b3 = ktB[s + 384];
        sc[s]       = fmaf(qB, b0, qA * a0) * 0.125f;
        sc[s + 128] = fmaf(qB, b1, qA * a1) * 0.125f;
        sc[s + 256] = fmaf(qB, b2, qA * a2) * 0.125f;
        sc[s + 384] = fmaf(qB, b3, qA * a3) * 0.125f;
      }
      for (; s < Vn; s += 128)
        sc[s] = fmaf(qB, ktB[s], qA * ktA[s]) * 0.125f;
    } else {
      for (int s = tid; s < Vn; s += 128) {
        float acc = 0.0f;
        for (int j = 0; j < nq; ++j)
          acc += qval[j] * Kt[(size_t)(hoff + qdim[j]) * T + s];
        sc[s] = acc * 0.125f;
      }
    }
    __syncthreads();  // B2

    // ---- selection + softmax: wave 0 only (lockstep; no barriers inside) ----
    if (wvid == 0) {
      int nsel = 0;
      if (Vn <= 64) {
        nsel = Vn;
        if (lane < Vn) { seli[lane] = lane; selv[lane] = sc[lane]; }
      } else {
        // compact positive scores (list index order == s order)
        int base = 0;
        for (int s0 = 0; s0 < Vn; s0 += 64) {
          int s = s0 + lane;
          float v = (s < Vn) ? sc[s] : -1.0f;
          unsigned long long pm = __ballot(v > 0.0f);
          if (v > 0.0f) {
            int pp = base + __popcll(pm & lmlt);
            if (pp < PCAP) { posv[pp] = v; posi[pp] = s; }
          }
          base += __popcll(pm);
        }
        int P = base;

        bool fullpath = false;
        if (P >= 64) {
          if (P <= 128) {
            // ---- bitonic-128 top-64 ----
            unsigned long long key0, key1;
            {
              int e0 = lane, e1 = lane + 64;
              key0 = (e0 < P) ? (((unsigned long long)ford(posv[e0]) << 32) |
                                 (unsigned long long)(0xFFFFFFFFu - (unsigned)e0)) : 0ull;
              key1 = (e1 < P) ? (((unsigned long long)ford(posv[e1]) << 32) |
                                 (unsigned long long)(0xFFFFFFFFu - (unsigned)e1)) : 0ull;
            }
            for (int k = 2; k <= 128; k <<= 1) {
              for (int j = k >> 1; j > 0; j >>= 1) {
                if (j == 64) {
                  if (key0 < key1) { unsigned long long tm = key0; key0 = key1; key1 = tm; }
                } else {
                  bool iLower = (lane & j) == 0;
                  {
                    unsigned long long prt = __shfl_xor(key0, j);
                    bool desc = ((lane & k) == 0);
                    bool keepMax = (iLower == desc);
                    key0 = keepMax ? (key0 > prt ? key0 : prt) : (key0 < prt ? key0 : prt);
                  }
                  {
                    unsigned long long prt = __shfl_xor(key1, j);
                    int e1 = lane + 64;
                    bool desc = ((e1 & k) == 0);
                    bool keepMax = (iLower == desc);
                    key1 = keepMax ? (key1 > prt ? key1 : prt) : (key1 < prt ? key1 : prt);
                  }
                }
              }
            }
            int e = (int)(0xFFFFFFFFu - (unsigned)(key0 & 0xFFFFFFFFull));
            seli[lane] = posi[e];
            selv[lane] = posv[e];
            nsel = 64;
          } else if (P <= PCAP) {
            for (int r = 0; r < 64; ++r) {
              unsigned long long best = 0ull;
              for (int j = lane; j < P; j += 64) {
                float v = posv[j];
                if (v > 0.0f) {
                  unsigned long long key =
                      ((unsigned long long)ford(v) << 32) | (unsigned)(0xFFFFFFFFu - (unsigned)j);
                  if (key > best) best = key;
                }
              }
              best = wave_max_u64(best);
              int j = (int)(0xFFFFFFFFu - (unsigned)(best & 0xFFFFFFFFull));
              if (lane == (j & 63)) {
                seli[r] = posi[j]; selv[r] = posv[j]; posv[j] = -INFINITY;
              }
            }
            nsel = 64;
          } else {
            fullpath = true;
          }
        } else {
          if (lane < P) { seli[lane] = posi[lane]; selv[lane] = posv[lane]; }
          int need = 64 - P;
          int zbase = 0;
          bool done = false;
          for (int s0 = 0; s0 < Vn && !done; s0 += 64) {
            int s = s0 + lane;
            bool isz = (s < Vn) && (sc[s] == 0.0f);
            unsigned long long zm = __ballot(isz);
            int pre = __popcll(zm & lmlt);
            if (isz && (zbase + pre) < need) {
              seli[P + zbase + pre] = s;
              selv[P + zbase + pre] = 0.0f;
            }
            zbase += __popcll(zm);
            if (zbase >= need) done = true;
          }
          if (zbase >= need) {
            nsel = 64;
          } else {
            fullpath = true;
          }
        }

        if (fullpath) {
          nsel = 64;
          for (int r = 0; r < 64; ++r) {
            unsigned long long best = 0ull;
            for (int s = lane; s < Vn; s += 64) {
              float v = sc[s];
              if (v != -INFINITY) {
                unsigned long long key =
                    ((unsigned long long)ford(v) << 32) | (unsigned)(0x7FFFFFFFu - (unsigned)s);
                if (key > best) best = key;
              }
            }
            best = wave_max_u64(best);
            if (best == 0ull) { nsel = r; break; }
            int s = (int)(0x7FFFFFFFu - (unsigned)(best & 0xFFFFFFFFull));
            if (lane == (s & 63)) {
              seli[r] = s; selv[r] = sc[s]; sc[s] = -INFINITY;
            }
          }
        }
      }

      // softmax weights (wsel[lane]==0 for lane >= nsel)
      float v = (lane < nsel) ? selv[lane] : -INFINITY;
      float m = wave_max_f(v);
      float w = (lane < nsel) ? expf(v - m) : 0.0f;
      float ds = wave_sum_f(w);
      wsel[lane] = w / ds;
    }
    __syncthreads();  // B3

    // ---- gather: wave0 sums r=0..31, wave1 sums r=32..63; batch-16 loads ----
    float o = 0.0f;
    int rbase = wvid * 32;
    const float* Vb = V + hoff + lane;
#pragma unroll
    for (int r0 = 0; r0 < 32; r0 += 16) {
      float wv[16];
      int ib[16];
#pragma unroll
      for (int i = 0; i < 16; ++i) {
        wv[i] = wsel[rbase + r0 + i];
        ib[i] = seli[rbase + r0 + i];
      }
      float vv[16];
#pragma unroll
      for (int i = 0; i < 16; ++i) vv[i] = Vb[(size_t)ib[i] * D_MODEL];
#pragma unroll
      for (int i = 0; i < 16; ++i) o = fmaf(wv[i], vv[i], o);
    }
    if (wvid == 1) partial[lane] = o;
    __syncthreads();  // B4
    if (wvid == 0) {
      o += partial[lane];
      size_t oidx = (size_t)t * D_MODEL + hoff + lane;
      if (Of) Of[oidx] = o;
      if (Oh) {
        unsigned short hh = f2bf(o);
        Oh[oidx] = hh;
        Ol[oidx] = f2bf(o - bf2f(hh));
      }
    }
  }
}

// ============ single bf16 MFMA GEMM (NT): C[M,N] = A @ B^T ============
template <int FLAGS, typename CT, bool SWAPXY = false>
__global__ __launch_bounds__(256) void gemm_bt_bf16(const unsigned short* __restrict__ A,
    const unsigned short* __restrict__ B, CT* __restrict__ C,
    const float* __restrict__ bias, const float* __restrict__ res, int M, int N, int K) {
  constexpr bool HAS_BIAS = (FLAGS & 1) != 0;
  constexpr bool HAS_GELU = (FLAGS & 2) != 0;
  constexpr bool HAS_RES = (FLAGS & 4) != 0;
  __shared__ unsigned short As[128 * 32];
  __shared__ unsigned short Bs[128 * 32];
  int tid = threadIdx.x;
  int lane = tid & 63, wid = tid >> 6;
  int wr = wid >> 1, wc = wid & 1;
  int m0 = (SWAPXY ? blockIdx.x : blockIdx.y) * 128;
  int n0 = (SWAPXY ? blockIdx.y : blockIdx.x) * 128;

  int r_in = lane >> 2;
  int slot = lane & 3;

  f32x4 acc[4][4] = {};

  int fr = lane & 15;
  int ksl = lane >> 4;

  for (int k0 = 0; k0 < K; k0 += 32) {
#pragma unroll
    for (int s = 0; s < 2; ++s) {
      int row = wid * 32 + s * 16 + r_in;
      int ksw = (slot ^ ((row >> 1) & 3)) * 8;
      const unsigned short* ga = A + (size_t)(m0 + row) * K + k0 + ksw;
      const unsigned short* gb = B + (size_t)(n0 + row) * K + k0 + ksw;
      gload_lds16(ga, &As[(wid * 32 + s * 16) * 32]);
      gload_lds16(gb, &Bs[(wid * 32 + s * 16) * 32]);
    }
    asm volatile("s_waitcnt vmcnt(0)" ::: "memory");
    __syncthreads();

    s16x8 av[4], bv[4];
#pragma unroll
    for (int mi = 0; mi < 4; ++mi) {
      int ar = wr * 64 + mi * 16 + fr;
      av[mi] = *(const s16x8*)&As[ar * 32 + ((ksl ^ ((ar >> 1) & 3)) * 8)];
    }
#pragma unroll
    for (int ni = 0; ni < 4; ++ni) {
      int br = wc * 64 + ni * 16 + fr;
      bv[ni] = *(const s16x8*)&Bs[br * 32 + ((ksl ^ ((br >> 1) & 3)) * 8)];
    }
#pragma unroll
    for (int mi = 0; mi < 4; ++mi)
#pragma unroll
      for (int ni = 0; ni < 4; ++ni)
        acc[mi][ni] = __builtin_amdgcn_mfma_f32_16x16x32_bf16(av[mi], bv[ni], acc[mi][ni], 0, 0, 0);
    __syncthreads();
  }

  int cr = lane >> 4, cc = lane & 15;
#pragma unroll
  for (int mi = 0; mi < 4; ++mi) {
#pragma unroll
    for (int j = 0; j < 4; ++j) {
      int row = m0 + wr * 64 + mi * 16 + cr * 4 + j;
#pragma unroll
      for (int ni = 0; ni < 4; ++ni) {
        int col = n0 + wc * 64 + ni * 16 + cc;
        float vv = acc[mi][ni][j];
        if (HAS_BIAS) vv += bias[col];
        if (HAS_GELU) vv = 0.5f * vv * (1.0f + erff(vv * 0.70710678118654752f));
        if (HAS_RES) vv += res[(size_t)row * N + col];
        if constexpr (sizeof(CT) == 2)
          C[(size_t)row * N + col] = (CT)f2bf(vv);
        else
          C[(size_t)row * N + col] = (CT)vv;
      }
    }
  }
}

// ============ bf16x3 split-precision MFMA GEMM (NT) ============
template <int FLAGS, int OUTMODE>
__global__ __launch_bounds__(256) void gemm3_bt(
    const unsigned short* __restrict__ Ah, const unsigned short* __restrict__ Al,
    const unsigned short* __restrict__ Bh, const unsigned short* __restrict__ Bl,
    float* __restrict__ Cf, unsigned short* __restrict__ Ch, unsigned short* __restrict__ Cl,
    const float* __restrict__ bias, const float* __restrict__ res, int M, int N, int K) {
  constexpr bool HAS_BIAS = (FLAGS & 1) != 0;
  constexpr bool HAS_GELU = (FLAGS & 2) != 0;
  constexpr bool HAS_RES = (FLAGS & 4) != 0;
  __shared__ unsigned short As[2][128 * 32];
  __shared__ unsigned short Bs[2][128 * 32];
  int tid = threadIdx.x;
  int lane = tid & 63, wid = tid >> 6;
  int wr = wid >> 1, wc = wid & 1;
  int m0 = blockIdx.y * 128, n0 = blockIdx.x * 128;

  int r_in = lane >> 2;
  int slot = lane & 3;

  f32x4 acc[4][4] = {};

  int fr = lane & 15;
  int ksl = lane >> 4;

  for (int k0 = 0; k0 < K; k0 += 32) {
#pragma unroll
    for (int s = 0; s < 2; ++s) {
      int row = wid * 32 + s * 16 + r_in;
      int ksw = (slot ^ ((row >> 1) & 3)) * 8;
      size_t ao = (size_t)(m0 + row) * K + k0 + ksw;
      size_t bo = (size_t)(n0 + row) * K + k0 + ksw;
      int ldst = (wid * 32 + s * 16) * 32;
      gload_lds16(Ah + ao, &As[0][ldst]);
      gload_lds16(Al + ao, &As[1][ldst]);
      gload_lds16(Bh + bo, &Bs[0][ldst]);
      gload_lds16(Bl + bo, &Bs[1][ldst]);
    }
    asm volatile("s_waitcnt vmcnt(0)" ::: "memory");
    __syncthreads();

    s16x8 avh[4], avl[4], bvh[4], bvl[4];
#pragma unroll
    for (int mi = 0; mi < 4; ++mi) {
      int ar = wr * 64 + mi * 16 + fr;
      int off = ar * 32 + ((ksl ^ ((ar >> 1) & 3)) * 8);
      avh[mi] = *(const s16x8*)&As[0][off];
      avl[mi] = *(const s16x8*)&As[1][off];
    }
#pragma unroll
    for (int ni = 0; ni < 4; ++ni) {
      int br = wc * 64 + ni * 16 + fr;
      int off = br * 32 + ((ksl ^ ((br >> 1) & 3)) * 8);
      bvh[ni] = *(const s16x8*)&Bs[0][off];
      bvl[ni] = *(const s16x8*)&Bs[1][off];
    }
#pragma unroll
    for (int mi = 0; mi < 4; ++mi)
#pragma unroll
      for (int ni = 0; ni < 4; ++ni) {
        acc[mi][ni] = __builtin_amdgcn_mfma_f32_16x16x32_bf16(avh[mi], bvh[ni], acc[mi][ni], 0, 0, 0);
        acc[mi][ni] = __builtin_amdgcn_mfma_f32_16x16x32_bf16(avl[mi], bvh[ni], acc[mi][ni], 0, 0, 0);
        acc[mi][ni] = __builtin_amdgcn_mfma_f32_16x16x32_bf16(avh[mi], bvl[ni], acc[mi][ni], 0, 0, 0);
      }
    __syncthreads();
  }

  int cr = lane >> 4, cc = lane & 15;
#pragma unroll
  for (int mi = 0; mi < 4; ++mi) {
#pragma unroll
    for (int j = 0; j < 4; ++j) {
      int row = m0 + wr * 64 + mi * 16 + cr * 4 + j;
#pragma unroll
      for (int ni = 0; ni < 4; ++ni) {
        int col = n0 + wc * 64 + ni * 16 + cc;
        float vv = acc[mi][ni][j];
        if (HAS_BIAS) vv += bias[col];
        if (HAS_GELU) vv = 0.5f * vv * (1.0f + erff(vv * 0.70710678118654752f));
        if (HAS_RES) vv += res[(size_t)row * N + col];
        if constexpr (OUTMODE == 0) {
          Cf[(size_t)row * N + col] = vv;
        } else {
          unsigned short h = f2bf(vv);
          Ch[(size_t)row * N + col] = h;
          Cl[(size_t)row * N + col] = f2bf(vv - bf2f(h));
        }
      }
    }
  }
}

// ============ bf16x3 fused QKV (NT): [q|k|v] = xn @ [Wq^T|Wk^T|Wv^T], fp32 out ====
__global__ __launch_bounds__(256) void gemm3_qkv(
    const unsigned short* __restrict__ Ah, const unsigned short* __restrict__ Al,
    const unsigned short* __restrict__ Bqh, const unsigned short* __restrict__ Bql,
    const unsigned short* __restrict__ Bkh, const unsigned short* __restrict__ Bkl,
    const unsigned short* __restrict__ Bvh, const unsigned short* __restrict__ Bvl,
    float* __restrict__ C, int M, int K) {
  __shared__ unsigned short As[2][128 * 32];
  __shared__ unsigned short Bs[2][128 * 32];
  int tid = threadIdx.x;
  int lane = tid & 63, wid = tid >> 6;
  int wr = wid >> 1, wc = wid & 1;
  int m0 = blockIdx.y * 128;
  int n0g = blockIdx.x * 128;
  int mat = n0g >> 10;               // 0,1,2
  const unsigned short* Bh = (mat == 0) ? Bqh : (mat == 1 ? Bkh : Bvh);
  const unsigned short* Bl = (mat == 0) ? Bql : (mat == 1 ? Bkl : Bvl);
  float* Cb = C + (size_t)mat * ((size_t)M * 1024);
  int n0 = n0g & 1023;

  int r_in = lane >> 2;
  int slot = lane & 3;

  f32x4 acc[4][4] = {};

  int fr = lane & 15;
  int ksl = lane >> 4;

  for (int k0 = 0; k0 < K; k0 += 32) {
#pragma unroll
    for (int s = 0; s < 2; ++s) {
      int row = wid * 32 + s * 16 + r_in;
      int ksw = (slot ^ ((row >> 1) & 3)) * 8;
      size_t ao = (size_t)(m0 + row) * K + k0 + ksw;
      size_t bo = (size_t)(n0 + row) * K + k0 + ksw;
      int ldst = (wid * 32 + s * 16) * 32;
      gload_lds16(Ah + ao, &As[0][ldst]);
      gload_lds16(Al + ao, &As[1][ldst]);
      gload_lds16(Bh + bo, &Bs[0][ldst]);
      gload_lds16(Bl + bo, &Bs[1][ldst]);
    }
    asm volatile("s_waitcnt vmcnt(0)" ::: "memory");
    __syncthreads();

    s16x8 avh[4], avl[4], bvh[4], bvl[4];
#pragma unroll
    for (int mi = 0; mi < 4; ++mi) {
      int ar = wr * 64 + mi * 16 + fr;
      int off = ar * 32 + ((ksl ^ ((ar >> 1) & 3)) * 8);
      avh[mi] = *(const s16x8*)&As[0][off];
      avl[mi] = *(const s16x8*)&As[1][off];
    }
#pragma unroll
    for (int ni = 0; ni < 4; ++ni) {
      int br = wc * 64 + ni * 16 + fr;
      int off = br * 32 + ((ksl ^ ((br >> 1) & 3)) * 8);
      bvh[ni] = *(const s16x8*)&Bs[0][off];
      bvl[ni] = *(const s16x8*)&Bs[1][off];
    }
#pragma unroll
    for (int mi = 0; mi < 4; ++mi)
#pragma unroll
      for (int ni = 0; ni < 4; ++ni) {
        acc[mi][ni] = __builtin_amdgcn_mfma_f32_16x16x32_bf16(avh[mi], bvh[ni], acc[mi][ni], 0, 0, 0);
        acc[mi][ni] = __builtin_amdgcn_mfma_f32_16x16x32_bf16(avl[mi], bvh[ni], acc[mi][ni], 0, 0, 0);
        acc[mi][ni] = __builtin_amdgcn_mfma_f32_16x16x32_bf16(avh[mi], bvl[ni], acc[mi][ni], 0, 0, 0);
      }
    __syncthreads();
  }

  int cr = lane >> 4, cc = lane & 15;
#pragma unroll
  for (int mi = 0; mi < 4; ++mi) {
#pragma unroll
    for (int j = 0; j < 4; ++j) {
      int row = m0 + wr * 64 + mi * 16 + cr * 4 + j;
#pragma unroll
      for (int ni = 0; ni < 4; ++ni) {
        int col = n0 + wc * 64 + ni * 16 + cc;
        Cb[(size_t)row * 1024 + col] = acc[mi][ni][j];
      }
    }
  }
}

// ---------------- fp32 tiled GEMM (NN, fallback) ----------------
template <int FLAGS>
__global__ __launch_bounds__(256) void gemm_nn(const float* __restrict__ A,
    const float* __restrict__ B, float* __restrict__ C, const float* __restrict__ bias,
    const float* __restrict__ res, int M, int N, int K) {
  constexpr bool HAS_BIAS = (FLAGS & 1) != 0;
  constexpr bool HAS_GELU = (FLAGS & 2) != 0;
  constexpr bool HAS_RES = (FLAGS & 4) != 0;
  __shared__ float As[16][68];
  __shared__ float Bs[16][68];
  int tid = threadIdx.x;
  int m0 = blockIdx.y * 64, n0 = blockIdx.x * 64;
  int tx = tid & 15, ty = tid >> 4;
  int am = tid >> 2, ak = (tid & 3) * 4;
  int bk = tid >> 4, bn = (tid & 15) * 4;
  const float* Ap = A + (size_t)(m0 + am) * K + ak;
  const float* Bp = B + (size_t)bk * N + n0 + bn;
  float acc[4][4] = {};
  for (int k0 = 0; k0 < K; k0 += 16) {
    float4 a4 = *(const float4*)(Ap + k0);
    float4 b4 = *(const float4*)(Bp + (size_t)k0 * N);
    As[ak + 0][am] = a4.x; As[ak + 1][am] = a4.y;
    As[ak + 2][am] = a4.z; As[ak + 3][am] = a4.w;
    *(float4*)&Bs[bk][bn] = b4;
    __syncthreads();
#pragma unroll
    for (int k = 0; k < 16; ++k) {
      float4 bq = *(const float4*)&Bs[k][tx * 4];
#pragma unroll
      for (int i = 0; i < 4; ++i) {
        float av = As[k][ty * 4 + i];
        acc[i][0] += av * bq.x; acc[i][1] += av * bq.y;
        acc[i][2] += av * bq.z; acc[i][3] += av * bq.w;
      }
    }
    __syncthreads();
  }
#pragma unroll
  for (int i = 0; i < 4; ++i) {
    int row = m0 + ty * 4 + i;
#pragma unroll
    for (int j = 0; j < 4; ++j) {
      int col = n0 + tx * 4 + j;
      float vv = acc[i][j];
      if (HAS_BIAS) vv += bias[col];
      if (HAS_GELU) vv = 0.5f * vv * (1.0f + erff(vv * 0.70710678118654752f));
      if (HAS_RES) vv += res[(size_t)row * N + col];
      C[(size_t)row * N + col] = vv;
    }
  }
}

// ---------------- fp32 tiled GEMM (NT, fallback logits) ----------------
template <int FLAGS>
__global__ __launch_bounds__(256) void gemm_nt(const float* __restrict__ A,
    const float* __restrict__ B, float* __restrict__ C, const float* __restrict__ bias,
    const float* __restrict__ res, int M, int N, int K) {
  constexpr bool HAS_BIAS = (FLAGS & 1) != 0;
  constexpr bool HAS_GELU = (FLAGS & 2) != 0;
  constexpr bool HAS_RES = (FLAGS & 4) != 0;
  __shared__ float As[16][68];
  __shared__ float Bs[16][68];
  int tid = threadIdx.x;
  int m0 = blockIdx.y * 64, n0 = blockIdx.x * 64;
  int tx = tid & 15, ty = tid >> 4;
  int am = tid >> 2, ak = (tid & 3) * 4;
  int bn2 = tid >> 2, bk2 = (tid & 3) * 4;
  const float* Ap = A + (size_t)(m0 + am) * K + ak;
  const float* Bp = B + (size_t)(n0 + bn2) * K + bk2;
  float acc[4][4] = {};
  for (int k0 = 0; k0 < K; k0 += 16) {
    float4 a4 = *(const float4*)(Ap + k0);
    float4 b4 = *(const float4*)(Bp + k0);
    As[ak + 0][am] = a4.x; As[ak + 1][am] = a4.y;
    As[ak + 2][am] = a4.z; As[ak + 3][am] = a4.w;
    Bs[bk2 + 0][bn2] = b4.x; Bs[bk2 + 1][bn2] = b4.y;
    Bs[bk2 + 2][bn2] = b4.z; Bs[bk2 + 3][bn2] = b4.w;
    __syncthreads();
#pragma unroll
    for (int k = 0; k < 16; ++k) {
      float4 bq = *(const float4*)&Bs[k][tx * 4];
#pragma unroll
      for (int i = 0; i < 4; ++i) {
        float av = As[k][ty * 4 + i];
        acc[i][0] += av * bq.x; acc[i][1] += av * bq.y;
        acc[i][2] += av * bq.z; acc[i][3] += av * bq.w;
      }
    }
    __syncthreads();
  }
#pragma unroll
  for (int i = 0; i < 4; ++i) {
    int row = m0 + ty * 4 + i;
#pragma unroll
    for (int j = 0; j < 4; ++j) {
      int col = n0 + tx * 4 + j;
      float vv = acc[i][j];
      if (HAS_BIAS) vv += bias[col];
      if (HAS_GELU) vv = 0.5f * vv * (1.0f + erff(vv * 0.70710678118654752f));
      if (HAS_RES) vv += res[(size_t)row * N + col];
      C[(size_t)row * N + col] = vv;
    }
  }
}

// ---------------- host orchestration ----------------
extern "C" void kernel_launch(void* const* d_in, const int* in_sizes, int n_in,
                              void* d_out, int out_size, void* d_ws, size_t ws_size,
                              hipStream_t stream) {
  const int* ids = (const int*)d_in[0];
  const float* Wemb = (const float*)d_in[1];
  const float* Wpos = (const float*)d_in[2];
  const float* ln1_g = (const float*)d_in[3];
  const float* ln1_b = (const float*)d_in[4];
  const float* Wq = (const float*)d_in[5];
  const float* Wk = (const float*)d_in[6];
  const float* Wv = (const float*)d_in[7];
  const float* Wo = (const float*)d_in[8];
  const float* ln2_g = (const float*)d_in[9];
  const float* ln2_b = (const float*)d_in[10];
  const float* W1 = (const float*)d_in[11];
  const float* b1 = (const float*)d_in[12];
  const float* W2 = (const float*)d_in[13];
  const float* b2 = (const float*)d_in[14];
  const float* lnf_g = (const float*)d_in[15];
  const float* lnf_b = (const float*)d_in[16];

  const int T = in_sizes[0];          // 2048
  const int D = D_MODEL;
  const int VOC = in_sizes[1] / D;    // 32000

  char* ws = (char*)d_ws;
  float* x = (float*)(ws);
  float* xn = (float*)(ws + 8388608ull);
  unsigned short* xnbh = (unsigned short*)(ws + 8388608ull);
  unsigned short* xnbl = (unsigned short*)(ws + 12582912ull);
  float* q = (float*)(ws + 16777216ull);
  float* k = (float*)(ws + 25165824ull);
  float* v = (float*)(ws + 33554432ull);
  float* kt = (float*)(ws + 41943040ull);
  unsigned short* w1th = (unsigned short*)(ws + 16777216ull);
  unsigned short* w1tl = (unsigned short*)(ws + 25165824ull);
  unsigned short* w2th = (unsigned short*)(ws + 33554432ull);
  unsigned short* w2tl = (unsigned short*)(ws + 41943040ull);
  unsigned short* hbh = (unsigned short*)(ws + 50331648ull);
  unsigned short* hbl = (unsigned short*)(ws + 67108864ull);
  unsigned short* wqth = (unsigned short*)(ws + 50331648ull);   // overlay hbh (dead)
  unsigned short* wqtl = (unsigned short*)(ws + 52428800ull);
  unsigned short* wkth = (unsigned short*)(ws + 54525952ull);
  unsigned short* wktl = (unsigned short*)(ws + 56623104ull);
  unsigned short* wvth = (unsigned short*)(ws + 58720256ull);
  unsigned short* wvtl = (unsigned short*)(ws + 60817408ull);
  unsigned short* woth = (unsigned short*)(ws + 83886080ull);
  unsigned short* wotl = (unsigned short*)(ws + 85983232ull);
  unsigned short* wembb = (unsigned short*)(ws + 16777216ull);
  const size_t NEED = 88080384ull;  // 84 MB

  int kkeep = (T < 64) ? T : 64;
  int fk = (HEAD_DIM * kkeep + T - 1) / T;
  if (fk < 1) fk = 1;
  int nseg = T * N_HEADS;

  embed_kernel<<<T, 256, 0, stream>>>(ids, Wemb, Wpos, x);

  if (ws_size >= NEED && (T % 128) == 0 && (VOC % 128) == 0 &&
      (size_t)VOC * D * 2 <= 67108864ull) {
    // ---- bf16 MFMA path ----
    for (int l = 0; l < 2; ++l) {
      const float* wq = Wq + (size_t)l * D * D;
      const float* wk = Wk + (size_t)l * D * D;
      const float* wv = Wv + (size_t)l * D * D;
      const float* wo = Wo + (size_t)l * D * D;

      ln_kernel<<<T, 256, 0, stream>>>(x, nullptr, xnbh, xnbl,
                                       ln1_g + (size_t)l * D, ln1_b + (size_t)l * D);

      // fused transpose of all 4 DxD weights (wq,wk,wv,wo)
      transpose_conv_pair4_kernel<<<dim3(D / 32, D / 32, 4), 256, 0, stream>>>(
          wq, wqth, wqtl, wk, wkth, wktl, wv, wvth, wvtl, wo, woth, wotl, D, D);

      gemm3_qkv<<<dim3(3 * D / 128, T / 128), 256, 0, stream>>>(
          xnbh, xnbl, wqth, wqtl, wkth, wktl, wvth, wvtl, q, T, D);

      sparsify_kernel<<<(3 * nseg + 3) / 4, 256, 0, stream>>>(q, 3 * nseg, fk);

      transpose_kernel<<<dim3(D / 32, T / 32), 256, 0, stream>>>(k, kt, T, D);

      attn_kernel<<<(T / 2) * N_HEADS, 128, 0, stream>>>(q, kt, v, nullptr, xnbh, xnbl, T);

      gemm3_bt<4, 0><<<dim3(D / 128, T / 128), 256, 0, stream>>>(
          xnbh, xnbl, woth, wotl, x, nullptr, nullptr, nullptr, x, T, D, D);

      ln_kernel<<<T, 256, 0, stream>>>(x, nullptr, xnbh, xnbl,
                                       ln2_g + (size_t)l * D, ln2_b + (size_t)l * D);

      transpose_conv_pair_kernel<<<dim3(HIDDEN / 32, D / 32), 256, 0, stream>>>(
          W1 + (size_t)l * D * HIDDEN, w1th, w1tl, D, HIDDEN);
      gemm3_bt<3, 1><<<dim3(HIDDEN / 128, T / 128), 256, 0, stream>>>(
          xnbh, xnbl, w1th, w1tl, nullptr, hbh, hbl,
          b1 + (size_t)l * HIDDEN, nullptr, T, HIDDEN, D);
      transpose_conv_pair_kernel<<<dim3(D / 32, HIDDEN / 32), 256, 0, stream>>>(
          W2 + (size_t)l * HIDDEN * D, w2th, w2tl, HIDDEN, D);
      gemm3_bt<5, 0><<<dim3(D / 128, T / 128), 256, 0, stream>>>(
          hbh, hbl, w2th, w2tl, x, nullptr, nullptr,
          b2 + (size_t)l * D, x, T, D, HIDDEN);
    }

    ln_kernel<<<T, 256, 0, stream>>>(x, nullptr, xnbh, nullptr, lnf_g, lnf_b);

    conv_bf16_kernel<<<4096, 256, 0, stream>>>(Wemb, wembb, (size_t)VOC * D);

    gemm_bt_bf16<0, float, true><<<dim3(T / 128, VOC / 128), 256, 0, stream>>>(
        xnbh, wembb, (float*)d_out, nullptr, nullptr, T, VOC, D);
  } else {
    // ---- fp32 fallback ----
    float* hbuf = q;
    for (int l = 0; l < 2; ++l) {
      const float* wq = Wq + (size_t)l * D * D;
      const float* wk = Wk + (size_t)l * D * D;
      const float* wv = Wv + (size_t)l * D * D;
      const float* wo = Wo + (size_t)l * D * D;

      ln_kernel<<<T, 256, 0, stream>>>(x, xn, nullptr, nullptr,
                                       ln1_g + (size_t)l * D, ln1_b + (size_t)l * D);

      dim3 g1(D / 64, T / 64);
      gemm_nn<0><<<g1, 256, 0, stream>>>(xn, wq, q, nullptr, nullptr, T, D, D);
      gemm_nn<0><<<g1, 256, 0, stream>>>(xn, wk, k, nullptr, nullptr, T, D, D);
      gemm_nn<0><<<g1, 256, 0, stream>>>(xn, wv, v, nullptr, nullptr, T, D, D);

      sparsify_kernel<<<(nseg + 3) / 4, 256, 0, stream>>>(q, nseg, fk);
      sparsify_kernel<<<(nseg + 3) / 4, 256, 0, stream>>>(k, nseg, fk);
      sparsify_kernel<<<(nseg + 3) / 4, 256, 0, stream>>>(v, nseg, fk);

      transpose_kernel<<<dim3(D / 32, T / 32), 256, 0, stream>>>(k, kt, T, D);

      attn_kernel<<<(T / 2) * N_HEADS, 128, 0, stream>>>(q, kt, v, xn, nullptr, nullptr, T);

      gemm_nn<4><<<g1, 256, 0, stream>>>(xn, wo, x, nullptr, x, T, D, D);

      ln_kernel<<<T, 256, 0, stream>>>(x, xn, nullptr, nullptr,
                                       ln2_g + (size_t)l * D, ln2_b + (size_t)l * D);

      gemm_nn<3><<<dim3(HIDDEN / 64, T / 64), 256, 0, stream>>>(
          xn, W1 + (size_t)l * D * HIDDEN, hbuf, b1 + (size_t)l * HIDDEN, nullptr, T, HIDDEN, D);
      gemm_nn<5><<<g1, 256, 0, stream>>>(
          hbuf, W2 + (size_t)l * HIDDEN * D, x, b2 + (size_t)l * D, x, T, D, HIDDEN);
    }

    ln_kernel<<<T, 256, 0, stream>>>(x, xn, nullptr, nullptr, lnf_g, lnf_b);

    gemm_nt<0><<<dim3(VOC / 64, T / 64), 256, 0, stream>>>(
        xn, Wemb, (float*)d_out, nullptr, nullptr, T, VOC, D);
  }
}